// Round 2
// baseline (1799.741 us; speedup 1.0000x reference)
//
#include <hip/hip_runtime.h>
#include <hip/hip_bf16.h>
#include <cstdint>
#include <cstddef>

// Problem constants
#define NB 8
#define NP 2048
#define NK 20
#define BN 16384      // NB*NP
#define SROW 512      // xcat row stride (64+64+128+256)

// ---------------- workspace layout (bytes) ----------------
static constexpr size_t OFF_IDX  = 0;                          // int[BN*20]
static constexpr size_t OFF_XT   = OFF_IDX  + (size_t)BN*NK*4; // f32[BN*3]
static constexpr size_t OFF_XCAT = OFF_XT   + (size_t)BN*3*4;  // f32[BN*512]
static constexpr size_t OFF_WT1  = OFF_XCAT + (size_t)BN*SROW*4;
static constexpr size_t OFF_WD1  = OFF_WT1  + 3*64*4;
static constexpr size_t OFF_WT2  = OFF_WD1  + 3*64*4;
static constexpr size_t OFF_WD2  = OFF_WT2  + 64*64*4;
static constexpr size_t OFF_WT3  = OFF_WD2  + 64*64*4;
static constexpr size_t OFF_WD3  = OFF_WT3  + 64*128*4;
static constexpr size_t OFF_WT4  = OFF_WD3  + 64*128*4;
static constexpr size_t OFF_WD4  = OFF_WT4  + 128*256*4;
static constexpr size_t OFF_WT5  = OFF_WD4  + 128*256*4;       // f32[512*1024]
static constexpr size_t OFF_HMAX = OFF_WT5  + (size_t)512*1024*4; // f32[BN*256]; reused as bf16 h5[BN*1024]
static constexpr size_t OFF_HMIN = OFF_HMAX + (size_t)BN*256*4;
static constexpr size_t OFF_PART = OFF_HMIN + (size_t)BN*256*4;   // 4 slabs of 1024*1024 f32 (sum, sumsq, pmax, pmin)
static constexpr size_t OFF_SS   = OFF_PART + (size_t)4*1024*1024*4;
static constexpr size_t OFF_Z    = OFF_SS   + 2*1024*4;        // f32[8*2048]
static constexpr size_t OFF_Z1P  = OFF_Z    + (size_t)NB*2048*4;
static constexpr size_t OFF_Z1   = OFF_Z1P  + NB*512*4;
static constexpr size_t OFF_Z2P  = OFF_Z1   + NB*512*4;
static constexpr size_t OFF_Z2   = OFF_Z2P  + NB*256*4;
// total ~84 MB

// ---------------- kernels ----------------

__global__ void k_transpose_x(const float* __restrict__ x, float* __restrict__ xt) {
  int t = blockIdx.x * 256 + threadIdx.x;       // over NB*3*NP
  if (t >= NB * 3 * NP) return;
  int n = t & (NP - 1);
  int c = (t / NP) % 3;
  int b = t / (3 * NP);
  xt[(size_t)(b * NP + n) * 3 + c] = x[t];
}

__global__ void k_prep_w(const float* __restrict__ W, float* __restrict__ Wt,
                         float* __restrict__ Wd, int C, int O) {
  int t = blockIdx.x * 256 + threadIdx.x;       // over C*O
  if (t >= C * O) return;
  int o = t % O, c = t / O;
  float w0 = W[o * 2 * C + c];
  float w1 = W[o * 2 * C + C + c];
  Wt[t] = w0;
  Wd[t] = w1 - w0;
}

__global__ void k_tr_w5(const float* __restrict__ W5, float* __restrict__ Wt5) {
  int t = blockIdx.x * 256 + threadIdx.x;       // over 512*1024
  if (t >= 512 * 1024) return;
  int o = t & 1023, c = t >> 10;
  Wt5[t] = W5[o * 512 + c];
}

// top-20 per row of 2048, lowest-index tie-break (matches jax.lax.top_k)
__global__ __launch_bounds__(256) void k_topk(const float* __restrict__ geod,
                                              int* __restrict__ idx) {
  int row = blockIdx.x;                          // 0..BN-1
  const float* g = geod + (size_t)row * NP;
  int tid = threadIdx.x;
  float v[8];
#pragma unroll
  for (int r = 0; r < 8; ++r) v[r] = g[tid + 256 * r];
  __shared__ float s_v[4];
  __shared__ int s_i[4];
  __shared__ int s_win;
  for (int it = 0; it < NK; ++it) {
    float bv = -__builtin_huge_valf();
    int bi = 1 << 30;
#pragma unroll
    for (int r = 0; r < 8; ++r) {                // ascending index, strict > keeps lowest
      if (v[r] > bv) { bv = v[r]; bi = tid + 256 * r; }
    }
#pragma unroll
    for (int s = 32; s; s >>= 1) {
      float ov = __shfl_xor(bv, s);
      int   oi = __shfl_xor(bi, s);
      if (ov > bv || (ov == bv && oi < bi)) { bv = ov; bi = oi; }
    }
    int w = tid >> 6;
    if ((tid & 63) == 0) { s_v[w] = bv; s_i[w] = bi; }
    __syncthreads();
    if (tid == 0) {
      float fbv = s_v[0]; int fbi = s_i[0];
#pragma unroll
      for (int ww = 1; ww < 4; ++ww)
        if (s_v[ww] > fbv || (s_v[ww] == fbv && s_i[ww] < fbi)) { fbv = s_v[ww]; fbi = s_i[ww]; }
      s_win = fbi;
      idx[(size_t)row * NK + it] = fbi;
    }
    __syncthreads();
    int win = s_win;
    if ((win & 255) == tid) v[win >> 8] = -__builtin_huge_valf();
  }
}

// EdgeConv phase A: per point compute per-channel max/min over k of pre-BN h,
// plus per-block partial sums/sumsq per channel.
template <int C, int O>
__global__ __launch_bounds__(256) void k_edge(
    const float* __restrict__ xin, int in_off, int in_stride,
    const int* __restrict__ idx,
    const float* __restrict__ Wt, const float* __restrict__ Wd,
    float* __restrict__ hmax, float* __restrict__ hmin,
    float* __restrict__ part, int ngrp) {
  constexpr int PIF = 256 / O;                   // points in flight
  __shared__ __align__(16) float lds[PIF * 21 * C];
  __shared__ int lidx[PIF * NK];
  __shared__ float red[256];
  int tid = threadIdx.x;
  int g = tid / O, o = tid % O;
  float ps = 0.f, ps2 = 0.f;
  for (int it = 0; it < ngrp; ++it) {
    int grp = blockIdx.x * ngrp + it;
    int p0 = grp * PIF;
    for (int u = tid; u < PIF * NK; u += 256) lidx[u] = idx[(size_t)p0 * NK + u];
    __syncthreads();
    for (int u = tid; u < PIF * 21 * C; u += 256) {
      int pp  = u / (21 * C);
      int rem = u - pp * 21 * C;
      int j   = rem / C;
      int c   = rem - j * C;
      int p   = p0 + pp;
      int bbase = p & ~(NP - 1);
      int srcn = (j == 20) ? p : (bbase + lidx[pp * NK + j]);
      lds[u] = xin[(size_t)srcn * in_stride + in_off + c];
    }
    __syncthreads();
    const float* xl = &lds[g * 21 * C];
    float base = 0.f;
    if constexpr (C % 4 == 0) {
      for (int c = 0; c < C; c += 4) {
        float4 xv = *(const float4*)&xl[20 * C + c];
        base += xv.x * Wd[(c + 0) * O + o] + xv.y * Wd[(c + 1) * O + o]
              + xv.z * Wd[(c + 2) * O + o] + xv.w * Wd[(c + 3) * O + o];
      }
    } else {
      for (int c = 0; c < C; ++c) base += xl[20 * C + c] * Wd[c * O + o];
    }
    float h[NK];
#pragma unroll
    for (int j = 0; j < NK; ++j) h[j] = base;
    if constexpr (C % 4 == 0) {
      for (int c = 0; c < C; c += 4) {
        float w0 = Wt[(c + 0) * O + o], w1 = Wt[(c + 1) * O + o];
        float w2 = Wt[(c + 2) * O + o], w3 = Wt[(c + 3) * O + o];
#pragma unroll
        for (int j = 0; j < NK; ++j) {
          float4 xv = *(const float4*)&xl[j * C + c];
          h[j] += xv.x * w0 + xv.y * w1 + xv.z * w2 + xv.w * w3;
        }
      }
    } else {
      for (int c = 0; c < C; ++c) {
        float w = Wt[c * O + o];
#pragma unroll
        for (int j = 0; j < NK; ++j) h[j] += xl[j * C + c] * w;
      }
    }
    float mx = h[0], mn = h[0];
#pragma unroll
    for (int j = 0; j < NK; ++j) {
      mx = fmaxf(mx, h[j]); mn = fminf(mn, h[j]);
      ps += h[j]; ps2 += h[j] * h[j];
    }
    int p = p0 + g;
    hmax[(size_t)p * O + o] = mx;
    hmin[(size_t)p * O + o] = mn;
    __syncthreads();                             // before lds overwrite next iter
  }
  red[tid] = ps;
  __syncthreads();
  if (tid < O) {
    float a = red[tid];
#pragma unroll
    for (int g2 = 1; g2 < PIF; ++g2) a += red[g2 * O + tid];
    part[(size_t)blockIdx.x * O + tid] = a;
  }
  __syncthreads();
  red[tid] = ps2;
  __syncthreads();
  if (tid < O) {
    float a = red[tid];
#pragma unroll
    for (int g2 = 1; g2 < PIF; ++g2) a += red[g2 * O + tid];
    part[((size_t)gridDim.x + blockIdx.x) * O + tid] = a;
  }
}

// reduce partials -> per-channel BN scale/shift.  grid = O blocks.
__global__ __launch_bounds__(256) void k_finalize(
    const float* __restrict__ part, int G, int O, float inv_count,
    const float* __restrict__ gamma, const float* __restrict__ beta,
    float* __restrict__ ss) {
  int o = blockIdx.x;
  float s = 0.f, s2 = 0.f;
  for (int g = threadIdx.x; g < G; g += 256) {
    s  += part[(size_t)g * O + o];
    s2 += part[((size_t)G + g) * O + o];
  }
#pragma unroll
  for (int sft = 32; sft; sft >>= 1) {
    s  += __shfl_down(s, sft);
    s2 += __shfl_down(s2, sft);
  }
  __shared__ float aw[4], aw2[4];
  int w = threadIdx.x >> 6;
  if ((threadIdx.x & 63) == 0) { aw[w] = s; aw2[w] = s2; }
  __syncthreads();
  if (threadIdx.x == 0) {
    s = aw[0] + aw[1] + aw[2] + aw[3];
    s2 = aw2[0] + aw2[1] + aw2[2] + aw2[3];
    float m   = s * inv_count;
    float var = s2 * inv_count - m * m;
    float scale = gamma[o] * rsqrtf(var + 1e-5f);
    ss[o]     = scale;
    ss[O + o] = beta[o] - m * scale;
  }
}

// apply BN+lrelu to (max or min per sign of scale), write into xcat slice
__global__ void k_edge_apply(const float* __restrict__ hmax, const float* __restrict__ hmin,
                             const float* __restrict__ ss, float* __restrict__ xcat,
                             int O, int out_off) {
  int t = blockIdx.x * 256 + threadIdx.x;        // over BN*O
  int o = t % O;
  int p = t / O;
  float scale = ss[o], shift = ss[O + o];
  float v = (scale >= 0.f) ? hmax[t] : hmin[t];
  v = scale * v + shift;
  v = (v >= 0.f) ? v : 0.2f * v;
  xcat[(size_t)p * SROW + out_off + o] = v;
}

// conv5 pass 1: h5[bn][o] = cat[bn][:512] . Wt5[:,o] ; store bf16 (for mean pool)
// + per-block partial sum/sumsq/max/min in fp32 (exact stats & exact max pool).
// grid = 1024 blocks, 16 rows each, each thread does o = tid + {0,256,512,768}.
__global__ __launch_bounds__(256) void k_conv5(
    const float* __restrict__ xcat, const float* __restrict__ Wt5,
    __hip_bfloat16* __restrict__ h5, float* __restrict__ part) {
  __shared__ __align__(16) float lds[16 * 512];
  int tid = threadIdx.x;
  size_t r0 = (size_t)blockIdx.x * 16;
  for (int u = tid; u < 16 * 512; u += 256) lds[u] = xcat[r0 * 512 + u];
  __syncthreads();
  float acc[16][4];
#pragma unroll
  for (int rr = 0; rr < 16; ++rr)
#pragma unroll
    for (int oi = 0; oi < 4; ++oi) acc[rr][oi] = 0.f;
  for (int c = 0; c < 512; c += 4) {
    float w[4][4];
#pragma unroll
    for (int cc = 0; cc < 4; ++cc)
#pragma unroll
      for (int oi = 0; oi < 4; ++oi)
        w[cc][oi] = Wt5[(size_t)(c + cc) * 1024 + oi * 256 + tid];
#pragma unroll
    for (int rr = 0; rr < 16; ++rr) {
      float4 xv = *(const float4*)&lds[rr * 512 + c];
#pragma unroll
      for (int oi = 0; oi < 4; ++oi)
        acc[rr][oi] += xv.x * w[0][oi] + xv.y * w[1][oi] + xv.z * w[2][oi] + xv.w * w[3][oi];
    }
  }
  float ps[4] = {0, 0, 0, 0}, ps2[4] = {0, 0, 0, 0};
  float pmx[4], pmn[4];
#pragma unroll
  for (int oi = 0; oi < 4; ++oi) { pmx[oi] = -__builtin_huge_valf(); pmn[oi] = __builtin_huge_valf(); }
#pragma unroll
  for (int rr = 0; rr < 16; ++rr)
#pragma unroll
    for (int oi = 0; oi < 4; ++oi) {
      float v = acc[rr][oi];
      h5[(r0 + rr) * 1024 + oi * 256 + tid] = __float2bfloat16(v);
      ps[oi] += v; ps2[oi] += v * v;
      pmx[oi] = fmaxf(pmx[oi], v); pmn[oi] = fminf(pmn[oi], v);
    }
#pragma unroll
  for (int oi = 0; oi < 4; ++oi) {
    part[(size_t)blockIdx.x * 1024 + oi * 256 + tid] = ps[oi];
    part[((size_t)1024 + blockIdx.x) * 1024 + oi * 256 + tid] = ps2[oi];
    part[((size_t)2048 + blockIdx.x) * 1024 + oi * 256 + tid] = pmx[oi];
    part[((size_t)3072 + blockIdx.x) * 1024 + oi * 256 + tid] = pmn[oi];
  }
}

// conv5 pass 2: exact max pool via fp32 block partials (BN+lrelu commute with max),
// mean pool via bf16 h5 scan (rounding error averages out over 2048 samples).
__global__ __launch_bounds__(256) void k_pool5(const __hip_bfloat16* __restrict__ h5,
                                               const float* __restrict__ part,
                                               const float* __restrict__ ss,
                                               float* __restrict__ z) {
  int b = blockIdx.x >> 2;
  int o = ((blockIdx.x & 3) << 8) + threadIdx.x;
  float scale = ss[o], shift = ss[1024 + o];
  const float* pmx = part + (size_t)2048 * 1024;
  const float* pmn = part + (size_t)3072 * 1024;
  float mxh = -__builtin_huge_valf(), mnh = __builtin_huge_valf();
  for (int q = 0; q < 128; ++q) {
    size_t base = ((size_t)(b * 128 + q)) * 1024 + o;
    mxh = fmaxf(mxh, pmx[base]);
    mnh = fminf(mnh, pmn[base]);
  }
  float hsel = (scale >= 0.f) ? mxh : mnh;
  float zmax = scale * hsel + shift;
  zmax = (zmax >= 0.f) ? zmax : 0.2f * zmax;
  float sm = 0.f;
  const __hip_bfloat16* p = h5 + (size_t)b * NP * 1024 + o;
  for (int n = 0; n < NP; ++n) {
    float v = __bfloat162float(p[(size_t)n * 1024]);
    v = scale * v + shift;
    v = (v >= 0.f) ? v : 0.2f * v;
    sm += v;
  }
  z[b * 2048 + o] = zmax;
  z[b * 2048 + 1024 + o] = sm * (1.f / NP);
}

// generic FC: out[b][o] = in[b][:IN] . W[o][:IN] (+ bias). one wave per (b,o).
__global__ __launch_bounds__(64) void k_fc(const float* __restrict__ in,
                                           const float* __restrict__ Wf,
                                           const float* __restrict__ bias,
                                           float* __restrict__ out, int IN, int O) {
  int blk = blockIdx.x;
  int b = blk / O, o = blk % O;
  const float* a = in + (size_t)b * IN;
  const float* w = Wf + (size_t)o * IN;
  float s = 0.f;
  for (int i = threadIdx.x; i < IN; i += 64) s += a[i] * w[i];
#pragma unroll
  for (int sft = 32; sft; sft >>= 1) s += __shfl_down(s, sft);
  if (threadIdx.x == 0) out[(size_t)b * O + o] = s + (bias ? bias[o] : 0.f);
}

// batch-axis BN (count=8) + lrelu
__global__ void k_bn_fc(const float* __restrict__ pre, const float* __restrict__ gamma,
                        const float* __restrict__ beta, float* __restrict__ out, int O) {
  int o = blockIdx.x * 256 + threadIdx.x;
  if (o >= O) return;
  float v[NB];
  float s = 0.f, s2 = 0.f;
#pragma unroll
  for (int b = 0; b < NB; ++b) {
    v[b] = pre[(size_t)b * O + o];
    s += v[b]; s2 += v[b] * v[b];
  }
  float m = s * (1.f / NB);
  float var = s2 * (1.f / NB) - m * m;
  float scale = gamma[o] * rsqrtf(var + 1e-5f);
  float shift = beta[o] - m * scale;
#pragma unroll
  for (int b = 0; b < NB; ++b) {
    float x = scale * v[b] + shift;
    out[(size_t)b * O + o] = (x >= 0.f) ? x : 0.2f * x;
  }
}

// ---------------- launcher ----------------
extern "C" void kernel_launch(void* const* d_in, const int* in_sizes, int n_in,
                              void* d_out, int out_size, void* d_ws, size_t ws_size,
                              hipStream_t stream) {
  (void)in_sizes; (void)n_in; (void)out_size; (void)ws_size;
  const float* x    = (const float*)d_in[0];
  const float* geod = (const float*)d_in[1];
  const float* W1   = (const float*)d_in[2];
  const float* g1   = (const float*)d_in[3];
  const float* bt1  = (const float*)d_in[4];
  const float* W2   = (const float*)d_in[5];
  const float* g2   = (const float*)d_in[6];
  const float* bt2  = (const float*)d_in[7];
  const float* W3   = (const float*)d_in[8];
  const float* g3   = (const float*)d_in[9];
  const float* bt3  = (const float*)d_in[10];
  const float* W4   = (const float*)d_in[11];
  const float* g4   = (const float*)d_in[12];
  const float* bt4  = (const float*)d_in[13];
  const float* W5   = (const float*)d_in[14];
  const float* g5   = (const float*)d_in[15];
  const float* bt5  = (const float*)d_in[16];
  const float* L1   = (const float*)d_in[17];
  const float* g6   = (const float*)d_in[18];
  const float* bt6  = (const float*)d_in[19];
  const float* L2   = (const float*)d_in[20];
  const float* bl2  = (const float*)d_in[21];
  const float* g7   = (const float*)d_in[22];
  const float* bt7  = (const float*)d_in[23];
  const float* L3   = (const float*)d_in[24];
  const float* bl3  = (const float*)d_in[25];

  char* ws = (char*)d_ws;
  int*   idx  = (int*)(ws + OFF_IDX);
  float* xt   = (float*)(ws + OFF_XT);
  float* xcat = (float*)(ws + OFF_XCAT);
  float* wt1 = (float*)(ws + OFF_WT1); float* wd1 = (float*)(ws + OFF_WD1);
  float* wt2 = (float*)(ws + OFF_WT2); float* wd2 = (float*)(ws + OFF_WD2);
  float* wt3 = (float*)(ws + OFF_WT3); float* wd3 = (float*)(ws + OFF_WD3);
  float* wt4 = (float*)(ws + OFF_WT4); float* wd4 = (float*)(ws + OFF_WD4);
  float* wt5 = (float*)(ws + OFF_WT5);
  float* hmax = (float*)(ws + OFF_HMAX);
  float* hmin = (float*)(ws + OFF_HMIN);
  __hip_bfloat16* h5 = (__hip_bfloat16*)(ws + OFF_HMAX);  // reuse (edge bufs dead)
  float* part = (float*)(ws + OFF_PART);
  float* ssb  = (float*)(ws + OFF_SS);
  float* z    = (float*)(ws + OFF_Z);
  float* z1p  = (float*)(ws + OFF_Z1P);
  float* z1   = (float*)(ws + OFF_Z1);
  float* z2p  = (float*)(ws + OFF_Z2P);
  float* z2   = (float*)(ws + OFF_Z2);

  const float invE = 1.f / (float)(BN * NK);   // edge BN count
  const float inv5 = 1.f / (float)(BN);        // conv5 BN count

  k_transpose_x<<<(NB * 3 * NP + 255) / 256, 256, 0, stream>>>(x, xt);
  k_prep_w<<<(3 * 64 + 255) / 256, 256, 0, stream>>>(W1, wt1, wd1, 3, 64);
  k_prep_w<<<(64 * 64 + 255) / 256, 256, 0, stream>>>(W2, wt2, wd2, 64, 64);
  k_prep_w<<<(64 * 128 + 255) / 256, 256, 0, stream>>>(W3, wt3, wd3, 64, 128);
  k_prep_w<<<(128 * 256 + 255) / 256, 256, 0, stream>>>(W4, wt4, wd4, 128, 256);
  k_tr_w5<<<(512 * 1024) / 256, 256, 0, stream>>>(W5, wt5);
  k_topk<<<BN, 256, 0, stream>>>(geod, idx);

  // layer 1: C=3 (xt, stride 3) -> xcat[:,0:64]
  k_edge<3, 64><<<2048, 256, 0, stream>>>(xt, 0, 3, idx, wt1, wd1, hmax, hmin, part, 2);
  k_finalize<<<64, 256, 0, stream>>>(part, 2048, 64, invE, g1, bt1, ssb);
  k_edge_apply<<<(BN * 64) / 256, 256, 0, stream>>>(hmax, hmin, ssb, xcat, 64, 0);
  // layer 2: C=64 (xcat off 0) -> xcat[:,64:128]
  k_edge<64, 64><<<2048, 256, 0, stream>>>(xcat, 0, SROW, idx, wt2, wd2, hmax, hmin, part, 2);
  k_finalize<<<64, 256, 0, stream>>>(part, 2048, 64, invE, g2, bt2, ssb);
  k_edge_apply<<<(BN * 64) / 256, 256, 0, stream>>>(hmax, hmin, ssb, xcat, 64, 64);
  // layer 3: C=64 (off 64) -> xcat[:,128:256]
  k_edge<64, 128><<<2048, 256, 0, stream>>>(xcat, 64, SROW, idx, wt3, wd3, hmax, hmin, part, 4);
  k_finalize<<<128, 256, 0, stream>>>(part, 2048, 128, invE, g3, bt3, ssb);
  k_edge_apply<<<(BN * 128) / 256, 256, 0, stream>>>(hmax, hmin, ssb, xcat, 128, 128);
  // layer 4: C=128 (off 128) -> xcat[:,256:512]
  k_edge<128, 256><<<2048, 256, 0, stream>>>(xcat, 128, SROW, idx, wt4, wd4, hmax, hmin, part, 8);
  k_finalize<<<256, 256, 0, stream>>>(part, 2048, 256, invE, g4, bt4, ssb);
  k_edge_apply<<<(BN * 256) / 256, 256, 0, stream>>>(hmax, hmin, ssb, xcat, 256, 256);

  // conv5
  k_conv5<<<1024, 256, 0, stream>>>(xcat, wt5, h5, part);
  k_finalize<<<1024, 256, 0, stream>>>(part, 1024, 1024, inv5, g5, bt5, ssb);
  k_pool5<<<32, 256, 0, stream>>>(h5, part, ssb, z);

  // FC head
  k_fc<<<NB * 512, 64, 0, stream>>>(z, L1, nullptr, z1p, 2048, 512);
  k_bn_fc<<<2, 256, 0, stream>>>(z1p, g6, bt6, z1, 512);
  k_fc<<<NB * 256, 64, 0, stream>>>(z1, L2, bl2, z2p, 512, 256);
  k_bn_fc<<<1, 256, 0, stream>>>(z2p, g7, bt7, z2, 256);
  k_fc<<<NB * 40, 64, 0, stream>>>(z2, L3, bl3, (float*)d_out, 256, 40);
}

// Round 3
// 524.493 us; speedup vs baseline: 3.4314x; 3.4314x over previous
//
#include <hip/hip_runtime.h>
#include <hip/hip_bf16.h>
#include <cstdint>
#include <cstddef>

// Problem constants
#define NB 8
#define NP 2048
#define NK 20
#define BN 16384      // NB*NP

typedef _Float16 half8 __attribute__((ext_vector_type(8)));
typedef float f32x4 __attribute__((ext_vector_type(4)));

__device__ __forceinline__ void gload_lds16(const void* g, void* l) {
  __builtin_amdgcn_global_load_lds(
      (const __attribute__((address_space(1))) unsigned int*)g,
      (__attribute__((address_space(3))) unsigned int*)l, 16, 0, 0);
}

// ---------------- workspace layout (bytes) ----------------
static constexpr size_t OFF_IDX   = 0;                                // int[BN*20]
static constexpr size_t OFF_XT    = OFF_IDX + (size_t)BN*NK*4;        // f32[BN*3]
static constexpr size_t OFF_XCATH = OFF_XT + (size_t)BN*3*4;          // f16[BN*512]
static constexpr size_t OFF_WT1   = OFF_XCATH + (size_t)BN*512*2;
static constexpr size_t OFF_WD1   = OFF_WT1 + 3*64*4;
static constexpr size_t OFF_B2    = OFF_WD1 + 3*64*4;                 // f16[128*64]
static constexpr size_t OFF_B3    = OFF_B2 + (size_t)128*64*2;        // f16[128*128]
static constexpr size_t OFF_B4    = OFF_B3 + (size_t)128*128*2;       // f16[256*256]
static constexpr size_t OFF_B5    = OFF_B4 + (size_t)256*256*2;       // f16[512*1024]
static constexpr size_t OFF_HMAX  = OFF_B5 + (size_t)512*1024*2;      // f32[BN*256]
static constexpr size_t OFF_HMIN  = OFF_HMAX + (size_t)BN*256*4;      // f32[BN*256]
static constexpr size_t OFF_H5    = OFF_HMAX;                         // f16[BN*1024] overlay (edge bufs dead)
static constexpr size_t OFF_PART  = OFF_HMIN + (size_t)BN*256*4;      // 4 MB partials
static constexpr size_t OFF_PMEAN = OFF_PART + (size_t)4*1024*1024;   // f32[8*8*1024]
static constexpr size_t OFF_SS    = OFF_PMEAN + (size_t)8*8*1024*4;   // f32[2*1024]
static constexpr size_t OFF_Z     = OFF_SS + 2*1024*4;                // f32[8*2048]
static constexpr size_t OFF_Z1P   = OFF_Z + (size_t)NB*2048*4;
static constexpr size_t OFF_Z1    = OFF_Z1P + NB*512*4;
static constexpr size_t OFF_Z2P   = OFF_Z1 + NB*512*4;
static constexpr size_t OFF_Z2    = OFF_Z2P + NB*256*4;
// total ~58 MB

// ---------------- small prep kernels ----------------

__global__ void k_transpose_x(const float* __restrict__ x, float* __restrict__ xt) {
  int t = blockIdx.x * 256 + threadIdx.x;
  if (t >= NB * 3 * NP) return;
  int n = t & (NP - 1);
  int c = (t / NP) % 3;
  int b = t / (3 * NP);
  xt[(size_t)(b * NP + n) * 3 + c] = x[t];
}

__global__ void k_prep_w(const float* __restrict__ W, float* __restrict__ Wt,
                         float* __restrict__ Wd, int C, int O) {
  int t = blockIdx.x * 256 + threadIdx.x;
  if (t >= C * O) return;
  int o = t % O, c = t / O;
  float w0 = W[o * 2 * C + c];
  float w1 = W[o * 2 * C + C + c];
  Wt[t] = w0;
  Wd[t] = w1 - w0;
}

// Pack weights into exact b-fragment order for mfma_f32_16x16x32_f16.
// K2 = K dimension of GEMM; CSPLIT>0: concat form, B[k] = W[k] (k<C) or W[k]-W[k-C].
// b-frag: lane l, elem e reads B[64*ch + 32*ks + 8*(l>>4)+e][16*sl + (l&15)].
template <int K2, int O, int CSPLIT>
__global__ void k_prep_b(const float* __restrict__ W, _Float16* __restrict__ Bp) {
  int t = blockIdx.x * 256 + threadIdx.x;
  if (t >= K2 * O) return;
  int o = t % O, k = t / O;
  float v = W[(size_t)o * K2 + k];
  if (CSPLIT > 0 && k >= CSPLIT) v -= W[(size_t)o * K2 + k - CSPLIT];
  int ch = k >> 6, ks = (k >> 5) & 1, kg = (k >> 3) & 3, e = k & 7;
  int sl = o >> 4, ol = o & 15;
  size_t flat = (((size_t)(ch * 2 + ks) * (O / 16) + sl) * 64 + (kg * 16 + ol)) * 8 + e;
  Bp[flat] = (_Float16)v;
}

// top-20 per row of 2048, lowest-index tie-break (matches jax.lax.top_k)
__global__ __launch_bounds__(256) void k_topk(const float* __restrict__ geod,
                                              int* __restrict__ idx) {
  int row = blockIdx.x;
  const float* g = geod + (size_t)row * NP;
  int tid = threadIdx.x;
  float v[8];
#pragma unroll
  for (int r = 0; r < 8; ++r) v[r] = g[tid + 256 * r];
  __shared__ float s_v[4];
  __shared__ int s_i[4];
  __shared__ int s_win;
  for (int it = 0; it < NK; ++it) {
    float bv = -__builtin_huge_valf();
    int bi = 1 << 30;
#pragma unroll
    for (int r = 0; r < 8; ++r) {
      if (v[r] > bv) { bv = v[r]; bi = tid + 256 * r; }
    }
#pragma unroll
    for (int s = 32; s; s >>= 1) {
      float ov = __shfl_xor(bv, s);
      int   oi = __shfl_xor(bi, s);
      if (ov > bv || (ov == bv && oi < bi)) { bv = ov; bi = oi; }
    }
    int w = tid >> 6;
    if ((tid & 63) == 0) { s_v[w] = bv; s_i[w] = bi; }
    __syncthreads();
    if (tid == 0) {
      float fbv = s_v[0]; int fbi = s_i[0];
#pragma unroll
      for (int ww = 1; ww < 4; ++ww)
        if (s_v[ww] > fbv || (s_v[ww] == fbv && s_i[ww] < fbi)) { fbv = s_v[ww]; fbi = s_i[ww]; }
      s_win = fbi;
      idx[(size_t)row * NK + it] = fbi;
    }
    __syncthreads();
    int win = s_win;
    if ((win & 255) == tid) v[win >> 8] = -__builtin_huge_valf();
  }
}

// ---------------- layer-1 EdgeConv (C=3, fp32 VALU) ----------------
template <int C, int O>
__global__ __launch_bounds__(256) void k_edge(
    const float* __restrict__ xin, int in_off, int in_stride,
    const int* __restrict__ idx,
    const float* __restrict__ Wt, const float* __restrict__ Wd,
    float* __restrict__ hmax, float* __restrict__ hmin,
    float* __restrict__ part, int ngrp) {
  constexpr int PIF = 256 / O;
  __shared__ __align__(16) float lds[PIF * 21 * C];
  __shared__ int lidx[PIF * NK];
  __shared__ float red[256];
  int tid = threadIdx.x;
  int g = tid / O, o = tid % O;
  float ps = 0.f, ps2 = 0.f;
  for (int it = 0; it < ngrp; ++it) {
    int grp = blockIdx.x * ngrp + it;
    int p0 = grp * PIF;
    for (int u = tid; u < PIF * NK; u += 256) lidx[u] = idx[(size_t)p0 * NK + u];
    __syncthreads();
    for (int u = tid; u < PIF * 21 * C; u += 256) {
      int pp  = u / (21 * C);
      int rem = u - pp * 21 * C;
      int j   = rem / C;
      int c   = rem - j * C;
      int p   = p0 + pp;
      int bbase = p & ~(NP - 1);
      int srcn = (j == 20) ? p : (bbase + lidx[pp * NK + j]);
      lds[u] = xin[(size_t)srcn * in_stride + in_off + c];
    }
    __syncthreads();
    const float* xl = &lds[g * 21 * C];
    float base = 0.f;
    for (int c = 0; c < C; ++c) base += xl[20 * C + c] * Wd[c * O + o];
    float h[NK];
#pragma unroll
    for (int j = 0; j < NK; ++j) h[j] = base;
    for (int c = 0; c < C; ++c) {
      float w = Wt[c * O + o];
#pragma unroll
      for (int j = 0; j < NK; ++j) h[j] += xl[j * C + c] * w;
    }
    float mx = h[0], mn = h[0];
#pragma unroll
    for (int j = 0; j < NK; ++j) {
      mx = fmaxf(mx, h[j]); mn = fminf(mn, h[j]);
      ps += h[j]; ps2 += h[j] * h[j];
    }
    int p = p0 + g;
    hmax[(size_t)p * O + o] = mx;
    hmin[(size_t)p * O + o] = mn;
    __syncthreads();
  }
  red[tid] = ps;
  __syncthreads();
  if (tid < O) {
    float a = red[tid];
#pragma unroll
    for (int g2 = 1; g2 < PIF; ++g2) a += red[g2 * O + tid];
    part[(size_t)blockIdx.x * O + tid] = a;
  }
  __syncthreads();
  red[tid] = ps2;
  __syncthreads();
  if (tid < O) {
    float a = red[tid];
#pragma unroll
    for (int g2 = 1; g2 < PIF; ++g2) a += red[g2 * O + tid];
    part[((size_t)gridDim.x + blockIdx.x) * O + tid] = a;
  }
}

// ---------------- MFMA EdgeConv (layers 2-4) ----------------
// A-row r (0..79 within 80-row wave group) -> point pp=(r>>2)&3, j=4*(r>>4)+(r&3):
// each lane's C-fragment then holds all 20 j of a single point -> lane-local max.
// A-row = concat(xh[nbr], xh[self]) so K2 = 2C; B pre-packed in frag order.
template <int C, int O, int NSPLIT>
__global__ __launch_bounds__(256) void k_edge_mfma(
    const _Float16* __restrict__ xh, int in_off,
    const int* __restrict__ idx,
    const _Float16* __restrict__ Bp,
    float* __restrict__ hmax, float* __restrict__ hmin,
    float* __restrict__ part) {
  constexpr int K2 = 2 * C;
  constexpr int NCH = K2 / 64;       // 64-wide K chunks
  constexpr int NO = O / NSPLIT;     // columns handled by this block
  constexpr int NSLO = NO / 16;      // 16-col slices in block
  constexpr int NS = NSLO / 2;       // slices per wave (2 ng-groups)
  constexpr int PAIRS = 2 * NSLO;    // (ks, slice) B sub-tiles per chunk
  __shared__ __align__(16) _Float16 ldsA[160 * 64];   // 20KB, XOR-swizzled
  __shared__ __align__(16) _Float16 ldsB[PAIRS * 512];
  __shared__ float ldsS[2][NO], ldsQ[2][NO];
  int tid = threadIdx.x, wv = tid >> 6, l = tid & 63;
  int mblk = blockIdx.x, nid = 0;
  if (NSPLIT > 1) { nid = mblk >> 11; mblk &= 2047; }
  int p0 = mblk * 8;                 // 8 points per block
  int bbase = p0 & ~(NP - 1);
  int n_base = nid * NO;
  int mg = wv & 1, ng = wv >> 1;
  f32x4 acc[5][NS];
#pragma unroll
  for (int m = 0; m < 5; ++m)
#pragma unroll
    for (int s = 0; s < NS; ++s)
#pragma unroll
      for (int r = 0; r < 4; ++r) acc[m][s][r] = 0.f;

  for (int ch = 0; ch < NCH; ++ch) {
    int cbase = ch * 64;
    // stage A: wave stages rows [40*wv, 40*wv+40), 8 rows (1024B) per issue.
    // source pre-swizzled: lane slot (l&7) holds source 16B-segment q=(l&7)^(l>>3).
#pragma unroll
    for (int it = 0; it < 5; ++it) {
      int r0 = wv * 40 + it * 8;
      int R = r0 + (l >> 3);
      int mgR = R / 80;
      int r = R - mgR * 80;
      int pp = 4 * mgR + ((r >> 2) & 3);
      int j = ((r >> 4) << 2) | (r & 3);
      int p = p0 + pp;
      int srcn, col0;
      if (cbase < C) { srcn = bbase + idx[p * NK + j]; col0 = in_off + cbase; }
      else           { srcn = p;                       col0 = in_off + cbase - C; }
      int q = (l & 7) ^ (l >> 3);
      gload_lds16(xh + (size_t)srcn * 512 + col0 + q * 8, ldsA + r0 * 64);
    }
    // stage B chunk (already in frag order)
    for (int u = wv; u < PAIRS; u += 4) {
      int ks = u / NSLO, sloc = u - ks * NSLO;
      gload_lds16(Bp + ((size_t)((ch * 2 + ks) * (O / 16) + (n_base >> 4) + sloc) * 64 + l) * 8,
                  ldsB + u * 512);
    }
    __syncthreads();
#pragma unroll
    for (int ks = 0; ks < 2; ++ks) {
      half8 b[NS];
#pragma unroll
      for (int s = 0; s < NS; ++s)
        b[s] = *(const half8*)(ldsB + (ks * NSLO + ng * NS + s) * 512 + l * 8);
#pragma unroll
      for (int mt = 0; mt < 5; ++mt) {
        int row = mg * 80 + mt * 16 + (l & 15);
        int slot = (ks * 4 + (l >> 4)) ^ (row & 7);
        half8 a = *(const half8*)(ldsA + row * 64 + slot * 8);
#pragma unroll
        for (int s = 0; s < NS; ++s)
          acc[mt][s] = __builtin_amdgcn_mfma_f32_16x16x32_f16(a, b[s], acc[mt][s], 0, 0, 0);
      }
    }
    __syncthreads();
  }
  // epilogue: lane-local j-max/min per point; cross-lane only for BN stats
  int g = l >> 4;
  int p = p0 + 4 * mg + g;
#pragma unroll
  for (int s = 0; s < NS; ++s) {
    float mx = -3.4e38f, mn = 3.4e38f, sm = 0.f, sq = 0.f;
#pragma unroll
    for (int mt = 0; mt < 5; ++mt)
#pragma unroll
      for (int r = 0; r < 4; ++r) {
        float v = acc[mt][s][r];
        mx = fmaxf(mx, v); mn = fminf(mn, v); sm += v; sq += v * v;
      }
    int colL = ng * (NS * 16) + s * 16 + (l & 15);
    hmax[(size_t)p * O + n_base + colL] = mx;
    hmin[(size_t)p * O + n_base + colL] = mn;
    sm += __shfl_xor(sm, 16); sm += __shfl_xor(sm, 32);
    sq += __shfl_xor(sq, 16); sq += __shfl_xor(sq, 32);
    if (l < 16) {
      ldsS[mg][ng * (NS * 16) + s * 16 + l] = sm;
      ldsQ[mg][ng * (NS * 16) + s * 16 + l] = sq;
    }
  }
  __syncthreads();
  for (int u = tid; u < NO; u += 256) {
    part[(size_t)mblk * O + n_base + u] = ldsS[0][u] + ldsS[1][u];
    part[((size_t)2048 + mblk) * O + n_base + u] = ldsQ[0][u] + ldsQ[1][u];
  }
}

// ---------------- conv5 MFMA: h5 = xcatH(16384x512) * B5(512x1024) ----------------
__global__ __launch_bounds__(256) void k_conv5_mfma(
    const _Float16* __restrict__ xh, const _Float16* __restrict__ Bp,
    _Float16* __restrict__ h5, float* __restrict__ part) {
  __shared__ __align__(16) _Float16 ldsA[64 * 64];     // 8KB
  __shared__ __align__(16) _Float16 ldsB[32 * 512];    // 32KB
  __shared__ float ldsS[2][256], ldsQ[2][256], ldsMx[2][256], ldsMn[2][256];
  int tid = threadIdx.x, wv = tid >> 6, l = tid & 63;
  int mblk = blockIdx.x & 255, nid = blockIdx.x >> 8;
  int m0 = mblk * 64;
  int n_base = nid * 256;
  int mg = wv & 1, ng = wv >> 1;
  f32x4 acc[2][8];
#pragma unroll
  for (int m = 0; m < 2; ++m)
#pragma unroll
    for (int s = 0; s < 8; ++s)
#pragma unroll
      for (int r = 0; r < 4; ++r) acc[m][s][r] = 0.f;

  for (int ch = 0; ch < 8; ++ch) {
#pragma unroll
    for (int it = 0; it < 2; ++it) {
      int r0 = wv * 16 + it * 8;
      int R = r0 + (l >> 3);
      int q = (l & 7) ^ (l >> 3);
      gload_lds16(xh + (size_t)(m0 + R) * 512 + ch * 64 + q * 8, ldsA + r0 * 64);
    }
    for (int u = wv; u < 32; u += 4) {
      int ks = u >> 4, sloc = u & 15;
      gload_lds16(Bp + ((size_t)((ch * 2 + ks) * 64 + (n_base >> 4) + sloc) * 64 + l) * 8,
                  ldsB + u * 512);
    }
    __syncthreads();
#pragma unroll
    for (int ks = 0; ks < 2; ++ks) {
      half8 b[8];
#pragma unroll
      for (int s = 0; s < 8; ++s)
        b[s] = *(const half8*)(ldsB + (ks * 16 + ng * 8 + s) * 512 + l * 8);
#pragma unroll
      for (int mt = 0; mt < 2; ++mt) {
        int row = mg * 32 + mt * 16 + (l & 15);
        int slot = (ks * 4 + (l >> 4)) ^ (row & 7);
        half8 a = *(const half8*)(ldsA + row * 64 + slot * 8);
#pragma unroll
        for (int s = 0; s < 8; ++s)
          acc[mt][s] = __builtin_amdgcn_mfma_f32_16x16x32_f16(a, b[s], acc[mt][s], 0, 0, 0);
      }
    }
    __syncthreads();
  }
  int g = l >> 4;
#pragma unroll
  for (int s = 0; s < 8; ++s) {
    float sm = 0.f, sq = 0.f, mx = -3.4e38f, mn = 3.4e38f;
    int col = n_base + ng * 128 + s * 16 + (l & 15);
#pragma unroll
    for (int mt = 0; mt < 2; ++mt)
#pragma unroll
      for (int r = 0; r < 4; ++r) {
        float v = acc[mt][s][r];
        int row = m0 + mg * 32 + mt * 16 + 4 * g + r;
        h5[(size_t)row * 1024 + col] = (_Float16)v;
        sm += v; sq += v * v; mx = fmaxf(mx, v); mn = fminf(mn, v);
      }
    sm += __shfl_xor(sm, 16); sm += __shfl_xor(sm, 32);
    sq += __shfl_xor(sq, 16); sq += __shfl_xor(sq, 32);
    mx = fmaxf(mx, __shfl_xor(mx, 16)); mx = fmaxf(mx, __shfl_xor(mx, 32));
    mn = fminf(mn, __shfl_xor(mn, 16)); mn = fminf(mn, __shfl_xor(mn, 32));
    if (l < 16) {
      int u = ng * 128 + s * 16 + l;
      ldsS[mg][u] = sm; ldsQ[mg][u] = sq; ldsMx[mg][u] = mx; ldsMn[mg][u] = mn;
    }
  }
  __syncthreads();
  {
    int u = tid;
    int col = n_base + u;
    part[(size_t)mblk * 1024 + col] = ldsS[0][u] + ldsS[1][u];
    part[((size_t)256 + mblk) * 1024 + col] = ldsQ[0][u] + ldsQ[1][u];
    part[((size_t)512 + mblk) * 1024 + col] = fmaxf(ldsMx[0][u], ldsMx[1][u]);
    part[((size_t)768 + mblk) * 1024 + col] = fminf(ldsMn[0][u], ldsMn[1][u]);
  }
}

// reduce partials -> per-channel BN scale/shift. grid = O blocks.
__global__ __launch_bounds__(256) void k_finalize(
    const float* __restrict__ part, int G, int O, float inv_count,
    const float* __restrict__ gamma, const float* __restrict__ beta,
    float* __restrict__ ss) {
  int o = blockIdx.x;
  float s = 0.f, s2 = 0.f;
  for (int g = threadIdx.x; g < G; g += 256) {
    s  += part[(size_t)g * O + o];
    s2 += part[((size_t)G + g) * O + o];
  }
#pragma unroll
  for (int sft = 32; sft; sft >>= 1) {
    s  += __shfl_down(s, sft);
    s2 += __shfl_down(s2, sft);
  }
  __shared__ float aw[4], aw2[4];
  int w = threadIdx.x >> 6;
  if ((threadIdx.x & 63) == 0) { aw[w] = s; aw2[w] = s2; }
  __syncthreads();
  if (threadIdx.x == 0) {
    s = aw[0] + aw[1] + aw[2] + aw[3];
    s2 = aw2[0] + aw2[1] + aw2[2] + aw2[3];
    float m   = s * inv_count;
    float var = s2 * inv_count - m * m;
    float scale = gamma[o] * rsqrtf(var + 1e-5f);
    ss[o]     = scale;
    ss[O + o] = beta[o] - m * scale;
  }
}

// apply BN+lrelu to (max or min per sign of scale), write fp16 into xcatH slice
__global__ void k_edge_apply(const float* __restrict__ hmax, const float* __restrict__ hmin,
                             const float* __restrict__ ss, _Float16* __restrict__ xh,
                             int O, int off) {
  int t = blockIdx.x * 256 + threadIdx.x;
  int o = t % O;
  int p = t / O;
  float scale = ss[o], shift = ss[O + o];
  float v = (scale >= 0.f) ? hmax[t] : hmin[t];
  v = scale * v + shift;
  v = (v >= 0.f) ? v : 0.2f * v;
  xh[(size_t)p * 512 + off + o] = (_Float16)v;
}

// conv5 mean-pool partials: grid = 8b*8ns*4cg = 256 blocks
__global__ __launch_bounds__(256) void k_pool5a(const _Float16* __restrict__ h5,
                                                const float* __restrict__ ss,
                                                float* __restrict__ pmean) {
  int bi = blockIdx.x;
  int b = bi >> 5, ns = (bi >> 2) & 7, cg = bi & 3;
  int col = cg * 256 + threadIdx.x;
  float scale = ss[col], shift = ss[1024 + col];
  float sm = 0.f;
  for (int n = ns * 256; n < ns * 256 + 256; ++n) {
    float v = (float)h5[(size_t)(b * 2048 + n) * 1024 + col];
    float y = scale * v + shift;
    y = (y >= 0.f) ? y : 0.2f * y;
    sm += y;
  }
  pmean[(size_t)(b * 8 + ns) * 1024 + col] = sm;
}

// final pool: exact max via fp32 partials (BN+lrelu commute), mean via pmean
__global__ __launch_bounds__(256) void k_pool5b(const float* __restrict__ part,
                                                const float* __restrict__ pmean,
                                                const float* __restrict__ ss,
                                                float* __restrict__ z) {
  int bi = blockIdx.x;
  int b = bi >> 2, cg = bi & 3;
  int col = cg * 256 + threadIdx.x;
  float scale = ss[col], shift = ss[1024 + col];
  const float* pmx = part + (size_t)512 * 1024;
  const float* pmn = part + (size_t)768 * 1024;
  float mxh = -3.4e38f, mnh = 3.4e38f;
  for (int q = 0; q < 32; ++q) {
    size_t base = (size_t)(b * 32 + q) * 1024 + col;
    mxh = fmaxf(mxh, pmx[base]);
    mnh = fminf(mnh, pmn[base]);
  }
  float hsel = (scale >= 0.f) ? mxh : mnh;
  float zmax = scale * hsel + shift;
  zmax = (zmax >= 0.f) ? zmax : 0.2f * zmax;
  float sm = 0.f;
  for (int ns = 0; ns < 8; ++ns) sm += pmean[(size_t)(b * 8 + ns) * 1024 + col];
  z[b * 2048 + col] = zmax;
  z[b * 2048 + 1024 + col] = sm * (1.f / 2048.f);
}

// generic FC: one wave per (b,o)
__global__ __launch_bounds__(64) void k_fc(const float* __restrict__ in,
                                           const float* __restrict__ Wf,
                                           const float* __restrict__ bias,
                                           float* __restrict__ out, int IN, int O) {
  int blk = blockIdx.x;
  int b = blk / O, o = blk % O;
  const float* a = in + (size_t)b * IN;
  const float* w = Wf + (size_t)o * IN;
  float s = 0.f;
  for (int i = threadIdx.x; i < IN; i += 64) s += a[i] * w[i];
#pragma unroll
  for (int sft = 32; sft; sft >>= 1) s += __shfl_down(s, sft);
  if (threadIdx.x == 0) out[(size_t)b * O + o] = s + (bias ? bias[o] : 0.f);
}

// batch-axis BN (count=8) + lrelu
__global__ void k_bn_fc(const float* __restrict__ pre, const float* __restrict__ gamma,
                        const float* __restrict__ beta, float* __restrict__ out, int O) {
  int o = blockIdx.x * 256 + threadIdx.x;
  if (o >= O) return;
  float v[NB];
  float s = 0.f, s2 = 0.f;
#pragma unroll
  for (int b = 0; b < NB; ++b) {
    v[b] = pre[(size_t)b * O + o];
    s += v[b]; s2 += v[b] * v[b];
  }
  float m = s * (1.f / NB);
  float var = s2 * (1.f / NB) - m * m;
  float scale = gamma[o] * rsqrtf(var + 1e-5f);
  float shift = beta[o] - m * scale;
#pragma unroll
  for (int b = 0; b < NB; ++b) {
    float x = scale * v[b] + shift;
    out[(size_t)b * O + o] = (x >= 0.f) ? x : 0.2f * x;
  }
}

// ---------------- launcher ----------------
extern "C" void kernel_launch(void* const* d_in, const int* in_sizes, int n_in,
                              void* d_out, int out_size, void* d_ws, size_t ws_size,
                              hipStream_t stream) {
  (void)in_sizes; (void)n_in; (void)out_size; (void)ws_size;
  const float* x    = (const float*)d_in[0];
  const float* geod = (const float*)d_in[1];
  const float* W1   = (const float*)d_in[2];
  const float* g1   = (const float*)d_in[3];
  const float* bt1  = (const float*)d_in[4];
  const float* W2   = (const float*)d_in[5];
  const float* g2   = (const float*)d_in[6];
  const float* bt2  = (const float*)d_in[7];
  const float* W3   = (const float*)d_in[8];
  const float* g3   = (const float*)d_in[9];
  const float* bt3  = (const float*)d_in[10];
  const float* W4   = (const float*)d_in[11];
  const float* g4   = (const float*)d_in[12];
  const float* bt4  = (const float*)d_in[13];
  const float* W5   = (const float*)d_in[14];
  const float* g5   = (const float*)d_in[15];
  const float* bt5  = (const float*)d_in[16];
  const float* L1   = (const float*)d_in[17];
  const float* g6   = (const float*)d_in[18];
  const float* bt6  = (const float*)d_in[19];
  const float* L2   = (const float*)d_in[20];
  const float* bl2  = (const float*)d_in[21];
  const float* g7   = (const float*)d_in[22];
  const float* bt7  = (const float*)d_in[23];
  const float* L3   = (const float*)d_in[24];
  const float* bl3  = (const float*)d_in[25];

  char* ws = (char*)d_ws;
  int*       idx   = (int*)(ws + OFF_IDX);
  float*     xt    = (float*)(ws + OFF_XT);
  _Float16*  xcatH = (_Float16*)(ws + OFF_XCATH);
  float*     wt1   = (float*)(ws + OFF_WT1);
  float*     wd1   = (float*)(ws + OFF_WD1);
  _Float16*  b2    = (_Float16*)(ws + OFF_B2);
  _Float16*  b3    = (_Float16*)(ws + OFF_B3);
  _Float16*  b4    = (_Float16*)(ws + OFF_B4);
  _Float16*  b5    = (_Float16*)(ws + OFF_B5);
  float*     hmax  = (float*)(ws + OFF_HMAX);
  float*     hmin  = (float*)(ws + OFF_HMIN);
  _Float16*  h5    = (_Float16*)(ws + OFF_H5);
  float*     part  = (float*)(ws + OFF_PART);
  float*     pmean = (float*)(ws + OFF_PMEAN);
  float*     ssb   = (float*)(ws + OFF_SS);
  float*     z     = (float*)(ws + OFF_Z);
  float*     z1p   = (float*)(ws + OFF_Z1P);
  float*     z1    = (float*)(ws + OFF_Z1);
  float*     z2p   = (float*)(ws + OFF_Z2P);
  float*     z2    = (float*)(ws + OFF_Z2);

  const float invE = 1.f / (float)(BN * NK);
  const float inv5 = 1.f / (float)(BN);

  k_transpose_x<<<(NB * 3 * NP + 255) / 256, 256, 0, stream>>>(x, xt);
  k_prep_w<<<1, 256, 0, stream>>>(W1, wt1, wd1, 3, 64);
  k_prep_b<128, 64, 64><<<32, 256, 0, stream>>>(W2, b2);
  k_prep_b<128, 128, 64><<<64, 256, 0, stream>>>(W3, b3);
  k_prep_b<256, 256, 128><<<256, 256, 0, stream>>>(W4, b4);
  k_prep_b<512, 1024, 0><<<2048, 256, 0, stream>>>(W5, b5);
  k_topk<<<BN, 256, 0, stream>>>(geod, idx);

  // layer 1 (C=3, fp32)
  k_edge<3, 64><<<2048, 256, 0, stream>>>(xt, 0, 3, idx, wt1, wd1, hmax, hmin, part, 2);
  k_finalize<<<64, 256, 0, stream>>>(part, 2048, 64, invE, g1, bt1, ssb);
  k_edge_apply<<<(BN * 64) / 256, 256, 0, stream>>>(hmax, hmin, ssb, xcatH, 64, 0);
  // layer 2 (C=64 -> O=64), input slice 0
  k_edge_mfma<64, 64, 1><<<2048, 256, 0, stream>>>(xcatH, 0, idx, b2, hmax, hmin, part);
  k_finalize<<<64, 256, 0, stream>>>(part, 2048, 64, invE, g2, bt2, ssb);
  k_edge_apply<<<(BN * 64) / 256, 256, 0, stream>>>(hmax, hmin, ssb, xcatH, 64, 64);
  // layer 3 (C=64 -> O=128), input slice 64
  k_edge_mfma<64, 128, 1><<<2048, 256, 0, stream>>>(xcatH, 64, idx, b3, hmax, hmin, part);
  k_finalize<<<128, 256, 0, stream>>>(part, 2048, 128, invE, g3, bt3, ssb);
  k_edge_apply<<<(BN * 128) / 256, 256, 0, stream>>>(hmax, hmin, ssb, xcatH, 128, 128);
  // layer 4 (C=128 -> O=256), input slice 128, N split in 2
  k_edge_mfma<128, 256, 2><<<4096, 256, 0, stream>>>(xcatH, 128, idx, b4, hmax, hmin, part);
  k_finalize<<<256, 256, 0, stream>>>(part, 2048, 256, invE, g4, bt4, ssb);
  k_edge_apply<<<(BN * 256) / 256, 256, 0, stream>>>(hmax, hmin, ssb, xcatH, 256, 256);

  // conv5 (16384x512 @ 512x1024)
  k_conv5_mfma<<<1024, 256, 0, stream>>>(xcatH, b5, h5, part);
  k_finalize<<<1024, 256, 0, stream>>>(part, 256, 1024, inv5, g5, bt5, ssb);
  k_pool5a<<<256, 256, 0, stream>>>(h5, ssb, pmean);
  k_pool5b<<<32, 256, 0, stream>>>(part, pmean, ssb, z);

  // FC head
  k_fc<<<NB * 512, 64, 0, stream>>>(z, L1, nullptr, z1p, 2048, 512);
  k_bn_fc<<<2, 256, 0, stream>>>(z1p, g6, bt6, z1, 512);
  k_fc<<<NB * 256, 64, 0, stream>>>(z1, L2, bl2, z2p, 512, 256);
  k_bn_fc<<<1, 256, 0, stream>>>(z2p, g7, bt7, z2, 256);
  k_fc<<<NB * 40, 64, 0, stream>>>(z2, L3, bl3, (float*)d_out, 256, 40);
}

// Round 4
// 358.132 us; speedup vs baseline: 5.0253x; 1.4645x over previous
//
#include <hip/hip_runtime.h>
#include <hip/hip_bf16.h>
#include <cstdint>
#include <cstddef>

// Problem constants
#define NB 8
#define NP 2048
#define NK 20
#define BN 16384      // NB*NP

typedef _Float16 half8 __attribute__((ext_vector_type(8)));
typedef float f32x4 __attribute__((ext_vector_type(4)));

__device__ __forceinline__ void gload_lds16(const void* g, void* l) {
  __builtin_amdgcn_global_load_lds(
      (const __attribute__((address_space(1))) unsigned int*)g,
      (__attribute__((address_space(3))) unsigned int*)l, 16, 0, 0);
}

// ---------------- workspace layout (bytes) ----------------
static constexpr size_t OFF_IDX   = 0;                                // int[BN*20]
static constexpr size_t OFF_XT    = OFF_IDX + (size_t)BN*NK*4;        // f32[BN*3]
static constexpr size_t OFF_XCATH = OFF_XT + (size_t)BN*3*4;          // f16[BN*512]
static constexpr size_t OFF_WT1   = OFF_XCATH + (size_t)BN*512*2;
static constexpr size_t OFF_WD1   = OFF_WT1 + 3*64*4;
static constexpr size_t OFF_B2    = OFF_WD1 + 3*64*4;                 // f16[128*64]
static constexpr size_t OFF_B3    = OFF_B2 + (size_t)128*64*2;        // f16[128*128]
static constexpr size_t OFF_B4    = OFF_B3 + (size_t)128*128*2;       // f16[256*256]
static constexpr size_t OFF_B5    = OFF_B4 + (size_t)256*256*2;       // f16[512*1024]
static constexpr size_t OFF_HMAX  = OFF_B5 + (size_t)512*1024*2;      // f32[BN*256]
static constexpr size_t OFF_HMIN  = OFF_HMAX + (size_t)BN*256*4;      // f32[BN*256]
static constexpr size_t OFF_H5    = OFF_HMAX;                         // f16[BN*1024] overlay (edge bufs dead)
static constexpr size_t OFF_PART  = OFF_HMIN + (size_t)BN*256*4;      // 4 MB partials
static constexpr size_t OFF_PMEAN = OFF_PART + (size_t)4*1024*1024;   // f32[8*8*1024]
static constexpr size_t OFF_SS    = OFF_PMEAN + (size_t)8*8*1024*4;   // f32[2*1024]
static constexpr size_t OFF_Z     = OFF_SS + 2*1024*4;                // f32[8*2048]
static constexpr size_t OFF_Z1P   = OFF_Z + (size_t)NB*2048*4;
static constexpr size_t OFF_Z1    = OFF_Z1P + NB*512*4;
static constexpr size_t OFF_Z2P   = OFF_Z1 + NB*512*4;
static constexpr size_t OFF_Z2    = OFF_Z2P + NB*256*4;
// total ~58 MB

// ---------------- small prep kernels ----------------

__global__ void k_transpose_x(const float* __restrict__ x, float* __restrict__ xt) {
  int t = blockIdx.x * 256 + threadIdx.x;
  if (t >= NB * 3 * NP) return;
  int n = t & (NP - 1);
  int c = (t / NP) % 3;
  int b = t / (3 * NP);
  xt[(size_t)(b * NP + n) * 3 + c] = x[t];
}

__global__ void k_prep_w(const float* __restrict__ W, float* __restrict__ Wt,
                         float* __restrict__ Wd, int C, int O) {
  int t = blockIdx.x * 256 + threadIdx.x;
  if (t >= C * O) return;
  int o = t % O, c = t / O;
  float w0 = W[o * 2 * C + c];
  float w1 = W[o * 2 * C + C + c];
  Wt[t] = w0;
  Wd[t] = w1 - w0;
}

// Pack weights into exact b-fragment order for mfma_f32_16x16x32_f16.
// K2 = K dimension of GEMM; CSPLIT>0: concat form, B[k] = W[k] (k<C) or W[k]-W[k-C].
// b-frag: lane l, elem e reads B[64*ch + 32*ks + 8*(l>>4)+e][16*sl + (l&15)].
template <int K2, int O, int CSPLIT>
__global__ void k_prep_b(const float* __restrict__ W, _Float16* __restrict__ Bp) {
  int t = blockIdx.x * 256 + threadIdx.x;
  if (t >= K2 * O) return;
  int o = t % O, k = t / O;
  float v = W[(size_t)o * K2 + k];
  if (CSPLIT > 0 && k >= CSPLIT) v -= W[(size_t)o * K2 + k - CSPLIT];
  int ch = k >> 6, ks = (k >> 5) & 1, kg = (k >> 3) & 3, e = k & 7;
  int sl = o >> 4, ol = o & 15;
  size_t flat = (((size_t)(ch * 2 + ks) * (O / 16) + sl) * 64 + (kg * 16 + ol)) * 8 + e;
  Bp[flat] = (_Float16)v;
}

// top-20 per row of 2048, lowest-index tie-break (matches jax.lax.top_k).
// One wave per row: 32 elems/lane in registers, barrier-free shuffle argmax;
// only the winning lane invalidates (compile-time indices) and rescans.
__global__ __launch_bounds__(256) void k_topk(const float* __restrict__ geod,
                                              int* __restrict__ idx) {
  int wv = threadIdx.x >> 6, l = threadIdx.x & 63;
  int row = blockIdx.x * 4 + wv;
  const float* g = geod + (size_t)row * NP;
  float4 v[8];
#pragma unroll
  for (int r = 0; r < 8; ++r) v[r] = *(const float4*)&g[r * 256 + l * 4];
  const float NEG = -__builtin_huge_valf();
  float bv = NEG; int bi = 0;
#pragma unroll
  for (int r = 0; r < 8; ++r) {
    if (v[r].x > bv) { bv = v[r].x; bi = r * 256 + l * 4 + 0; }
    if (v[r].y > bv) { bv = v[r].y; bi = r * 256 + l * 4 + 1; }
    if (v[r].z > bv) { bv = v[r].z; bi = r * 256 + l * 4 + 2; }
    if (v[r].w > bv) { bv = v[r].w; bi = r * 256 + l * 4 + 3; }
  }
  for (int it = 0; it < NK; ++it) {
    float cv = bv; int ci = bi;
#pragma unroll
    for (int s = 1; s < 64; s <<= 1) {
      float ov = __shfl_xor(cv, s);
      int   oi = __shfl_xor(ci, s);
      if (ov > cv || (ov == cv && oi < ci)) { cv = ov; ci = oi; }
    }
    if (l == 0) idx[(size_t)row * NK + it] = ci;
    if (((ci >> 2) & 63) == l) {          // winner lane only
      int wr = ci >> 8, we = ci & 3;
#pragma unroll
      for (int r = 0; r < 8; ++r) {
        if (r == wr) {
          if (we == 0) v[r].x = NEG;
          if (we == 1) v[r].y = NEG;
          if (we == 2) v[r].z = NEG;
          if (we == 3) v[r].w = NEG;
        }
      }
      bv = NEG; bi = 0;
#pragma unroll
      for (int r = 0; r < 8; ++r) {
        if (v[r].x > bv) { bv = v[r].x; bi = r * 256 + l * 4 + 0; }
        if (v[r].y > bv) { bv = v[r].y; bi = r * 256 + l * 4 + 1; }
        if (v[r].z > bv) { bv = v[r].z; bi = r * 256 + l * 4 + 2; }
        if (v[r].w > bv) { bv = v[r].w; bi = r * 256 + l * 4 + 3; }
      }
    }
  }
}

// ---------------- layer-1 EdgeConv (C=3, fp32 VALU) ----------------
template <int C, int O>
__global__ __launch_bounds__(256) void k_edge(
    const float* __restrict__ xin, int in_off, int in_stride,
    const int* __restrict__ idx,
    const float* __restrict__ Wt, const float* __restrict__ Wd,
    float* __restrict__ hmax, float* __restrict__ hmin,
    float* __restrict__ part, int ngrp) {
  constexpr int PIF = 256 / O;
  __shared__ __align__(16) float lds[PIF * 21 * C];
  __shared__ int lidx[PIF * NK];
  __shared__ float red[256];
  int tid = threadIdx.x;
  int g = tid / O, o = tid % O;
  float ps = 0.f, ps2 = 0.f;
  for (int it = 0; it < ngrp; ++it) {
    int grp = blockIdx.x * ngrp + it;
    int p0 = grp * PIF;
    for (int u = tid; u < PIF * NK; u += 256) lidx[u] = idx[(size_t)p0 * NK + u];
    __syncthreads();
    for (int u = tid; u < PIF * 21 * C; u += 256) {
      int pp  = u / (21 * C);
      int rem = u - pp * 21 * C;
      int j   = rem / C;
      int c   = rem - j * C;
      int p   = p0 + pp;
      int bbase = p & ~(NP - 1);
      int srcn = (j == 20) ? p : (bbase + lidx[pp * NK + j]);
      lds[u] = xin[(size_t)srcn * in_stride + in_off + c];
    }
    __syncthreads();
    const float* xl = &lds[g * 21 * C];
    float base = 0.f;
    for (int c = 0; c < C; ++c) base += xl[20 * C + c] * Wd[c * O + o];
    float h[NK];
#pragma unroll
    for (int j = 0; j < NK; ++j) h[j] = base;
    for (int c = 0; c < C; ++c) {
      float w = Wt[c * O + o];
#pragma unroll
      for (int j = 0; j < NK; ++j) h[j] += xl[j * C + c] * w;
    }
    float mx = h[0], mn = h[0];
#pragma unroll
    for (int j = 0; j < NK; ++j) {
      mx = fmaxf(mx, h[j]); mn = fminf(mn, h[j]);
      ps += h[j]; ps2 += h[j] * h[j];
    }
    int p = p0 + g;
    hmax[(size_t)p * O + o] = mx;
    hmin[(size_t)p * O + o] = mn;
    __syncthreads();
  }
  red[tid] = ps;
  __syncthreads();
  if (tid < O) {
    float a = red[tid];
#pragma unroll
    for (int g2 = 1; g2 < PIF; ++g2) a += red[g2 * O + tid];
    part[(size_t)blockIdx.x * O + tid] = a;
  }
  __syncthreads();
  red[tid] = ps2;
  __syncthreads();
  if (tid < O) {
    float a = red[tid];
#pragma unroll
    for (int g2 = 1; g2 < PIF; ++g2) a += red[g2 * O + tid];
    part[((size_t)gridDim.x + blockIdx.x) * O + tid] = a;
  }
}

// ---------------- MFMA EdgeConv (layers 2-4) ----------------
// A-row r (0..79 within 80-row wave group) -> point pp=(r>>2)&3, j=4*(r>>4)+(r&3):
// each lane's C-fragment then holds all 20 j of a single point -> lane-local max.
// A-row = concat(xh[nbr], xh[self]) so K2 = 2C; B pre-packed in frag order.
template <int C, int O, int NSPLIT>
__global__ __launch_bounds__(256) void k_edge_mfma(
    const _Float16* __restrict__ xh, int in_off,
    const int* __restrict__ idx,
    const _Float16* __restrict__ Bp,
    float* __restrict__ hmax, float* __restrict__ hmin,
    float* __restrict__ part) {
  constexpr int K2 = 2 * C;
  constexpr int NCH = K2 / 64;       // 64-wide K chunks
  constexpr int NO = O / NSPLIT;     // columns handled by this block
  constexpr int NSLO = NO / 16;      // 16-col slices in block
  constexpr int NS = NSLO / 2;       // slices per wave (2 ng-groups)
  constexpr int PAIRS = 2 * NSLO;    // (ks, slice) B sub-tiles per chunk
  __shared__ __align__(16) _Float16 ldsA[160 * 64];   // 20KB, XOR-swizzled
  __shared__ __align__(16) _Float16 ldsB[PAIRS * 512];
  __shared__ float ldsS[2][NO], ldsQ[2][NO];
  int tid = threadIdx.x, wv = tid >> 6, l = tid & 63;
  int mblk = blockIdx.x, nid = 0;
  if (NSPLIT > 1) { nid = mblk >> 11; mblk &= 2047; }
  int p0 = mblk * 8;                 // 8 points per block
  int bbase = p0 & ~(NP - 1);
  int n_base = nid * NO;
  int mg = wv & 1, ng = wv >> 1;
  f32x4 acc[5][NS];
#pragma unroll
  for (int m = 0; m < 5; ++m)
#pragma unroll
    for (int s = 0; s < NS; ++s)
#pragma unroll
      for (int r = 0; r < 4; ++r) acc[m][s][r] = 0.f;

  for (int ch = 0; ch < NCH; ++ch) {
    int cbase = ch * 64;
    // stage A: wave stages rows [40*wv, 40*wv+40), 8 rows (1024B) per issue.
    // source pre-swizzled: lane slot (l&7) holds source 16B-segment q=(l&7)^(l>>3).
#pragma unroll
    for (int it = 0; it < 5; ++it) {
      int r0 = wv * 40 + it * 8;
      int R = r0 + (l >> 3);
      int mgR = R / 80;
      int r = R - mgR * 80;
      int pp = 4 * mgR + ((r >> 2) & 3);
      int j = ((r >> 4) << 2) | (r & 3);
      int p = p0 + pp;
      int srcn, col0;
      if (cbase < C) { srcn = bbase + idx[p * NK + j]; col0 = in_off + cbase; }
      else           { srcn = p;                       col0 = in_off + cbase - C; }
      int q = (l & 7) ^ (l >> 3);
      gload_lds16(xh + (size_t)srcn * 512 + col0 + q * 8, ldsA + r0 * 64);
    }
    // stage B chunk (already in frag order)
    for (int u = wv; u < PAIRS; u += 4) {
      int ks = u / NSLO, sloc = u - ks * NSLO;
      gload_lds16(Bp + ((size_t)((ch * 2 + ks) * (O / 16) + (n_base >> 4) + sloc) * 64 + l) * 8,
                  ldsB + u * 512);
    }
    __syncthreads();
#pragma unroll
    for (int ks = 0; ks < 2; ++ks) {
      half8 b[NS];
#pragma unroll
      for (int s = 0; s < NS; ++s)
        b[s] = *(const half8*)(ldsB + (ks * NSLO + ng * NS + s) * 512 + l * 8);
#pragma unroll
      for (int mt = 0; mt < 5; ++mt) {
        int row = mg * 80 + mt * 16 + (l & 15);
        int slot = (ks * 4 + (l >> 4)) ^ (row & 7);
        half8 a = *(const half8*)(ldsA + row * 64 + slot * 8);
#pragma unroll
        for (int s = 0; s < NS; ++s)
          acc[mt][s] = __builtin_amdgcn_mfma_f32_16x16x32_f16(a, b[s], acc[mt][s], 0, 0, 0);
      }
    }
    __syncthreads();
  }
  // epilogue: lane-local j-max/min per point; cross-lane only for BN stats
  int g = l >> 4;
  int p = p0 + 4 * mg + g;
#pragma unroll
  for (int s = 0; s < NS; ++s) {
    float mx = -3.4e38f, mn = 3.4e38f, sm = 0.f, sq = 0.f;
#pragma unroll
    for (int mt = 0; mt < 5; ++mt)
#pragma unroll
      for (int r = 0; r < 4; ++r) {
        float v = acc[mt][s][r];
        mx = fmaxf(mx, v); mn = fminf(mn, v); sm += v; sq += v * v;
      }
    int colL = ng * (NS * 16) + s * 16 + (l & 15);
    hmax[(size_t)p * O + n_base + colL] = mx;
    hmin[(size_t)p * O + n_base + colL] = mn;
    sm += __shfl_xor(sm, 16); sm += __shfl_xor(sm, 32);
    sq += __shfl_xor(sq, 16); sq += __shfl_xor(sq, 32);
    if (l < 16) {
      ldsS[mg][ng * (NS * 16) + s * 16 + l] = sm;
      ldsQ[mg][ng * (NS * 16) + s * 16 + l] = sq;
    }
  }
  __syncthreads();
  for (int u = tid; u < NO; u += 256) {
    part[(size_t)mblk * O + n_base + u] = ldsS[0][u] + ldsS[1][u];
    part[((size_t)2048 + mblk) * O + n_base + u] = ldsQ[0][u] + ldsQ[1][u];
  }
}

// ---------------- conv5 MFMA: h5 = xcatH(16384x512) * B5(512x1024) ----------------
__global__ __launch_bounds__(256) void k_conv5_mfma(
    const _Float16* __restrict__ xh, const _Float16* __restrict__ Bp,
    _Float16* __restrict__ h5, float* __restrict__ part) {
  __shared__ __align__(16) _Float16 ldsA[64 * 64];     // 8KB
  __shared__ __align__(16) _Float16 ldsB[32 * 512];    // 32KB
  __shared__ float ldsS[2][256], ldsQ[2][256], ldsMx[2][256], ldsMn[2][256];
  int tid = threadIdx.x, wv = tid >> 6, l = tid & 63;
  int mblk = blockIdx.x & 255, nid = blockIdx.x >> 8;
  int m0 = mblk * 64;
  int n_base = nid * 256;
  int mg = wv & 1, ng = wv >> 1;
  f32x4 acc[2][8];
#pragma unroll
  for (int m = 0; m < 2; ++m)
#pragma unroll
    for (int s = 0; s < 8; ++s)
#pragma unroll
      for (int r = 0; r < 4; ++r) acc[m][s][r] = 0.f;

  for (int ch = 0; ch < 8; ++ch) {
#pragma unroll
    for (int it = 0; it < 2; ++it) {
      int r0 = wv * 16 + it * 8;
      int R = r0 + (l >> 3);
      int q = (l & 7) ^ (l >> 3);
      gload_lds16(xh + (size_t)(m0 + R) * 512 + ch * 64 + q * 8, ldsA + r0 * 64);
    }
    for (int u = wv; u < 32; u += 4) {
      int ks = u >> 4, sloc = u & 15;
      gload_lds16(Bp + ((size_t)((ch * 2 + ks) * 64 + (n_base >> 4) + sloc) * 64 + l) * 8,
                  ldsB + u * 512);
    }
    __syncthreads();
#pragma unroll
    for (int ks = 0; ks < 2; ++ks) {
      half8 b[8];
#pragma unroll
      for (int s = 0; s < 8; ++s)
        b[s] = *(const half8*)(ldsB + (ks * 16 + ng * 8 + s) * 512 + l * 8);
#pragma unroll
      for (int mt = 0; mt < 2; ++mt) {
        int row = mg * 32 + mt * 16 + (l & 15);
        int slot = (ks * 4 + (l >> 4)) ^ (row & 7);
        half8 a = *(const half8*)(ldsA + row * 64 + slot * 8);
#pragma unroll
        for (int s = 0; s < 8; ++s)
          acc[mt][s] = __builtin_amdgcn_mfma_f32_16x16x32_f16(a, b[s], acc[mt][s], 0, 0, 0);
      }
    }
    __syncthreads();
  }
  int g = l >> 4;
#pragma unroll
  for (int s = 0; s < 8; ++s) {
    float sm = 0.f, sq = 0.f, mx = -3.4e38f, mn = 3.4e38f;
    int col = n_base + ng * 128 + s * 16 + (l & 15);
#pragma unroll
    for (int mt = 0; mt < 2; ++mt)
#pragma unroll
      for (int r = 0; r < 4; ++r) {
        float v = acc[mt][s][r];
        int row = m0 + mg * 32 + mt * 16 + 4 * g + r;
        h5[(size_t)row * 1024 + col] = (_Float16)v;
        sm += v; sq += v * v; mx = fmaxf(mx, v); mn = fminf(mn, v);
      }
    sm += __shfl_xor(sm, 16); sm += __shfl_xor(sm, 32);
    sq += __shfl_xor(sq, 16); sq += __shfl_xor(sq, 32);
    mx = fmaxf(mx, __shfl_xor(mx, 16)); mx = fmaxf(mx, __shfl_xor(mx, 32));
    mn = fminf(mn, __shfl_xor(mn, 16)); mn = fminf(mn, __shfl_xor(mn, 32));
    if (l < 16) {
      int u = ng * 128 + s * 16 + l;
      ldsS[mg][u] = sm; ldsQ[mg][u] = sq; ldsMx[mg][u] = mx; ldsMn[mg][u] = mn;
    }
  }
  __syncthreads();
  {
    int u = tid;
    int col = n_base + u;
    part[(size_t)mblk * 1024 + col] = ldsS[0][u] + ldsS[1][u];
    part[((size_t)256 + mblk) * 1024 + col] = ldsQ[0][u] + ldsQ[1][u];
    part[((size_t)512 + mblk) * 1024 + col] = fmaxf(ldsMx[0][u], ldsMx[1][u]);
    part[((size_t)768 + mblk) * 1024 + col] = fminf(ldsMn[0][u], ldsMn[1][u]);
  }
}

// reduce partials -> per-channel BN scale/shift. grid = O blocks.
__global__ __launch_bounds__(256) void k_finalize(
    const float* __restrict__ part, int G, int O, float inv_count,
    const float* __restrict__ gamma, const float* __restrict__ beta,
    float* __restrict__ ss) {
  int o = blockIdx.x;
  float s = 0.f, s2 = 0.f;
  for (int g = threadIdx.x; g < G; g += 256) {
    s  += part[(size_t)g * O + o];
    s2 += part[((size_t)G + g) * O + o];
  }
#pragma unroll
  for (int sft = 32; sft; sft >>= 1) {
    s  += __shfl_down(s, sft);
    s2 += __shfl_down(s2, sft);
  }
  __shared__ float aw[4], aw2[4];
  int w = threadIdx.x >> 6;
  if ((threadIdx.x & 63) == 0) { aw[w] = s; aw2[w] = s2; }
  __syncthreads();
  if (threadIdx.x == 0) {
    s = aw[0] + aw[1] + aw[2] + aw[3];
    s2 = aw2[0] + aw2[1] + aw2[2] + aw2[3];
    float m   = s * inv_count;
    float var = s2 * inv_count - m * m;
    float scale = gamma[o] * rsqrtf(var + 1e-5f);
    ss[o]     = scale;
    ss[O + o] = beta[o] - m * scale;
  }
}

// apply BN+lrelu to (max or min per sign of scale), write fp16 into xcatH slice
__global__ void k_edge_apply(const float* __restrict__ hmax, const float* __restrict__ hmin,
                             const float* __restrict__ ss, _Float16* __restrict__ xh,
                             int O, int off) {
  int t = blockIdx.x * 256 + threadIdx.x;
  int o = t % O;
  int p = t / O;
  float scale = ss[o], shift = ss[O + o];
  float v = (scale >= 0.f) ? hmax[t] : hmin[t];
  v = scale * v + shift;
  v = (v >= 0.f) ? v : 0.2f * v;
  xh[(size_t)p * 512 + off + o] = (_Float16)v;
}

// conv5 mean-pool partials: grid = 8b*8ns*4cg = 256 blocks
__global__ __launch_bounds__(256) void k_pool5a(const _Float16* __restrict__ h5,
                                                const float* __restrict__ ss,
                                                float* __restrict__ pmean) {
  int bi = blockIdx.x;
  int b = bi >> 5, ns = (bi >> 2) & 7, cg = bi & 3;
  int col = cg * 256 + threadIdx.x;
  float scale = ss[col], shift = ss[1024 + col];
  float sm = 0.f;
  for (int n = ns * 256; n < ns * 256 + 256; ++n) {
    float v = (float)h5[(size_t)(b * 2048 + n) * 1024 + col];
    float y = scale * v + shift;
    y = (y >= 0.f) ? y : 0.2f * y;
    sm += y;
  }
  pmean[(size_t)(b * 8 + ns) * 1024 + col] = sm;
}

// final pool: exact max via fp32 partials (BN+lrelu commute), mean via pmean
__global__ __launch_bounds__(256) void k_pool5b(const float* __restrict__ part,
                                                const float* __restrict__ pmean,
                                                const float* __restrict__ ss,
                                                float* __restrict__ z) {
  int bi = blockIdx.x;
  int b = bi >> 2, cg = bi & 3;
  int col = cg * 256 + threadIdx.x;
  float scale = ss[col], shift = ss[1024 + col];
  const float* pmx = part + (size_t)512 * 1024;
  const float* pmn = part + (size_t)768 * 1024;
  float mxh = -3.4e38f, mnh = 3.4e38f;
  for (int q = 0; q < 32; ++q) {
    size_t base = (size_t)(b * 32 + q) * 1024 + col;
    mxh = fmaxf(mxh, pmx[base]);
    mnh = fminf(mnh, pmn[base]);
  }
  float hsel = (scale >= 0.f) ? mxh : mnh;
  float zmax = scale * hsel + shift;
  zmax = (zmax >= 0.f) ? zmax : 0.2f * zmax;
  float sm = 0.f;
  for (int ns = 0; ns < 8; ++ns) sm += pmean[(size_t)(b * 8 + ns) * 1024 + col];
  z[b * 2048 + col] = zmax;
  z[b * 2048 + 1024 + col] = sm * (1.f / 2048.f);
}

// generic FC: one wave per (b,o)
__global__ __launch_bounds__(64) void k_fc(const float* __restrict__ in,
                                           const float* __restrict__ Wf,
                                           const float* __restrict__ bias,
                                           float* __restrict__ out, int IN, int O) {
  int blk = blockIdx.x;
  int b = blk / O, o = blk % O;
  const float* a = in + (size_t)b * IN;
  const float* w = Wf + (size_t)o * IN;
  float s = 0.f;
  for (int i = threadIdx.x; i < IN; i += 64) s += a[i] * w[i];
#pragma unroll
  for (int sft = 32; sft; sft >>= 1) s += __shfl_down(s, sft);
  if (threadIdx.x == 0) out[(size_t)b * O + o] = s + (bias ? bias[o] : 0.f);
}

// batch-axis BN (count=8) + lrelu
__global__ void k_bn_fc(const float* __restrict__ pre, const float* __restrict__ gamma,
                        const float* __restrict__ beta, float* __restrict__ out, int O) {
  int o = blockIdx.x * 256 + threadIdx.x;
  if (o >= O) return;
  float v[NB];
  float s = 0.f, s2 = 0.f;
#pragma unroll
  for (int b = 0; b < NB; ++b) {
    v[b] = pre[(size_t)b * O + o];
    s += v[b]; s2 += v[b] * v[b];
  }
  float m = s * (1.f / NB);
  float var = s2 * (1.f / NB) - m * m;
  float scale = gamma[o] * rsqrtf(var + 1e-5f);
  float shift = beta[o] - m * scale;
#pragma unroll
  for (int b = 0; b < NB; ++b) {
    float x = scale * v[b] + shift;
    out[(size_t)b * O + o] = (x >= 0.f) ? x : 0.2f * x;
  }
}

// ---------------- launcher ----------------
extern "C" void kernel_launch(void* const* d_in, const int* in_sizes, int n_in,
                              void* d_out, int out_size, void* d_ws, size_t ws_size,
                              hipStream_t stream) {
  (void)in_sizes; (void)n_in; (void)out_size; (void)ws_size;
  const float* x    = (const float*)d_in[0];
  const float* geod = (const float*)d_in[1];
  const float* W1   = (const float*)d_in[2];
  const float* g1   = (const float*)d_in[3];
  const float* bt1  = (const float*)d_in[4];
  const float* W2   = (const float*)d_in[5];
  const float* g2   = (const float*)d_in[6];
  const float* bt2  = (const float*)d_in[7];
  const float* W3   = (const float*)d_in[8];
  const float* g3   = (const float*)d_in[9];
  const float* bt3  = (const float*)d_in[10];
  const float* W4   = (const float*)d_in[11];
  const float* g4   = (const float*)d_in[12];
  const float* bt4  = (const float*)d_in[13];
  const float* W5   = (const float*)d_in[14];
  const float* g5   = (const float*)d_in[15];
  const float* bt5  = (const float*)d_in[16];
  const float* L1   = (const float*)d_in[17];
  const float* g6   = (const float*)d_in[18];
  const float* bt6  = (const float*)d_in[19];
  const float* L2   = (const float*)d_in[20];
  const float* bl2  = (const float*)d_in[21];
  const float* g7   = (const float*)d_in[22];
  const float* bt7  = (const float*)d_in[23];
  const float* L3   = (const float*)d_in[24];
  const float* bl3  = (const float*)d_in[25];

  char* ws = (char*)d_ws;
  int*       idx   = (int*)(ws + OFF_IDX);
  float*     xt    = (float*)(ws + OFF_XT);
  _Float16*  xcatH = (_Float16*)(ws + OFF_XCATH);
  float*     wt1   = (float*)(ws + OFF_WT1);
  float*     wd1   = (float*)(ws + OFF_WD1);
  _Float16*  b2    = (_Float16*)(ws + OFF_B2);
  _Float16*  b3    = (_Float16*)(ws + OFF_B3);
  _Float16*  b4    = (_Float16*)(ws + OFF_B4);
  _Float16*  b5    = (_Float16*)(ws + OFF_B5);
  float*     hmax  = (float*)(ws + OFF_HMAX);
  float*     hmin  = (float*)(ws + OFF_HMIN);
  _Float16*  h5    = (_Float16*)(ws + OFF_H5);
  float*     part  = (float*)(ws + OFF_PART);
  float*     pmean = (float*)(ws + OFF_PMEAN);
  float*     ssb   = (float*)(ws + OFF_SS);
  float*     z     = (float*)(ws + OFF_Z);
  float*     z1p   = (float*)(ws + OFF_Z1P);
  float*     z1    = (float*)(ws + OFF_Z1);
  float*     z2p   = (float*)(ws + OFF_Z2P);
  float*     z2    = (float*)(ws + OFF_Z2);

  const float invE = 1.f / (float)(BN * NK);
  const float inv5 = 1.f / (float)(BN);

  k_transpose_x<<<(NB * 3 * NP + 255) / 256, 256, 0, stream>>>(x, xt);
  k_prep_w<<<1, 256, 0, stream>>>(W1, wt1, wd1, 3, 64);
  k_prep_b<128, 64, 64><<<32, 256, 0, stream>>>(W2, b2);
  k_prep_b<128, 128, 64><<<64, 256, 0, stream>>>(W3, b3);
  k_prep_b<256, 256, 128><<<256, 256, 0, stream>>>(W4, b4);
  k_prep_b<512, 1024, 0><<<2048, 256, 0, stream>>>(W5, b5);
  k_topk<<<BN / 4, 256, 0, stream>>>(geod, idx);

  // layer 1 (C=3, fp32)
  k_edge<3, 64><<<2048, 256, 0, stream>>>(xt, 0, 3, idx, wt1, wd1, hmax, hmin, part, 2);
  k_finalize<<<64, 256, 0, stream>>>(part, 2048, 64, invE, g1, bt1, ssb);
  k_edge_apply<<<(BN * 64) / 256, 256, 0, stream>>>(hmax, hmin, ssb, xcatH, 64, 0);
  // layer 2 (C=64 -> O=64), input slice 0
  k_edge_mfma<64, 64, 1><<<2048, 256, 0, stream>>>(xcatH, 0, idx, b2, hmax, hmin, part);
  k_finalize<<<64, 256, 0, stream>>>(part, 2048, 64, invE, g2, bt2, ssb);
  k_edge_apply<<<(BN * 64) / 256, 256, 0, stream>>>(hmax, hmin, ssb, xcatH, 64, 64);
  // layer 3 (C=64 -> O=128), input slice 64
  k_edge_mfma<64, 128, 1><<<2048, 256, 0, stream>>>(xcatH, 64, idx, b3, hmax, hmin, part);
  k_finalize<<<128, 256, 0, stream>>>(part, 2048, 128, invE, g3, bt3, ssb);
  k_edge_apply<<<(BN * 128) / 256, 256, 0, stream>>>(hmax, hmin, ssb, xcatH, 128, 128);
  // layer 4 (C=128 -> O=256), input slice 128, N split in 2
  k_edge_mfma<128, 256, 2><<<4096, 256, 0, stream>>>(xcatH, 128, idx, b4, hmax, hmin, part);
  k_finalize<<<256, 256, 0, stream>>>(part, 2048, 256, invE, g4, bt4, ssb);
  k_edge_apply<<<(BN * 256) / 256, 256, 0, stream>>>(hmax, hmin, ssb, xcatH, 256, 256);

  // conv5 (16384x512 @ 512x1024)
  k_conv5_mfma<<<1024, 256, 0, stream>>>(xcatH, b5, h5, part);
  k_finalize<<<1024, 256, 0, stream>>>(part, 256, 1024, inv5, g5, bt5, ssb);
  k_pool5a<<<256, 256, 0, stream>>>(h5, ssb, pmean);
  k_pool5b<<<32, 256, 0, stream>>>(part, pmean, ssb, z);

  // FC head
  k_fc<<<NB * 512, 64, 0, stream>>>(z, L1, nullptr, z1p, 2048, 512);
  k_bn_fc<<<2, 256, 0, stream>>>(z1p, g6, bt6, z1, 512);
  k_fc<<<NB * 256, 64, 0, stream>>>(z1, L2, bl2, z2p, 512, 256);
  k_bn_fc<<<1, 256, 0, stream>>>(z2p, g7, bt7, z2, 256);
  k_fc<<<NB * 40, 64, 0, stream>>>(z2, L3, bl3, (float*)d_out, 256, 40);
}

// Round 5
// 318.957 us; speedup vs baseline: 5.6426x; 1.1228x over previous
//
#include <hip/hip_runtime.h>
#include <hip/hip_bf16.h>
#include <cstdint>
#include <cstddef>

// Problem constants
#define NB 8
#define NP 2048
#define NK 20
#define BN 16384      // NB*NP

typedef _Float16 half8 __attribute__((ext_vector_type(8)));
typedef float f32x4 __attribute__((ext_vector_type(4)));

__device__ __forceinline__ void gload_lds16(const void* g, void* l) {
  __builtin_amdgcn_global_load_lds(
      (const __attribute__((address_space(1))) unsigned int*)g,
      (__attribute__((address_space(3))) unsigned int*)l, 16, 0, 0);
}

// ---------------- workspace layout (bytes) ----------------
static constexpr size_t OFF_IDX   = 0;                                // int[BN*20]
static constexpr size_t OFF_XT    = OFF_IDX + (size_t)BN*NK*4;        // f32[BN*3]
static constexpr size_t OFF_XCATH = OFF_XT + (size_t)BN*3*4;          // f16[BN*512]
static constexpr size_t OFF_WT1   = OFF_XCATH + (size_t)BN*512*2;
static constexpr size_t OFF_WD1   = OFF_WT1 + 3*64*4;
static constexpr size_t OFF_B2    = OFF_WD1 + 3*64*4;                 // f16[128*64]
static constexpr size_t OFF_B3    = OFF_B2 + (size_t)128*64*2;        // f16[128*128]
static constexpr size_t OFF_B4    = OFF_B3 + (size_t)128*128*2;       // f16[256*256]
static constexpr size_t OFF_B5    = OFF_B4 + (size_t)256*256*2;       // f16[512*1024]
static constexpr size_t OFF_HMAX  = OFF_B5 + (size_t)512*1024*2;      // f32[BN*256]
static constexpr size_t OFF_HMIN  = OFF_HMAX + (size_t)BN*256*4;      // f32[BN*256]
static constexpr size_t OFF_H5    = OFF_HMAX;                         // f16[BN*1024] overlay (edge bufs dead)
static constexpr size_t OFF_PART  = OFF_HMIN + (size_t)BN*256*4;      // 4 MB partials
static constexpr size_t OFF_PMEAN = OFF_PART + (size_t)4*1024*1024;   // f32[8*8*1024]
static constexpr size_t OFF_SS    = OFF_PMEAN + (size_t)8*8*1024*4;   // f32[2*1024]
static constexpr size_t OFF_Z     = OFF_SS + 2*1024*4;                // f32[8*2048]
static constexpr size_t OFF_Z1P   = OFF_Z + (size_t)NB*2048*4;
static constexpr size_t OFF_Z1    = OFF_Z1P + NB*512*4;
static constexpr size_t OFF_Z2P   = OFF_Z1 + NB*512*4;
static constexpr size_t OFF_Z2    = OFF_Z2P + NB*256*4;
// total ~58 MB

// ---------------- small prep kernels ----------------

__global__ void k_transpose_x(const float* __restrict__ x, float* __restrict__ xt) {
  int t = blockIdx.x * 256 + threadIdx.x;
  if (t >= NB * 3 * NP) return;
  int n = t & (NP - 1);
  int c = (t / NP) % 3;
  int b = t / (3 * NP);
  xt[(size_t)(b * NP + n) * 3 + c] = x[t];
}

__global__ void k_prep_w(const float* __restrict__ W, float* __restrict__ Wt,
                         float* __restrict__ Wd, int C, int O) {
  int t = blockIdx.x * 256 + threadIdx.x;
  if (t >= C * O) return;
  int o = t % O, c = t / O;
  float w0 = W[o * 2 * C + c];
  float w1 = W[o * 2 * C + C + c];
  Wt[t] = w0;
  Wd[t] = w1 - w0;
}

// Pack weights into exact b-fragment order for mfma_f32_16x16x32_f16.
// K2 = K dimension of GEMM; CSPLIT>0: concat form, B[k] = W[k] (k<C) or W[k]-W[k-C].
// b-frag: lane l, elem e reads B[64*ch + 32*ks + 8*(l>>4)+e][16*sl + (l&15)].
template <int K2, int O, int CSPLIT>
__global__ void k_prep_b(const float* __restrict__ W, _Float16* __restrict__ Bp) {
  int t = blockIdx.x * 256 + threadIdx.x;
  if (t >= K2 * O) return;
  int o = t % O, k = t / O;
  float v = W[(size_t)o * K2 + k];
  if (CSPLIT > 0 && k >= CSPLIT) v -= W[(size_t)o * K2 + k - CSPLIT];
  int ch = k >> 6, ks = (k >> 5) & 1, kg = (k >> 3) & 3, e = k & 7;
  int sl = o >> 4, ol = o & 15;
  size_t flat = (((size_t)(ch * 2 + ks) * (O / 16) + sl) * 64 + (kg * 16 + ol)) * 8 + e;
  Bp[flat] = (_Float16)v;
}

// top-20 per row of 2048, lowest-index tie-break (matches jax.lax.top_k).
// One wave per row. Per iteration: value-only 6-step max butterfly (+v_max),
// ballot + scalar-pipe tie-break for the index; per-lane top-2 cache so the
// 32-element masked rescan only runs when a lane wins twice (rare).
__global__ __launch_bounds__(256) void k_topk(const float* __restrict__ geod,
                                              int* __restrict__ idx) {
  int wv = threadIdx.x >> 6, l = threadIdx.x & 63;
  int row = blockIdx.x * 4 + wv;
  const float* g = geod + (size_t)row * NP;
  float4 v[8];
#pragma unroll
  for (int r = 0; r < 8; ++r) v[r] = *(const float4*)&g[r * 256 + l * 4];
  const float NEG = -__builtin_huge_valf();
  unsigned int dead = 0;
  float m1 = NEG, m2 = NEG;
  int i1 = 0, i2 = 0;
  // initial top-2 scan: ascending index, strict > keeps lowest index
#pragma unroll
  for (int r = 0; r < 8; ++r) {
    float vals[4] = {v[r].x, v[r].y, v[r].z, v[r].w};
#pragma unroll
    for (int e = 0; e < 4; ++e) {
      float val = vals[e];
      int gi = r * 256 + l * 4 + e;
      if (val > m1) { m2 = m1; i2 = i1; m1 = val; i1 = gi; }
      else if (val > m2) { m2 = val; i2 = gi; }
    }
  }
  for (int it = 0; it < NK; ++it) {
    float cv = m1;
#pragma unroll
    for (int s = 1; s < 64; s <<= 1) cv = fmaxf(cv, __shfl_xor(cv, s));
    unsigned long long mask = __ballot(m1 == cv);
    int best_i = 1 << 30, best_l = 0;
    while (mask) {                       // wave-uniform scalar loop, typ. 1 iter
      int L = (int)__builtin_ctzll(mask);
      int ii = __builtin_amdgcn_readlane(i1, L);
      if (ii < best_i) { best_i = ii; best_l = L; }
      mask &= mask - 1;
    }
    if (l == 0) idx[(size_t)row * NK + it] = best_i;
    if (l == best_l) {
      dead |= 1u << (((best_i >> 8) << 2) | (best_i & 3));
      m1 = m2; i1 = i2; m2 = NEG; i2 = 0;
      if (m1 == NEG) {                   // cache exhausted: masked rescan
#pragma unroll
        for (int r = 0; r < 8; ++r) {
          float vals[4] = {v[r].x, v[r].y, v[r].z, v[r].w};
#pragma unroll
          for (int e = 0; e < 4; ++e) {
            int el = r * 4 + e;
            float val = ((dead >> el) & 1u) ? NEG : vals[e];
            int gi = r * 256 + l * 4 + e;
            if (val > m1) { m2 = m1; i2 = i1; m1 = val; i1 = gi; }
            else if (val > m2) { m2 = val; i2 = gi; }
          }
        }
      }
    }
  }
}

// ---------------- layer-1 EdgeConv (C=3, fp32 VALU) ----------------
template <int C, int O>
__global__ __launch_bounds__(256) void k_edge(
    const float* __restrict__ xin, int in_off, int in_stride,
    const int* __restrict__ idx,
    const float* __restrict__ Wt, const float* __restrict__ Wd,
    float* __restrict__ hmax, float* __restrict__ hmin,
    float* __restrict__ part, int ngrp) {
  constexpr int PIF = 256 / O;
  __shared__ __align__(16) float lds[PIF * 21 * C];
  __shared__ int lidx[PIF * NK];
  __shared__ float red[256];
  int tid = threadIdx.x;
  int g = tid / O, o = tid % O;
  float ps = 0.f, ps2 = 0.f;
  for (int it = 0; it < ngrp; ++it) {
    int grp = blockIdx.x * ngrp + it;
    int p0 = grp * PIF;
    for (int u = tid; u < PIF * NK; u += 256) lidx[u] = idx[(size_t)p0 * NK + u];
    __syncthreads();
    for (int u = tid; u < PIF * 21 * C; u += 256) {
      int pp  = u / (21 * C);
      int rem = u - pp * 21 * C;
      int j   = rem / C;
      int c   = rem - j * C;
      int p   = p0 + pp;
      int bbase = p & ~(NP - 1);
      int srcn = (j == 20) ? p : (bbase + lidx[pp * NK + j]);
      lds[u] = xin[(size_t)srcn * in_stride + in_off + c];
    }
    __syncthreads();
    const float* xl = &lds[g * 21 * C];
    float base = 0.f;
    for (int c = 0; c < C; ++c) base += xl[20 * C + c] * Wd[c * O + o];
    float h[NK];
#pragma unroll
    for (int j = 0; j < NK; ++j) h[j] = base;
    for (int c = 0; c < C; ++c) {
      float w = Wt[c * O + o];
#pragma unroll
      for (int j = 0; j < NK; ++j) h[j] += xl[j * C + c] * w;
    }
    float mx = h[0], mn = h[0];
#pragma unroll
    for (int j = 0; j < NK; ++j) {
      mx = fmaxf(mx, h[j]); mn = fminf(mn, h[j]);
      ps += h[j]; ps2 += h[j] * h[j];
    }
    int p = p0 + g;
    hmax[(size_t)p * O + o] = mx;
    hmin[(size_t)p * O + o] = mn;
    __syncthreads();
  }
  red[tid] = ps;
  __syncthreads();
  if (tid < O) {
    float a = red[tid];
#pragma unroll
    for (int g2 = 1; g2 < PIF; ++g2) a += red[g2 * O + tid];
    part[(size_t)blockIdx.x * O + tid] = a;
  }
  __syncthreads();
  red[tid] = ps2;
  __syncthreads();
  if (tid < O) {
    float a = red[tid];
#pragma unroll
    for (int g2 = 1; g2 < PIF; ++g2) a += red[g2 * O + tid];
    part[((size_t)gridDim.x + blockIdx.x) * O + tid] = a;
  }
}

// ---------------- MFMA EdgeConv (layers 2-4) ----------------
// A-row r (0..79 within 80-row wave group) -> point pp=(r>>2)&3, j=4*(r>>4)+(r&3):
// each lane's C-fragment then holds all 20 j of a single point -> lane-local max.
// A-row = concat(xh[nbr], xh[self]) so K2 = 2C; B pre-packed in frag order.
template <int C, int O, int NSPLIT>
__global__ __launch_bounds__(256) void k_edge_mfma(
    const _Float16* __restrict__ xh, int in_off,
    const int* __restrict__ idx,
    const _Float16* __restrict__ Bp,
    float* __restrict__ hmax, float* __restrict__ hmin,
    float* __restrict__ part) {
  constexpr int K2 = 2 * C;
  constexpr int NCH = K2 / 64;       // 64-wide K chunks
  constexpr int NO = O / NSPLIT;     // columns handled by this block
  constexpr int NSLO = NO / 16;      // 16-col slices in block
  constexpr int NS = NSLO / 2;       // slices per wave (2 ng-groups)
  constexpr int PAIRS = 2 * NSLO;    // (ks, slice) B sub-tiles per chunk
  __shared__ __align__(16) _Float16 ldsA[160 * 64];   // 20KB, XOR-swizzled
  __shared__ __align__(16) _Float16 ldsB[PAIRS * 512];
  __shared__ float ldsS[2][NO], ldsQ[2][NO];
  int tid = threadIdx.x, wv = tid >> 6, l = tid & 63;
  int mblk = blockIdx.x, nid = 0;
  if (NSPLIT > 1) { nid = mblk >> 11; mblk &= 2047; }
  int p0 = mblk * 8;                 // 8 points per block
  int bbase = p0 & ~(NP - 1);
  int n_base = nid * NO;
  int mg = wv & 1, ng = wv >> 1;
  f32x4 acc[5][NS];
#pragma unroll
  for (int m = 0; m < 5; ++m)
#pragma unroll
    for (int s = 0; s < NS; ++s)
#pragma unroll
      for (int r = 0; r < 4; ++r) acc[m][s][r] = 0.f;

  for (int ch = 0; ch < NCH; ++ch) {
    int cbase = ch * 64;
    // stage A: wave stages rows [40*wv, 40*wv+40), 8 rows (1024B) per issue.
    // source pre-swizzled: lane slot (l&7) holds source 16B-segment q=(l&7)^(l>>3).
#pragma unroll
    for (int it = 0; it < 5; ++it) {
      int r0 = wv * 40 + it * 8;
      int R = r0 + (l >> 3);
      int mgR = R / 80;
      int r = R - mgR * 80;
      int pp = 4 * mgR + ((r >> 2) & 3);
      int j = ((r >> 4) << 2) | (r & 3);
      int p = p0 + pp;
      int srcn, col0;
      if (cbase < C) { srcn = bbase + idx[p * NK + j]; col0 = in_off + cbase; }
      else           { srcn = p;                       col0 = in_off + cbase - C; }
      int q = (l & 7) ^ (l >> 3);
      gload_lds16(xh + (size_t)srcn * 512 + col0 + q * 8, ldsA + r0 * 64);
    }
    // stage B chunk (already in frag order)
    for (int u = wv; u < PAIRS; u += 4) {
      int ks = u / NSLO, sloc = u - ks * NSLO;
      gload_lds16(Bp + ((size_t)((ch * 2 + ks) * (O / 16) + (n_base >> 4) + sloc) * 64 + l) * 8,
                  ldsB + u * 512);
    }
    __syncthreads();
#pragma unroll
    for (int ks = 0; ks < 2; ++ks) {
      half8 b[NS];
#pragma unroll
      for (int s = 0; s < NS; ++s)
        b[s] = *(const half8*)(ldsB + (ks * NSLO + ng * NS + s) * 512 + l * 8);
#pragma unroll
      for (int mt = 0; mt < 5; ++mt) {
        int row = mg * 80 + mt * 16 + (l & 15);
        int slot = (ks * 4 + (l >> 4)) ^ (row & 7);
        half8 a = *(const half8*)(ldsA + row * 64 + slot * 8);
#pragma unroll
        for (int s = 0; s < NS; ++s)
          acc[mt][s] = __builtin_amdgcn_mfma_f32_16x16x32_f16(a, b[s], acc[mt][s], 0, 0, 0);
      }
    }
    __syncthreads();
  }
  // epilogue: lane-local j-max/min per point; cross-lane only for BN stats
  int g = l >> 4;
  int p = p0 + 4 * mg + g;
#pragma unroll
  for (int s = 0; s < NS; ++s) {
    float mx = -3.4e38f, mn = 3.4e38f, sm = 0.f, sq = 0.f;
#pragma unroll
    for (int mt = 0; mt < 5; ++mt)
#pragma unroll
      for (int r = 0; r < 4; ++r) {
        float v = acc[mt][s][r];
        mx = fmaxf(mx, v); mn = fminf(mn, v); sm += v; sq += v * v;
      }
    int colL = ng * (NS * 16) + s * 16 + (l & 15);
    hmax[(size_t)p * O + n_base + colL] = mx;
    hmin[(size_t)p * O + n_base + colL] = mn;
    sm += __shfl_xor(sm, 16); sm += __shfl_xor(sm, 32);
    sq += __shfl_xor(sq, 16); sq += __shfl_xor(sq, 32);
    if (l < 16) {
      ldsS[mg][ng * (NS * 16) + s * 16 + l] = sm;
      ldsQ[mg][ng * (NS * 16) + s * 16 + l] = sq;
    }
  }
  __syncthreads();
  for (int u = tid; u < NO; u += 256) {
    part[(size_t)mblk * O + n_base + u] = ldsS[0][u] + ldsS[1][u];
    part[((size_t)2048 + mblk) * O + n_base + u] = ldsQ[0][u] + ldsQ[1][u];
  }
}

// ---------------- conv5 MFMA: h5 = xcatH(16384x512) * B5(512x1024) ----------------
__global__ __launch_bounds__(256) void k_conv5_mfma(
    const _Float16* __restrict__ xh, const _Float16* __restrict__ Bp,
    _Float16* __restrict__ h5, float* __restrict__ part) {
  __shared__ __align__(16) _Float16 ldsA[64 * 64];     // 8KB
  __shared__ __align__(16) _Float16 ldsB[32 * 512];    // 32KB
  __shared__ float ldsS[2][256], ldsQ[2][256], ldsMx[2][256], ldsMn[2][256];
  int tid = threadIdx.x, wv = tid >> 6, l = tid & 63;
  int mblk = blockIdx.x & 255, nid = blockIdx.x >> 8;
  int m0 = mblk * 64;
  int n_base = nid * 256;
  int mg = wv & 1, ng = wv >> 1;
  f32x4 acc[2][8];
#pragma unroll
  for (int m = 0; m < 2; ++m)
#pragma unroll
    for (int s = 0; s < 8; ++s)
#pragma unroll
      for (int r = 0; r < 4; ++r) acc[m][s][r] = 0.f;

  for (int ch = 0; ch < 8; ++ch) {
#pragma unroll
    for (int it = 0; it < 2; ++it) {
      int r0 = wv * 16 + it * 8;
      int R = r0 + (l >> 3);
      int q = (l & 7) ^ (l >> 3);
      gload_lds16(xh + (size_t)(m0 + R) * 512 + ch * 64 + q * 8, ldsA + r0 * 64);
    }
    for (int u = wv; u < 32; u += 4) {
      int ks = u >> 4, sloc = u & 15;
      gload_lds16(Bp + ((size_t)((ch * 2 + ks) * 64 + (n_base >> 4) + sloc) * 64 + l) * 8,
                  ldsB + u * 512);
    }
    __syncthreads();
#pragma unroll
    for (int ks = 0; ks < 2; ++ks) {
      half8 b[8];
#pragma unroll
      for (int s = 0; s < 8; ++s)
        b[s] = *(const half8*)(ldsB + (ks * 16 + ng * 8 + s) * 512 + l * 8);
#pragma unroll
      for (int mt = 0; mt < 2; ++mt) {
        int row = mg * 32 + mt * 16 + (l & 15);
        int slot = (ks * 4 + (l >> 4)) ^ (row & 7);
        half8 a = *(const half8*)(ldsA + row * 64 + slot * 8);
#pragma unroll
        for (int s = 0; s < 8; ++s)
          acc[mt][s] = __builtin_amdgcn_mfma_f32_16x16x32_f16(a, b[s], acc[mt][s], 0, 0, 0);
      }
    }
    __syncthreads();
  }
  int g = l >> 4;
#pragma unroll
  for (int s = 0; s < 8; ++s) {
    float sm = 0.f, sq = 0.f, mx = -3.4e38f, mn = 3.4e38f;
    int col = n_base + ng * 128 + s * 16 + (l & 15);
#pragma unroll
    for (int mt = 0; mt < 2; ++mt)
#pragma unroll
      for (int r = 0; r < 4; ++r) {
        float v = acc[mt][s][r];
        int row = m0 + mg * 32 + mt * 16 + 4 * g + r;
        h5[(size_t)row * 1024 + col] = (_Float16)v;
        sm += v; sq += v * v; mx = fmaxf(mx, v); mn = fminf(mn, v);
      }
    sm += __shfl_xor(sm, 16); sm += __shfl_xor(sm, 32);
    sq += __shfl_xor(sq, 16); sq += __shfl_xor(sq, 32);
    mx = fmaxf(mx, __shfl_xor(mx, 16)); mx = fmaxf(mx, __shfl_xor(mx, 32));
    mn = fminf(mn, __shfl_xor(mn, 16)); mn = fminf(mn, __shfl_xor(mn, 32));
    if (l < 16) {
      int u = ng * 128 + s * 16 + l;
      ldsS[mg][u] = sm; ldsQ[mg][u] = sq; ldsMx[mg][u] = mx; ldsMn[mg][u] = mn;
    }
  }
  __syncthreads();
  {
    int u = tid;
    int col = n_base + u;
    part[(size_t)mblk * 1024 + col] = ldsS[0][u] + ldsS[1][u];
    part[((size_t)256 + mblk) * 1024 + col] = ldsQ[0][u] + ldsQ[1][u];
    part[((size_t)512 + mblk) * 1024 + col] = fmaxf(ldsMx[0][u], ldsMx[1][u]);
    part[((size_t)768 + mblk) * 1024 + col] = fminf(ldsMn[0][u], ldsMn[1][u]);
  }
}

// reduce partials -> per-channel BN scale/shift. grid = O blocks.
__global__ __launch_bounds__(256) void k_finalize(
    const float* __restrict__ part, int G, int O, float inv_count,
    const float* __restrict__ gamma, const float* __restrict__ beta,
    float* __restrict__ ss) {
  int o = blockIdx.x;
  float s = 0.f, s2 = 0.f;
  for (int g = threadIdx.x; g < G; g += 256) {
    s  += part[(size_t)g * O + o];
    s2 += part[((size_t)G + g) * O + o];
  }
#pragma unroll
  for (int sft = 32; sft; sft >>= 1) {
    s  += __shfl_down(s, sft);
    s2 += __shfl_down(s2, sft);
  }
  __shared__ float aw[4], aw2[4];
  int w = threadIdx.x >> 6;
  if ((threadIdx.x & 63) == 0) { aw[w] = s; aw2[w] = s2; }
  __syncthreads();
  if (threadIdx.x == 0) {
    s = aw[0] + aw[1] + aw[2] + aw[3];
    s2 = aw2[0] + aw2[1] + aw2[2] + aw2[3];
    float m   = s * inv_count;
    float var = s2 * inv_count - m * m;
    float scale = gamma[o] * rsqrtf(var + 1e-5f);
    ss[o]     = scale;
    ss[O + o] = beta[o] - m * scale;
  }
}

// apply BN+lrelu to (max or min per sign of scale), write fp16 into xcatH slice
__global__ void k_edge_apply(const float* __restrict__ hmax, const float* __restrict__ hmin,
                             const float* __restrict__ ss, _Float16* __restrict__ xh,
                             int O, int off) {
  int t = blockIdx.x * 256 + threadIdx.x;
  int o = t % O;
  int p = t / O;
  float scale = ss[o], shift = ss[O + o];
  float v = (scale >= 0.f) ? hmax[t] : hmin[t];
  v = scale * v + shift;
  v = (v >= 0.f) ? v : 0.2f * v;
  xh[(size_t)p * 512 + off + o] = (_Float16)v;
}

// conv5 mean-pool partials: grid = 8b*8ns*4cg = 256 blocks
__global__ __launch_bounds__(256) void k_pool5a(const _Float16* __restrict__ h5,
                                                const float* __restrict__ ss,
                                                float* __restrict__ pmean) {
  int bi = blockIdx.x;
  int b = bi >> 5, ns = (bi >> 2) & 7, cg = bi & 3;
  int col = cg * 256 + threadIdx.x;
  float scale = ss[col], shift = ss[1024 + col];
  float sm = 0.f;
  for (int n = ns * 256; n < ns * 256 + 256; ++n) {
    float v = (float)h5[(size_t)(b * 2048 + n) * 1024 + col];
    float y = scale * v + shift;
    y = (y >= 0.f) ? y : 0.2f * y;
    sm += y;
  }
  pmean[(size_t)(b * 8 + ns) * 1024 + col] = sm;
}

// final pool: exact max via fp32 partials (BN+lrelu commute), mean via pmean
__global__ __launch_bounds__(256) void k_pool5b(const float* __restrict__ part,
                                                const float* __restrict__ pmean,
                                                const float* __restrict__ ss,
                                                float* __restrict__ z) {
  int bi = blockIdx.x;
  int b = bi >> 2, cg = bi & 3;
  int col = cg * 256 + threadIdx.x;
  float scale = ss[col], shift = ss[1024 + col];
  const float* pmx = part + (size_t)512 * 1024;
  const float* pmn = part + (size_t)768 * 1024;
  float mxh = -3.4e38f, mnh = 3.4e38f;
  for (int q = 0; q < 32; ++q) {
    size_t base = (size_t)(b * 32 + q) * 1024 + col;
    mxh = fmaxf(mxh, pmx[base]);
    mnh = fminf(mnh, pmn[base]);
  }
  float hsel = (scale >= 0.f) ? mxh : mnh;
  float zmax = scale * hsel + shift;
  zmax = (zmax >= 0.f) ? zmax : 0.2f * zmax;
  float sm = 0.f;
  for (int ns = 0; ns < 8; ++ns) sm += pmean[(size_t)(b * 8 + ns) * 1024 + col];
  z[b * 2048 + col] = zmax;
  z[b * 2048 + 1024 + col] = sm * (1.f / 2048.f);
}

// generic FC: one wave per (b,o)
__global__ __launch_bounds__(64) void k_fc(const float* __restrict__ in,
                                           const float* __restrict__ Wf,
                                           const float* __restrict__ bias,
                                           float* __restrict__ out, int IN, int O) {
  int blk = blockIdx.x;
  int b = blk / O, o = blk % O;
  const float* a = in + (size_t)b * IN;
  const float* w = Wf + (size_t)o * IN;
  float s = 0.f;
  for (int i = threadIdx.x; i < IN; i += 64) s += a[i] * w[i];
#pragma unroll
  for (int sft = 32; sft; sft >>= 1) s += __shfl_down(s, sft);
  if (threadIdx.x == 0) out[(size_t)b * O + o] = s + (bias ? bias[o] : 0.f);
}

// batch-axis BN (count=8) + lrelu
__global__ void k_bn_fc(const float* __restrict__ pre, const float* __restrict__ gamma,
                        const float* __restrict__ beta, float* __restrict__ out, int O) {
  int o = blockIdx.x * 256 + threadIdx.x;
  if (o >= O) return;
  float v[NB];
  float s = 0.f, s2 = 0.f;
#pragma unroll
  for (int b = 0; b < NB; ++b) {
    v[b] = pre[(size_t)b * O + o];
    s += v[b]; s2 += v[b] * v[b];
  }
  float m = s * (1.f / NB);
  float var = s2 * (1.f / NB) - m * m;
  float scale = gamma[o] * rsqrtf(var + 1e-5f);
  float shift = beta[o] - m * scale;
#pragma unroll
  for (int b = 0; b < NB; ++b) {
    float x = scale * v[b] + shift;
    out[(size_t)b * O + o] = (x >= 0.f) ? x : 0.2f * x;
  }
}

// ---------------- launcher ----------------
extern "C" void kernel_launch(void* const* d_in, const int* in_sizes, int n_in,
                              void* d_out, int out_size, void* d_ws, size_t ws_size,
                              hipStream_t stream) {
  (void)in_sizes; (void)n_in; (void)out_size; (void)ws_size;
  const float* x    = (const float*)d_in[0];
  const float* geod = (const float*)d_in[1];
  const float* W1   = (const float*)d_in[2];
  const float* g1   = (const float*)d_in[3];
  const float* bt1  = (const float*)d_in[4];
  const float* W2   = (const float*)d_in[5];
  const float* g2   = (const float*)d_in[6];
  const float* bt2  = (const float*)d_in[7];
  const float* W3   = (const float*)d_in[8];
  const float* g3   = (const float*)d_in[9];
  const float* bt3  = (const float*)d_in[10];
  const float* W4   = (const float*)d_in[11];
  const float* g4   = (const float*)d_in[12];
  const float* bt4  = (const float*)d_in[13];
  const float* W5   = (const float*)d_in[14];
  const float* g5   = (const float*)d_in[15];
  const float* bt5  = (const float*)d_in[16];
  const float* L1   = (const float*)d_in[17];
  const float* g6   = (const float*)d_in[18];
  const float* bt6  = (const float*)d_in[19];
  const float* L2   = (const float*)d_in[20];
  const float* bl2  = (const float*)d_in[21];
  const float* g7   = (const float*)d_in[22];
  const float* bt7  = (const float*)d_in[23];
  const float* L3   = (const float*)d_in[24];
  const float* bl3  = (const float*)d_in[25];

  char* ws = (char*)d_ws;
  int*       idx   = (int*)(ws + OFF_IDX);
  float*     xt    = (float*)(ws + OFF_XT);
  _Float16*  xcatH = (_Float16*)(ws + OFF_XCATH);
  float*     wt1   = (float*)(ws + OFF_WT1);
  float*     wd1   = (float*)(ws + OFF_WD1);
  _Float16*  b2    = (_Float16*)(ws + OFF_B2);
  _Float16*  b3    = (_Float16*)(ws + OFF_B3);
  _Float16*  b4    = (_Float16*)(ws + OFF_B4);
  _Float16*  b5    = (_Float16*)(ws + OFF_B5);
  float*     hmax  = (float*)(ws + OFF_HMAX);
  float*     hmin  = (float*)(ws + OFF_HMIN);
  _Float16*  h5    = (_Float16*)(ws + OFF_H5);
  float*     part  = (float*)(ws + OFF_PART);
  float*     pmean = (float*)(ws + OFF_PMEAN);
  float*     ssb   = (float*)(ws + OFF_SS);
  float*     z     = (float*)(ws + OFF_Z);
  float*     z1p   = (float*)(ws + OFF_Z1P);
  float*     z1    = (float*)(ws + OFF_Z1);
  float*     z2p   = (float*)(ws + OFF_Z2P);
  float*     z2    = (float*)(ws + OFF_Z2);

  const float invE = 1.f / (float)(BN * NK);
  const float inv5 = 1.f / (float)(BN);

  k_transpose_x<<<(NB * 3 * NP + 255) / 256, 256, 0, stream>>>(x, xt);
  k_prep_w<<<1, 256, 0, stream>>>(W1, wt1, wd1, 3, 64);
  k_prep_b<128, 64, 64><<<32, 256, 0, stream>>>(W2, b2);
  k_prep_b<128, 128, 64><<<64, 256, 0, stream>>>(W3, b3);
  k_prep_b<256, 256, 128><<<256, 256, 0, stream>>>(W4, b4);
  k_prep_b<512, 1024, 0><<<2048, 256, 0, stream>>>(W5, b5);
  k_topk<<<BN / 4, 256, 0, stream>>>(geod, idx);

  // layer 1 (C=3, fp32)
  k_edge<3, 64><<<2048, 256, 0, stream>>>(xt, 0, 3, idx, wt1, wd1, hmax, hmin, part, 2);
  k_finalize<<<64, 256, 0, stream>>>(part, 2048, 64, invE, g1, bt1, ssb);
  k_edge_apply<<<(BN * 64) / 256, 256, 0, stream>>>(hmax, hmin, ssb, xcatH, 64, 0);
  // layer 2 (C=64 -> O=64), input slice 0
  k_edge_mfma<64, 64, 1><<<2048, 256, 0, stream>>>(xcatH, 0, idx, b2, hmax, hmin, part);
  k_finalize<<<64, 256, 0, stream>>>(part, 2048, 64, invE, g2, bt2, ssb);
  k_edge_apply<<<(BN * 64) / 256, 256, 0, stream>>>(hmax, hmin, ssb, xcatH, 64, 64);
  // layer 3 (C=64 -> O=128), input slice 64
  k_edge_mfma<64, 128, 1><<<2048, 256, 0, stream>>>(xcatH, 64, idx, b3, hmax, hmin, part);
  k_finalize<<<128, 256, 0, stream>>>(part, 2048, 128, invE, g3, bt3, ssb);
  k_edge_apply<<<(BN * 128) / 256, 256, 0, stream>>>(hmax, hmin, ssb, xcatH, 128, 128);
  // layer 4 (C=128 -> O=256), input slice 128, N split in 2
  k_edge_mfma<128, 256, 2><<<4096, 256, 0, stream>>>(xcatH, 128, idx, b4, hmax, hmin, part);
  k_finalize<<<256, 256, 0, stream>>>(part, 2048, 256, invE, g4, bt4, ssb);
  k_edge_apply<<<(BN * 256) / 256, 256, 0, stream>>>(hmax, hmin, ssb, xcatH, 256, 256);

  // conv5 (16384x512 @ 512x1024)
  k_conv5_mfma<<<1024, 256, 0, stream>>>(xcatH, b5, h5, part);
  k_finalize<<<1024, 256, 0, stream>>>(part, 256, 1024, inv5, g5, bt5, ssb);
  k_pool5a<<<256, 256, 0, stream>>>(h5, ssb, pmean);
  k_pool5b<<<32, 256, 0, stream>>>(part, pmean, ssb, z);

  // FC head
  k_fc<<<NB * 512, 64, 0, stream>>>(z, L1, nullptr, z1p, 2048, 512);
  k_bn_fc<<<2, 256, 0, stream>>>(z1p, g6, bt6, z1, 512);
  k_fc<<<NB * 256, 64, 0, stream>>>(z1, L2, bl2, z2p, 512, 256);
  k_bn_fc<<<1, 256, 0, stream>>>(z2p, g7, bt7, z2, 256);
  k_fc<<<NB * 40, 64, 0, stream>>>(z2, L3, bl3, (float*)d_out, 256, 40);
}

// Round 6
// 297.092 us; speedup vs baseline: 6.0578x; 1.0736x over previous
//
#include <hip/hip_runtime.h>
#include <hip/hip_bf16.h>
#include <cstdint>
#include <cstddef>

// Problem constants
#define NB 8
#define NP 2048
#define NK 20
#define BN 16384      // NB*NP

typedef _Float16 half8 __attribute__((ext_vector_type(8)));
typedef float f32x4 __attribute__((ext_vector_type(4)));

__device__ __forceinline__ void gload_lds16(const void* g, void* l) {
  __builtin_amdgcn_global_load_lds(
      (const __attribute__((address_space(1))) unsigned int*)g,
      (__attribute__((address_space(3))) unsigned int*)l, 16, 0, 0);
}

// ---------------- workspace layout (bytes) ----------------
static constexpr size_t OFF_IDX   = 0;                                // int[BN*20]
static constexpr size_t OFF_XT    = OFF_IDX + (size_t)BN*NK*4;        // f32[BN*3]
static constexpr size_t OFF_XCATH = OFF_XT + (size_t)BN*3*4;          // f16[BN*512]
static constexpr size_t OFF_WT1   = OFF_XCATH + (size_t)BN*512*2;
static constexpr size_t OFF_WD1   = OFF_WT1 + 3*64*4;
static constexpr size_t OFF_B2    = OFF_WD1 + 3*64*4;                 // f16[64*64]   W0
static constexpr size_t OFF_S2    = OFF_B2 + (size_t)64*64*2;         // f16[64*64]   W1-W0
static constexpr size_t OFF_B3    = OFF_S2 + (size_t)64*64*2;         // f16[64*128]
static constexpr size_t OFF_S3    = OFF_B3 + (size_t)64*128*2;
static constexpr size_t OFF_B4    = OFF_S3 + (size_t)64*128*2;        // f16[128*256]
static constexpr size_t OFF_S4    = OFF_B4 + (size_t)128*256*2;
static constexpr size_t OFF_B5    = OFF_S4 + (size_t)128*256*2;       // f16[512*1024]
static constexpr size_t OFF_SBASE = OFF_B5 + (size_t)512*1024*2;      // f32[BN*256] self-term
static constexpr size_t OFF_HMAX  = OFF_SBASE + (size_t)BN*256*4;     // f32[BN*256]
static constexpr size_t OFF_HMIN  = OFF_HMAX + (size_t)BN*256*4;      // f32[BN*256]
static constexpr size_t OFF_H5    = OFF_HMAX;                         // f16[BN*1024] overlay (edge bufs dead)
static constexpr size_t OFF_PART  = OFF_HMIN + (size_t)BN*256*4;      // 4 MB partials
static constexpr size_t OFF_PMEAN = OFF_PART + (size_t)4*1024*1024;   // f32[8*8*1024]
static constexpr size_t OFF_SS    = OFF_PMEAN + (size_t)8*8*1024*4;   // f32[2*1024]
static constexpr size_t OFF_Z     = OFF_SS + 2*1024*4;                // f32[8*2048]
static constexpr size_t OFF_Z1P   = OFF_Z + (size_t)NB*2048*4;
static constexpr size_t OFF_Z1    = OFF_Z1P + NB*512*4;
static constexpr size_t OFF_Z2P   = OFF_Z1 + NB*512*4;
static constexpr size_t OFF_Z2    = OFF_Z2P + NB*256*4;
// total ~75 MB

// ---------------- small prep kernels ----------------

__global__ void k_transpose_x(const float* __restrict__ x, float* __restrict__ xt) {
  int t = blockIdx.x * 256 + threadIdx.x;
  if (t >= NB * 3 * NP) return;
  int n = t & (NP - 1);
  int c = (t / NP) % 3;
  int b = t / (3 * NP);
  xt[(size_t)(b * NP + n) * 3 + c] = x[t];
}

__global__ void k_prep_w(const float* __restrict__ W, float* __restrict__ Wt,
                         float* __restrict__ Wd, int C, int O) {
  int t = blockIdx.x * 256 + threadIdx.x;
  if (t >= C * O) return;
  int o = t % O, c = t / O;
  float w0 = W[o * 2 * C + c];
  float w1 = W[o * 2 * C + C + c];
  Wt[t] = w0;
  Wd[t] = w1 - w0;
}

// Pack weights into exact b-fragment order for mfma_f32_16x16x32_f16.
// K2 = GEMM K; RS = row stride of W (O-major); DIFF: pack W[:,K2+k]-W[:,k].
// b-frag: lane l, elem e reads B[64*ch + 32*ks + 8*(l>>4)+e][16*sl + (l&15)].
template <int K2, int O, int RS, bool DIFF>
__global__ void k_prep_b(const float* __restrict__ W, _Float16* __restrict__ Bp) {
  int t = blockIdx.x * 256 + threadIdx.x;
  if (t >= K2 * O) return;
  int o = t % O, k = t / O;
  float v;
  if (DIFF) v = W[(size_t)o * RS + K2 + k] - W[(size_t)o * RS + k];
  else      v = W[(size_t)o * RS + k];
  int ch = k >> 6, ks = (k >> 5) & 1, kg = (k >> 3) & 3, e = k & 7;
  int sl = o >> 4, ol = o & 15;
  size_t flat = (((size_t)(ch * 2 + ks) * (O / 16) + sl) * 64 + (kg * 16 + ol)) * 8 + e;
  Bp[flat] = (_Float16)v;
}

// top-20 per row of 2048, lowest-index tie-break (matches jax.lax.top_k).
// One wave per row. Per-lane sorted top-3 cache (value+index, branchless
// insertion); value-only butterfly max; ballot + scalar tie-break; rescan
// only when a lane wins a 4th time (E~0.26/row).
__global__ __launch_bounds__(256) void k_topk(const float* __restrict__ geod,
                                              int* __restrict__ idx) {
  int wv = threadIdx.x >> 6, l = threadIdx.x & 63;
  int row = blockIdx.x * 4 + wv;
  const float* g = geod + (size_t)row * NP;
  float4 v[8];
#pragma unroll
  for (int r = 0; r < 8; ++r) v[r] = *(const float4*)&g[r * 256 + l * 4];
  const float NEG = -__builtin_huge_valf();
  unsigned int dead = 0;
  float m1 = NEG, m2 = NEG, m3 = NEG;
  int i1 = 0, i2 = 0, i3 = 0;
#pragma unroll
  for (int r = 0; r < 8; ++r) {
    float vals[4] = {v[r].x, v[r].y, v[r].z, v[r].w};
#pragma unroll
    for (int e = 0; e < 4; ++e) {
      float val = vals[e];
      int gi = r * 256 + l * 4 + e;
      bool c1 = val > m1;
      float t  = c1 ? m1 : val;   int ti  = c1 ? i1 : gi;
      m1 = c1 ? val : m1;         i1 = c1 ? gi : i1;
      bool c2 = t > m2;
      float t2 = c2 ? m2 : t;     int t2i = c2 ? i2 : ti;
      m2 = c2 ? t : m2;           i2 = c2 ? ti : i2;
      bool c3 = t2 > m3;
      m3 = c3 ? t2 : m3;          i3 = c3 ? t2i : i3;
    }
  }
  for (int it = 0; it < NK; ++it) {
    float cv = m1;
#pragma unroll
    for (int s = 1; s < 64; s <<= 1) cv = fmaxf(cv, __shfl_xor(cv, s));
    unsigned long long mask = __ballot(m1 == cv);
    int best_i = 1 << 30, best_l = 0;
    while (mask) {                       // wave-uniform scalar loop, typ. 1 iter
      int L = (int)__builtin_ctzll(mask);
      int ii = __builtin_amdgcn_readlane(i1, L);
      if (ii < best_i) { best_i = ii; best_l = L; }
      mask &= mask - 1;
    }
    if (l == 0) idx[(size_t)row * NK + it] = best_i;
    if (l == best_l) {
      dead |= 1u << (((i1 >> 8) << 2) | (i1 & 3));
      m1 = m2; i1 = i2; m2 = m3; i2 = i3; m3 = NEG; i3 = 0;
      if (m1 == NEG) {                   // cache exhausted (4th win): rescan
#pragma unroll
        for (int r = 0; r < 8; ++r) {
          float vals[4] = {v[r].x, v[r].y, v[r].z, v[r].w};
#pragma unroll
          for (int e = 0; e < 4; ++e) {
            int el = r * 4 + e;
            float val = ((dead >> el) & 1u) ? NEG : vals[e];
            int gi = r * 256 + l * 4 + e;
            bool c1 = val > m1;
            float t  = c1 ? m1 : val;   int ti  = c1 ? i1 : gi;
            m1 = c1 ? val : m1;         i1 = c1 ? gi : i1;
            bool c2 = t > m2;
            float t2 = c2 ? m2 : t;     int t2i = c2 ? i2 : ti;
            m2 = c2 ? t : m2;           i2 = c2 ? ti : i2;
            bool c3 = t2 > m3;
            m3 = c3 ? t2 : m3;          i3 = c3 ? t2i : i3;
          }
        }
      }
    }
  }
}

// ---------------- layer-1 EdgeConv (C=3, fp32 VALU) ----------------
template <int C, int O>
__global__ __launch_bounds__(256) void k_edge(
    const float* __restrict__ xin, int in_off, int in_stride,
    const int* __restrict__ idx,
    const float* __restrict__ Wt, const float* __restrict__ Wd,
    float* __restrict__ hmax, float* __restrict__ hmin,
    float* __restrict__ part, int ngrp) {
  constexpr int PIF = 256 / O;
  __shared__ __align__(16) float lds[PIF * 21 * C];
  __shared__ int lidx[PIF * NK];
  __shared__ float red[256];
  int tid = threadIdx.x;
  int g = tid / O, o = tid % O;
  float ps = 0.f, ps2 = 0.f;
  for (int it = 0; it < ngrp; ++it) {
    int grp = blockIdx.x * ngrp + it;
    int p0 = grp * PIF;
    for (int u = tid; u < PIF * NK; u += 256) lidx[u] = idx[(size_t)p0 * NK + u];
    __syncthreads();
    for (int u = tid; u < PIF * 21 * C; u += 256) {
      int pp  = u / (21 * C);
      int rem = u - pp * 21 * C;
      int j   = rem / C;
      int c   = rem - j * C;
      int p   = p0 + pp;
      int bbase = p & ~(NP - 1);
      int srcn = (j == 20) ? p : (bbase + lidx[pp * NK + j]);
      lds[u] = xin[(size_t)srcn * in_stride + in_off + c];
    }
    __syncthreads();
    const float* xl = &lds[g * 21 * C];
    float base = 0.f;
    for (int c = 0; c < C; ++c) base += xl[20 * C + c] * Wd[c * O + o];
    float h[NK];
#pragma unroll
    for (int j = 0; j < NK; ++j) h[j] = base;
    for (int c = 0; c < C; ++c) {
      float w = Wt[c * O + o];
#pragma unroll
      for (int j = 0; j < NK; ++j) h[j] += xl[j * C + c] * w;
    }
    float mx = h[0], mn = h[0];
#pragma unroll
    for (int j = 0; j < NK; ++j) {
      mx = fmaxf(mx, h[j]); mn = fminf(mn, h[j]);
      ps += h[j]; ps2 += h[j] * h[j];
    }
    int p = p0 + g;
    hmax[(size_t)p * O + o] = mx;
    hmin[(size_t)p * O + o] = mn;
    __syncthreads();
  }
  red[tid] = ps;
  __syncthreads();
  if (tid < O) {
    float a = red[tid];
#pragma unroll
    for (int g2 = 1; g2 < PIF; ++g2) a += red[g2 * O + tid];
    part[(size_t)blockIdx.x * O + tid] = a;
  }
  __syncthreads();
  red[tid] = ps2;
  __syncthreads();
  if (tid < O) {
    float a = red[tid];
#pragma unroll
    for (int g2 = 1; g2 < PIF; ++g2) a += red[g2 * O + tid];
    part[((size_t)gridDim.x + blockIdx.x) * O + tid] = a;
  }
}

// ---------------- self-term GEMM: sbase[p][o] = x[p]·(W1-W0) ----------------
// conv5-like structure: 64 rows/block, O cols, 4 waves (mg 2 x ng 2).
template <int C, int O>
__global__ __launch_bounds__(256) void k_self_mfma(
    const _Float16* __restrict__ xh, int in_off,
    const _Float16* __restrict__ Bp, float* __restrict__ sbase) {
  constexpr int NCH = C / 64;
  constexpr int NSLO = O / 16;
  constexpr int NS = NSLO / 2;       // 16-col slices per wave
  constexpr int PAIRS = 2 * NSLO;
  __shared__ __align__(16) _Float16 ldsA[64 * 64];
  __shared__ __align__(16) _Float16 ldsB[PAIRS * 512];
  int tid = threadIdx.x, wv = tid >> 6, l = tid & 63;
  int m0 = blockIdx.x * 64;
  int mg = wv & 1, ng = wv >> 1;
  f32x4 acc[2][NS];
#pragma unroll
  for (int m = 0; m < 2; ++m)
#pragma unroll
    for (int s = 0; s < NS; ++s)
#pragma unroll
      for (int r = 0; r < 4; ++r) acc[m][s][r] = 0.f;

  for (int ch = 0; ch < NCH; ++ch) {
#pragma unroll
    for (int it = 0; it < 2; ++it) {
      int r0 = wv * 16 + it * 8;
      int R = r0 + (l >> 3);
      int q = (l & 7) ^ (l >> 3);
      gload_lds16(xh + (size_t)(m0 + R) * 512 + in_off + ch * 64 + q * 8, ldsA + r0 * 64);
    }
    for (int u = wv; u < PAIRS; u += 4) {
      int ks = u / NSLO, sloc = u - ks * NSLO;
      gload_lds16(Bp + ((size_t)((ch * 2 + ks) * NSLO + sloc) * 64 + l) * 8,
                  ldsB + u * 512);
    }
    __syncthreads();
#pragma unroll
    for (int ks = 0; ks < 2; ++ks) {
      half8 b[NS];
#pragma unroll
      for (int s = 0; s < NS; ++s)
        b[s] = *(const half8*)(ldsB + (ks * NSLO + ng * NS + s) * 512 + l * 8);
#pragma unroll
      for (int mt = 0; mt < 2; ++mt) {
        int row = mg * 32 + mt * 16 + (l & 15);
        int slot = (ks * 4 + (l >> 4)) ^ (row & 7);
        half8 a = *(const half8*)(ldsA + row * 64 + slot * 8);
#pragma unroll
        for (int s = 0; s < NS; ++s)
          acc[mt][s] = __builtin_amdgcn_mfma_f32_16x16x32_f16(a, b[s], acc[mt][s], 0, 0, 0);
      }
    }
    __syncthreads();
  }
  int g = l >> 4;
#pragma unroll
  for (int s = 0; s < NS; ++s) {
    int col = ng * (NS * 16) + s * 16 + (l & 15);
#pragma unroll
    for (int mt = 0; mt < 2; ++mt)
#pragma unroll
      for (int r = 0; r < 4; ++r) {
        int row = m0 + mg * 32 + mt * 16 + 4 * g + r;
        sbase[(size_t)row * O + col] = acc[mt][s][r];
      }
  }
}

// ---------------- MFMA EdgeConv neighbor-GEMM (layers 2-4), K = C ----------------
// A-row r (0..79 within 80-row wave group) -> point pp=(r>>2)&3, j=4*(r>>4)+(r&3):
// each lane's C-fragment holds all 20 j of a single point -> lane-local max.
// Self-term (j-invariant) comes from sbase[], added in the epilogue.
template <int C, int O, int NSPLIT>
__global__ __launch_bounds__(256) void k_edge_mfma(
    const _Float16* __restrict__ xh, int in_off,
    const int* __restrict__ idx,
    const _Float16* __restrict__ Bp, const float* __restrict__ sbase,
    float* __restrict__ hmax, float* __restrict__ hmin,
    float* __restrict__ part) {
  constexpr int NCH = C / 64;        // 64-wide K chunks
  constexpr int NO = O / NSPLIT;     // columns handled by this block
  constexpr int NSLO = NO / 16;      // 16-col slices in block
  constexpr int NS = NSLO / 2;       // slices per wave (2 ng-groups)
  constexpr int PAIRS = 2 * NSLO;    // (ks, slice) B sub-tiles per chunk
  __shared__ __align__(16) _Float16 ldsA[160 * 64];   // 20KB, XOR-swizzled
  __shared__ __align__(16) _Float16 ldsB[PAIRS * 512];
  __shared__ float ldsS[2][NO], ldsQ[2][NO];
  int tid = threadIdx.x, wv = tid >> 6, l = tid & 63;
  int mblk = blockIdx.x, nid = 0;
  if (NSPLIT > 1) { nid = mblk >> 11; mblk &= 2047; }
  int p0 = mblk * 8;                 // 8 points per block
  int bbase = p0 & ~(NP - 1);
  int n_base = nid * NO;
  int mg = wv & 1, ng = wv >> 1;
  f32x4 acc[5][NS];
#pragma unroll
  for (int m = 0; m < 5; ++m)
#pragma unroll
    for (int s = 0; s < NS; ++s)
#pragma unroll
      for (int r = 0; r < 4; ++r) acc[m][s][r] = 0.f;

  for (int ch = 0; ch < NCH; ++ch) {
    int cbase = ch * 64;
    // stage A: wave stages rows [40*wv, 40*wv+40), 8 rows (1024B) per issue.
    // source pre-swizzled: lane slot (l&7) holds source 16B-segment q=(l&7)^(l>>3).
#pragma unroll
    for (int it = 0; it < 5; ++it) {
      int r0 = wv * 40 + it * 8;
      int R = r0 + (l >> 3);
      int mgR = R / 80;
      int r = R - mgR * 80;
      int pp = 4 * mgR + ((r >> 2) & 3);
      int j = ((r >> 4) << 2) | (r & 3);
      int p = p0 + pp;
      int srcn = bbase + idx[p * NK + j];
      int q = (l & 7) ^ (l >> 3);
      gload_lds16(xh + (size_t)srcn * 512 + in_off + cbase + q * 8, ldsA + r0 * 64);
    }
    // stage B chunk (already in frag order)
    for (int u = wv; u < PAIRS; u += 4) {
      int ks = u / NSLO, sloc = u - ks * NSLO;
      gload_lds16(Bp + ((size_t)((ch * 2 + ks) * (O / 16) + (n_base >> 4) + sloc) * 64 + l) * 8,
                  ldsB + u * 512);
    }
    __syncthreads();
#pragma unroll
    for (int ks = 0; ks < 2; ++ks) {
      half8 b[NS];
#pragma unroll
      for (int s = 0; s < NS; ++s)
        b[s] = *(const half8*)(ldsB + (ks * NSLO + ng * NS + s) * 512 + l * 8);
#pragma unroll
      for (int mt = 0; mt < 5; ++mt) {
        int row = mg * 80 + mt * 16 + (l & 15);
        int slot = (ks * 4 + (l >> 4)) ^ (row & 7);
        half8 a = *(const half8*)(ldsA + row * 64 + slot * 8);
#pragma unroll
        for (int s = 0; s < NS; ++s)
          acc[mt][s] = __builtin_amdgcn_mfma_f32_16x16x32_f16(a, b[s], acc[mt][s], 0, 0, 0);
      }
    }
    __syncthreads();
  }
  // epilogue: add j-invariant self-term, lane-local j-max/min per point;
  // cross-lane only for BN stats
  int g = l >> 4;
  int p = p0 + 4 * mg + g;
#pragma unroll
  for (int s = 0; s < NS; ++s) {
    int colL = ng * (NS * 16) + s * 16 + (l & 15);
    float sb = sbase[(size_t)p * O + n_base + colL];
    float mx = -3.4e38f, mn = 3.4e38f, sm = 0.f, sq = 0.f;
#pragma unroll
    for (int mt = 0; mt < 5; ++mt)
#pragma unroll
      for (int r = 0; r < 4; ++r) {
        float v = acc[mt][s][r] + sb;
        mx = fmaxf(mx, v); mn = fminf(mn, v); sm += v; sq += v * v;
      }
    hmax[(size_t)p * O + n_base + colL] = mx;
    hmin[(size_t)p * O + n_base + colL] = mn;
    sm += __shfl_xor(sm, 16); sm += __shfl_xor(sm, 32);
    sq += __shfl_xor(sq, 16); sq += __shfl_xor(sq, 32);
    if (l < 16) {
      ldsS[mg][ng * (NS * 16) + s * 16 + l] = sm;
      ldsQ[mg][ng * (NS * 16) + s * 16 + l] = sq;
    }
  }
  __syncthreads();
  for (int u = tid; u < NO; u += 256) {
    part[(size_t)mblk * O + n_base + u] = ldsS[0][u] + ldsS[1][u];
    part[((size_t)2048 + mblk) * O + n_base + u] = ldsQ[0][u] + ldsQ[1][u];
  }
}

// ---------------- conv5 MFMA: h5 = xcatH(16384x512) * B5(512x1024) ----------------
__global__ __launch_bounds__(256) void k_conv5_mfma(
    const _Float16* __restrict__ xh, const _Float16* __restrict__ Bp,
    _Float16* __restrict__ h5, float* __restrict__ part) {
  __shared__ __align__(16) _Float16 ldsA[64 * 64];     // 8KB
  __shared__ __align__(16) _Float16 ldsB[32 * 512];    // 32KB
  __shared__ float ldsS[2][256], ldsQ[2][256], ldsMx[2][256], ldsMn[2][256];
  int tid = threadIdx.x, wv = tid >> 6, l = tid & 63;
  int mblk = blockIdx.x & 255, nid = blockIdx.x >> 8;
  int m0 = mblk * 64;
  int n_base = nid * 256;
  int mg = wv & 1, ng = wv >> 1;
  f32x4 acc[2][8];
#pragma unroll
  for (int m = 0; m < 2; ++m)
#pragma unroll
    for (int s = 0; s < 8; ++s)
#pragma unroll
      for (int r = 0; r < 4; ++r) acc[m][s][r] = 0.f;

  for (int ch = 0; ch < 8; ++ch) {
#pragma unroll
    for (int it = 0; it < 2; ++it) {
      int r0 = wv * 16 + it * 8;
      int R = r0 + (l >> 3);
      int q = (l & 7) ^ (l >> 3);
      gload_lds16(xh + (size_t)(m0 + R) * 512 + ch * 64 + q * 8, ldsA + r0 * 64);
    }
    for (int u = wv; u < 32; u += 4) {
      int ks = u >> 4, sloc = u & 15;
      gload_lds16(Bp + ((size_t)((ch * 2 + ks) * 64 + (n_base >> 4) + sloc) * 64 + l) * 8,
                  ldsB + u * 512);
    }
    __syncthreads();
#pragma unroll
    for (int ks = 0; ks < 2; ++ks) {
      half8 b[8];
#pragma unroll
      for (int s = 0; s < 8; ++s)
        b[s] = *(const half8*)(ldsB + (ks * 16 + ng * 8 + s) * 512 + l * 8);
#pragma unroll
      for (int mt = 0; mt < 2; ++mt) {
        int row = mg * 32 + mt * 16 + (l & 15);
        int slot = (ks * 4 + (l >> 4)) ^ (row & 7);
        half8 a = *(const half8*)(ldsA + row * 64 + slot * 8);
#pragma unroll
        for (int s = 0; s < 8; ++s)
          acc[mt][s] = __builtin_amdgcn_mfma_f32_16x16x32_f16(a, b[s], acc[mt][s], 0, 0, 0);
      }
    }
    __syncthreads();
  }
  int g = l >> 4;
#pragma unroll
  for (int s = 0; s < 8; ++s) {
    float sm = 0.f, sq = 0.f, mx = -3.4e38f, mn = 3.4e38f;
    int col = n_base + ng * 128 + s * 16 + (l & 15);
#pragma unroll
    for (int mt = 0; mt < 2; ++mt)
#pragma unroll
      for (int r = 0; r < 4; ++r) {
        float v = acc[mt][s][r];
        int row = m0 + mg * 32 + mt * 16 + 4 * g + r;
        h5[(size_t)row * 1024 + col] = (_Float16)v;
        sm += v; sq += v * v; mx = fmaxf(mx, v); mn = fminf(mn, v);
      }
    sm += __shfl_xor(sm, 16); sm += __shfl_xor(sm, 32);
    sq += __shfl_xor(sq, 16); sq += __shfl_xor(sq, 32);
    mx = fmaxf(mx, __shfl_xor(mx, 16)); mx = fmaxf(mx, __shfl_xor(mx, 32));
    mn = fminf(mn, __shfl_xor(mn, 16)); mn = fminf(mn, __shfl_xor(mn, 32));
    if (l < 16) {
      int u = ng * 128 + s * 16 + l;
      ldsS[mg][u] = sm; ldsQ[mg][u] = sq; ldsMx[mg][u] = mx; ldsMn[mg][u] = mn;
    }
  }
  __syncthreads();
  {
    int u = tid;
    int col = n_base + u;
    part[(size_t)mblk * 1024 + col] = ldsS[0][u] + ldsS[1][u];
    part[((size_t)256 + mblk) * 1024 + col] = ldsQ[0][u] + ldsQ[1][u];
    part[((size_t)512 + mblk) * 1024 + col] = fmaxf(ldsMx[0][u], ldsMx[1][u]);
    part[((size_t)768 + mblk) * 1024 + col] = fminf(ldsMn[0][u], ldsMn[1][u]);
  }
}

// reduce partials -> per-channel BN scale/shift. grid = O blocks.
__global__ __launch_bounds__(256) void k_finalize(
    const float* __restrict__ part, int G, int O, float inv_count,
    const float* __restrict__ gamma, const float* __restrict__ beta,
    float* __restrict__ ss) {
  int o = blockIdx.x;
  float s = 0.f, s2 = 0.f;
  for (int g = threadIdx.x; g < G; g += 256) {
    s  += part[(size_t)g * O + o];
    s2 += part[((size_t)G + g) * O + o];
  }
#pragma unroll
  for (int sft = 32; sft; sft >>= 1) {
    s  += __shfl_down(s, sft);
    s2 += __shfl_down(s2, sft);
  }
  __shared__ float aw[4], aw2[4];
  int w = threadIdx.x >> 6;
  if ((threadIdx.x & 63) == 0) { aw[w] = s; aw2[w] = s2; }
  __syncthreads();
  if (threadIdx.x == 0) {
    s = aw[0] + aw[1] + aw[2] + aw[3];
    s2 = aw2[0] + aw2[1] + aw2[2] + aw2[3];
    float m   = s * inv_count;
    float var = s2 * inv_count - m * m;
    float scale = gamma[o] * rsqrtf(var + 1e-5f);
    ss[o]     = scale;
    ss[O + o] = beta[o] - m * scale;
  }
}

// apply BN+lrelu to (max or min per sign of scale), write fp16 into xcatH slice
__global__ void k_edge_apply(const float* __restrict__ hmax, const float* __restrict__ hmin,
                             const float* __restrict__ ss, _Float16* __restrict__ xh,
                             int O, int off) {
  int t = blockIdx.x * 256 + threadIdx.x;
  int o = t % O;
  int p = t / O;
  float scale = ss[o], shift = ss[O + o];
  float v = (scale >= 0.f) ? hmax[t] : hmin[t];
  v = scale * v + shift;
  v = (v >= 0.f) ? v : 0.2f * v;
  xh[(size_t)p * 512 + off + o] = (_Float16)v;
}

// conv5 mean-pool partials: grid = 8b*8ns*4cg = 256 blocks
__global__ __launch_bounds__(256) void k_pool5a(const _Float16* __restrict__ h5,
                                                const float* __restrict__ ss,
                                                float* __restrict__ pmean) {
  int bi = blockIdx.x;
  int b = bi >> 5, ns = (bi >> 2) & 7, cg = bi & 3;
  int col = cg * 256 + threadIdx.x;
  float scale = ss[col], shift = ss[1024 + col];
  float sm = 0.f;
  for (int n = ns * 256; n < ns * 256 + 256; ++n) {
    float v = (float)h5[(size_t)(b * 2048 + n) * 1024 + col];
    float y = scale * v + shift;
    y = (y >= 0.f) ? y : 0.2f * y;
    sm += y;
  }
  pmean[(size_t)(b * 8 + ns) * 1024 + col] = sm;
}

// final pool: exact max via fp32 partials (BN+lrelu commute), mean via pmean
__global__ __launch_bounds__(256) void k_pool5b(const float* __restrict__ part,
                                                const float* __restrict__ pmean,
                                                const float* __restrict__ ss,
                                                float* __restrict__ z) {
  int bi = blockIdx.x;
  int b = bi >> 2, cg = bi & 3;
  int col = cg * 256 + threadIdx.x;
  float scale = ss[col], shift = ss[1024 + col];
  const float* pmx = part + (size_t)512 * 1024;
  const float* pmn = part + (size_t)768 * 1024;
  float mxh = -3.4e38f, mnh = 3.4e38f;
  for (int q = 0; q < 32; ++q) {
    size_t base = (size_t)(b * 32 + q) * 1024 + col;
    mxh = fmaxf(mxh, pmx[base]);
    mnh = fminf(mnh, pmn[base]);
  }
  float hsel = (scale >= 0.f) ? mxh : mnh;
  float zmax = scale * hsel + shift;
  zmax = (zmax >= 0.f) ? zmax : 0.2f * zmax;
  float sm = 0.f;
  for (int ns = 0; ns < 8; ++ns) sm += pmean[(size_t)(b * 8 + ns) * 1024 + col];
  z[b * 2048 + col] = zmax;
  z[b * 2048 + 1024 + col] = sm * (1.f / 2048.f);
}

// generic FC: one wave per (b,o)
__global__ __launch_bounds__(64) void k_fc(const float* __restrict__ in,
                                           const float* __restrict__ Wf,
                                           const float* __restrict__ bias,
                                           float* __restrict__ out, int IN, int O) {
  int blk = blockIdx.x;
  int b = blk / O, o = blk % O;
  const float* a = in + (size_t)b * IN;
  const float* w = Wf + (size_t)o * IN;
  float s = 0.f;
  for (int i = threadIdx.x; i < IN; i += 64) s += a[i] * w[i];
#pragma unroll
  for (int sft = 32; sft; sft >>= 1) s += __shfl_down(s, sft);
  if (threadIdx.x == 0) out[(size_t)b * O + o] = s + (bias ? bias[o] : 0.f);
}

// batch-axis BN (count=8) + lrelu
__global__ void k_bn_fc(const float* __restrict__ pre, const float* __restrict__ gamma,
                        const float* __restrict__ beta, float* __restrict__ out, int O) {
  int o = blockIdx.x * 256 + threadIdx.x;
  if (o >= O) return;
  float v[NB];
  float s = 0.f, s2 = 0.f;
#pragma unroll
  for (int b = 0; b < NB; ++b) {
    v[b] = pre[(size_t)b * O + o];
    s += v[b]; s2 += v[b] * v[b];
  }
  float m = s * (1.f / NB);
  float var = s2 * (1.f / NB) - m * m;
  float scale = gamma[o] * rsqrtf(var + 1e-5f);
  float shift = beta[o] - m * scale;
#pragma unroll
  for (int b = 0; b < NB; ++b) {
    float x = scale * v[b] + shift;
    out[(size_t)b * O + o] = (x >= 0.f) ? x : 0.2f * x;
  }
}

// ---------------- launcher ----------------
extern "C" void kernel_launch(void* const* d_in, const int* in_sizes, int n_in,
                              void* d_out, int out_size, void* d_ws, size_t ws_size,
                              hipStream_t stream) {
  (void)in_sizes; (void)n_in; (void)out_size; (void)ws_size;
  const float* x    = (const float*)d_in[0];
  const float* geod = (const float*)d_in[1];
  const float* W1   = (const float*)d_in[2];
  const float* g1   = (const float*)d_in[3];
  const float* bt1  = (const float*)d_in[4];
  const float* W2   = (const float*)d_in[5];
  const float* g2   = (const float*)d_in[6];
  const float* bt2  = (const float*)d_in[7];
  const float* W3   = (const float*)d_in[8];
  const float* g3   = (const float*)d_in[9];
  const float* bt3  = (const float*)d_in[10];
  const float* W4   = (const float*)d_in[11];
  const float* g4   = (const float*)d_in[12];
  const float* bt4  = (const float*)d_in[13];
  const float* W5   = (const float*)d_in[14];
  const float* g5   = (const float*)d_in[15];
  const float* bt5  = (const float*)d_in[16];
  const float* L1   = (const float*)d_in[17];
  const float* g6   = (const float*)d_in[18];
  const float* bt6  = (const float*)d_in[19];
  const float* L2   = (const float*)d_in[20];
  const float* bl2  = (const float*)d_in[21];
  const float* g7   = (const float*)d_in[22];
  const float* bt7  = (const float*)d_in[23];
  const float* L3   = (const float*)d_in[24];
  const float* bl3  = (const float*)d_in[25];

  char* ws = (char*)d_ws;
  int*       idx   = (int*)(ws + OFF_IDX);
  float*     xt    = (float*)(ws + OFF_XT);
  _Float16*  xcatH = (_Float16*)(ws + OFF_XCATH);
  float*     wt1   = (float*)(ws + OFF_WT1);
  float*     wd1   = (float*)(ws + OFF_WD1);
  _Float16*  b2    = (_Float16*)(ws + OFF_B2);
  _Float16*  s2w   = (_Float16*)(ws + OFF_S2);
  _Float16*  b3    = (_Float16*)(ws + OFF_B3);
  _Float16*  s3w   = (_Float16*)(ws + OFF_S3);
  _Float16*  b4    = (_Float16*)(ws + OFF_B4);
  _Float16*  s4w   = (_Float16*)(ws + OFF_S4);
  _Float16*  b5    = (_Float16*)(ws + OFF_B5);
  float*     sbase = (float*)(ws + OFF_SBASE);
  float*     hmax  = (float*)(ws + OFF_HMAX);
  float*     hmin  = (float*)(ws + OFF_HMIN);
  _Float16*  h5    = (_Float16*)(ws + OFF_H5);
  float*     part  = (float*)(ws + OFF_PART);
  float*     pmean = (float*)(ws + OFF_PMEAN);
  float*     ssb   = (float*)(ws + OFF_SS);
  float*     z     = (float*)(ws + OFF_Z);
  float*     z1p   = (float*)(ws + OFF_Z1P);
  float*     z1    = (float*)(ws + OFF_Z1);
  float*     z2p   = (float*)(ws + OFF_Z2P);
  float*     z2    = (float*)(ws + OFF_Z2);

  const float invE = 1.f / (float)(BN * NK);
  const float inv5 = 1.f / (float)(BN);

  k_transpose_x<<<(NB * 3 * NP + 255) / 256, 256, 0, stream>>>(x, xt);
  k_prep_w<<<1, 256, 0, stream>>>(W1, wt1, wd1, 3, 64);
  k_prep_b<64, 64, 128, false><<<16, 256, 0, stream>>>(W2, b2);
  k_prep_b<64, 64, 128, true><<<16, 256, 0, stream>>>(W2, s2w);
  k_prep_b<64, 128, 128, false><<<32, 256, 0, stream>>>(W3, b3);
  k_prep_b<64, 128, 128, true><<<32, 256, 0, stream>>>(W3, s3w);
  k_prep_b<128, 256, 256, false><<<128, 256, 0, stream>>>(W4, b4);
  k_prep_b<128, 256, 256, true><<<128, 256, 0, stream>>>(W4, s4w);
  k_prep_b<512, 1024, 512, false><<<2048, 256, 0, stream>>>(W5, b5);
  k_topk<<<BN / 4, 256, 0, stream>>>(geod, idx);

  // layer 1 (C=3, fp32)
  k_edge<3, 64><<<2048, 256, 0, stream>>>(xt, 0, 3, idx, wt1, wd1, hmax, hmin, part, 2);
  k_finalize<<<64, 256, 0, stream>>>(part, 2048, 64, invE, g1, bt1, ssb);
  k_edge_apply<<<(BN * 64) / 256, 256, 0, stream>>>(hmax, hmin, ssb, xcatH, 64, 0);
  // layer 2 (C=64 -> O=64), input slice 0
  k_self_mfma<64, 64><<<256, 256, 0, stream>>>(xcatH, 0, s2w, sbase);
  k_edge_mfma<64, 64, 1><<<2048, 256, 0, stream>>>(xcatH, 0, idx, b2, sbase, hmax, hmin, part);
  k_finalize<<<64, 256, 0, stream>>>(part, 2048, 64, invE, g2, bt2, ssb);
  k_edge_apply<<<(BN * 64) / 256, 256, 0, stream>>>(hmax, hmin, ssb, xcatH, 64, 64);
  // layer 3 (C=64 -> O=128), input slice 64
  k_self_mfma<64, 128><<<256, 256, 0, stream>>>(xcatH, 64, s3w, sbase);
  k_edge_mfma<64, 128, 1><<<2048, 256, 0, stream>>>(xcatH, 64, idx, b3, sbase, hmax, hmin, part);
  k_finalize<<<128, 256, 0, stream>>>(part, 2048, 128, invE, g3, bt3, ssb);
  k_edge_apply<<<(BN * 128) / 256, 256, 0, stream>>>(hmax, hmin, ssb, xcatH, 128, 128);
  // layer 4 (C=128 -> O=256), input slice 128, N split in 2
  k_self_mfma<128, 256><<<256, 256, 0, stream>>>(xcatH, 128, s4w, sbase);
  k_edge_mfma<128, 256, 2><<<4096, 256, 0, stream>>>(xcatH, 128, idx, b4, sbase, hmax, hmin, part);
  k_finalize<<<256, 256, 0, stream>>>(part, 2048, 256, invE, g4, bt4, ssb);
  k_edge_apply<<<(BN * 256) / 256, 256, 0, stream>>>(hmax, hmin, ssb, xcatH, 256, 256);

  // conv5 (16384x512 @ 512x1024)
  k_conv5_mfma<<<1024, 256, 0, stream>>>(xcatH, b5, h5, part);
  k_finalize<<<1024, 256, 0, stream>>>(part, 256, 1024, inv5, g5, bt5, ssb);
  k_pool5a<<<256, 256, 0, stream>>>(h5, ssb, pmean);
  k_pool5b<<<32, 256, 0, stream>>>(part, pmean, ssb, z);

  // FC head
  k_fc<<<NB * 512, 64, 0, stream>>>(z, L1, nullptr, z1p, 2048, 512);
  k_bn_fc<<<2, 256, 0, stream>>>(z1p, g6, bt6, z1, 512);
  k_fc<<<NB * 256, 64, 0, stream>>>(z1, L2, bl2, z2p, 512, 256);
  k_bn_fc<<<1, 256, 0, stream>>>(z2p, g7, bt7, z2, 256);
  k_fc<<<NB * 40, 64, 0, stream>>>(z2, L3, bl3, (float*)d_out, 256, 40);
}

// Round 7
// 275.425 us; speedup vs baseline: 6.5344x; 1.0787x over previous
//
#include <hip/hip_runtime.h>
#include <hip/hip_bf16.h>
#include <cstdint>
#include <cstddef>

// Problem constants
#define NB 8
#define NP 2048
#define NK 20
#define BN 16384      // NB*NP

typedef _Float16 half8 __attribute__((ext_vector_type(8)));
typedef float f32x4 __attribute__((ext_vector_type(4)));

__device__ __forceinline__ void gload_lds16(const void* g, void* l) {
  __builtin_amdgcn_global_load_lds(
      (const __attribute__((address_space(1))) unsigned int*)g,
      (__attribute__((address_space(3))) unsigned int*)l, 16, 0, 0);
}

// ---------------- workspace layout (bytes) ----------------
static constexpr size_t OFF_IDX   = 0;                                // int[BN*20]
static constexpr size_t OFF_XT    = OFF_IDX + (size_t)BN*NK*4;        // f32[BN*3]
static constexpr size_t OFF_XCATH = OFF_XT + (size_t)BN*3*4;          // f16[BN*512]
static constexpr size_t OFF_WT1   = OFF_XCATH + (size_t)BN*512*2;
static constexpr size_t OFF_WD1   = OFF_WT1 + 3*64*4;
static constexpr size_t OFF_B2    = OFF_WD1 + 3*64*4;                 // f16[64*64]   W0
static constexpr size_t OFF_S2    = OFF_B2 + (size_t)64*64*2;         // f16[64*64]   W1-W0
static constexpr size_t OFF_B3    = OFF_S2 + (size_t)64*64*2;         // f16[64*128]
static constexpr size_t OFF_S3    = OFF_B3 + (size_t)64*128*2;
static constexpr size_t OFF_B4    = OFF_S3 + (size_t)64*128*2;        // f16[128*256]
static constexpr size_t OFF_S4    = OFF_B4 + (size_t)128*256*2;
static constexpr size_t OFF_B5    = OFF_S4 + (size_t)128*256*2;       // f16[512*1024]
static constexpr size_t OFF_SBASE = OFF_B5 + (size_t)512*1024*2;      // f32[BN*256] self-term
static constexpr size_t OFF_HMAX  = OFF_SBASE + (size_t)BN*256*4;     // f32[BN*256]
static constexpr size_t OFF_HMIN  = OFF_HMAX + (size_t)BN*256*4;      // f32[BN*256]
static constexpr size_t OFF_H5    = OFF_HMAX;                         // f16[BN*1024] overlay (edge bufs dead)
static constexpr size_t OFF_PART  = OFF_HMIN + (size_t)BN*256*4;      // 4 MB partials
static constexpr size_t OFF_PMEAN = OFF_PART + (size_t)4*1024*1024;   // f32[8*8*1024]
static constexpr size_t OFF_SS    = OFF_PMEAN + (size_t)8*8*1024*4;   // f32[2*1024]
static constexpr size_t OFF_Z     = OFF_SS + 2*1024*4;                // f32[8*2048]
static constexpr size_t OFF_Z1P   = OFF_Z + (size_t)NB*2048*4;
static constexpr size_t OFF_Z1    = OFF_Z1P + NB*512*4;
static constexpr size_t OFF_Z2P   = OFF_Z1 + NB*512*4;
static constexpr size_t OFF_Z2    = OFF_Z2P + NB*256*4;
// total ~75 MB

// ---------------- fused prep kernel ----------------
// b-frag order (mfma_f32_16x16x32_f16): lane l, elem e reads
// B[64*ch + 32*ks + 8*(l>>4)+e][16*sl + (l&15)].
__device__ __forceinline__ void prep_b_dev(const float* __restrict__ W,
                                           _Float16* __restrict__ Bp, int t,
                                           int K2, int lgO, int lgRS, bool diff) {
  int O = 1 << lgO;
  int o = t & (O - 1), k = t >> lgO;
  float v;
  if (diff) v = W[((size_t)o << lgRS) + K2 + k] - W[((size_t)o << lgRS) + k];
  else      v = W[((size_t)o << lgRS) + k];
  int ch = k >> 6, ks = (k >> 5) & 1, kg = (k >> 3) & 3, e = k & 7;
  int sl = o >> 4, ol = o & 15;
  size_t flat = (((size_t)(ch * 2 + ks) * (O >> 4) + sl) * 64 + (kg * 16 + ol)) * 8 + e;
  Bp[flat] = (_Float16)v;
}

// segment block offsets
static constexpr int PB_TR = 0;              // 192 blocks: transpose x
static constexpr int PB_W1 = PB_TR + 192;    // 1 block:   wt1/wd1
static constexpr int PB_B2 = PB_W1 + 1;      // 16
static constexpr int PB_S2 = PB_B2 + 16;     // 16
static constexpr int PB_B3 = PB_S2 + 16;     // 32
static constexpr int PB_S3 = PB_B3 + 32;     // 32
static constexpr int PB_B4 = PB_S3 + 32;     // 128
static constexpr int PB_S4 = PB_B4 + 128;    // 128
static constexpr int PB_B5 = PB_S4 + 128;    // 2048
static constexpr int PB_END = PB_B5 + 2048;  // 2593

__global__ __launch_bounds__(256) void k_prep_all(
    const float* __restrict__ x, float* __restrict__ xt,
    const float* __restrict__ W1, float* __restrict__ wt1, float* __restrict__ wd1,
    const float* __restrict__ W2, _Float16* __restrict__ b2, _Float16* __restrict__ s2w,
    const float* __restrict__ W3, _Float16* __restrict__ b3, _Float16* __restrict__ s3w,
    const float* __restrict__ W4, _Float16* __restrict__ b4, _Float16* __restrict__ s4w,
    const float* __restrict__ W5, _Float16* __restrict__ b5) {
  int blk = blockIdx.x, tid = threadIdx.x;
  if (blk < PB_W1) {                       // transpose x (B,3,N)->(B,N,3)
    int t = blk * 256 + tid;
    int n = t & (NP - 1);
    int c = (t / NP) % 3;
    int b = t / (3 * NP);
    xt[(size_t)(b * NP + n) * 3 + c] = x[t];
  } else if (blk < PB_B2) {                // layer-1 weights
    int t = tid;
    if (t < 192) {
      int o = t & 63, c = t >> 6;
      float w0 = W1[o * 6 + c];
      float w1 = W1[o * 6 + 3 + c];
      wt1[c * 64 + o] = w0;
      wd1[c * 64 + o] = w1 - w0;
    }
  } else if (blk < PB_S2) prep_b_dev(W2, b2,  (blk - PB_B2) * 256 + tid, 64, 6, 7, false);
  else if (blk < PB_B3)   prep_b_dev(W2, s2w, (blk - PB_S2) * 256 + tid, 64, 6, 7, true);
  else if (blk < PB_S3)   prep_b_dev(W3, b3,  (blk - PB_B3) * 256 + tid, 64, 7, 7, false);
  else if (blk < PB_B4)   prep_b_dev(W3, s3w, (blk - PB_S3) * 256 + tid, 64, 7, 7, true);
  else if (blk < PB_S4)   prep_b_dev(W4, b4,  (blk - PB_B4) * 256 + tid, 128, 8, 8, false);
  else if (blk < PB_B5)   prep_b_dev(W4, s4w, (blk - PB_S4) * 256 + tid, 128, 8, 8, true);
  else                    prep_b_dev(W5, b5,  (blk - PB_B5) * 256 + tid, 512, 10, 9, false);
}

// top-20 per row of 2048, lowest-index tie-break (matches jax.lax.top_k).
// One wave per row. Per-lane sorted top-3 cache (value+index, branchless
// insertion); value-only butterfly max; ballot + scalar tie-break; rescan
// only when a lane wins a 4th time (E~0.26/row).
__global__ __launch_bounds__(256) void k_topk(const float* __restrict__ geod,
                                              int* __restrict__ idx) {
  int wv = threadIdx.x >> 6, l = threadIdx.x & 63;
  int row = blockIdx.x * 4 + wv;
  const float* g = geod + (size_t)row * NP;
  float4 v[8];
#pragma unroll
  for (int r = 0; r < 8; ++r) v[r] = *(const float4*)&g[r * 256 + l * 4];
  const float NEG = -__builtin_huge_valf();
  unsigned int dead = 0;
  float m1 = NEG, m2 = NEG, m3 = NEG;
  int i1 = 0, i2 = 0, i3 = 0;
#pragma unroll
  for (int r = 0; r < 8; ++r) {
    float vals[4] = {v[r].x, v[r].y, v[r].z, v[r].w};
#pragma unroll
    for (int e = 0; e < 4; ++e) {
      float val = vals[e];
      int gi = r * 256 + l * 4 + e;
      bool c1 = val > m1;
      float t  = c1 ? m1 : val;   int ti  = c1 ? i1 : gi;
      m1 = c1 ? val : m1;         i1 = c1 ? gi : i1;
      bool c2 = t > m2;
      float t2 = c2 ? m2 : t;     int t2i = c2 ? i2 : ti;
      m2 = c2 ? t : m2;           i2 = c2 ? ti : i2;
      bool c3 = t2 > m3;
      m3 = c3 ? t2 : m3;          i3 = c3 ? t2i : i3;
    }
  }
  for (int it = 0; it < NK; ++it) {
    float cv = m1;
#pragma unroll
    for (int s = 1; s < 64; s <<= 1) cv = fmaxf(cv, __shfl_xor(cv, s));
    unsigned long long mask = __ballot(m1 == cv);
    int best_i = 1 << 30, best_l = 0;
    while (mask) {                       // wave-uniform scalar loop, typ. 1 iter
      int L = (int)__builtin_ctzll(mask);
      int ii = __builtin_amdgcn_readlane(i1, L);
      if (ii < best_i) { best_i = ii; best_l = L; }
      mask &= mask - 1;
    }
    if (l == 0) idx[(size_t)row * NK + it] = best_i;
    if (l == best_l) {
      dead |= 1u << (((i1 >> 8) << 2) | (i1 & 3));
      m1 = m2; i1 = i2; m2 = m3; i2 = i3; m3 = NEG; i3 = 0;
      if (m1 == NEG) {                   // cache exhausted (4th win): rescan
#pragma unroll
        for (int r = 0; r < 8; ++r) {
          float vals[4] = {v[r].x, v[r].y, v[r].z, v[r].w};
#pragma unroll
          for (int e = 0; e < 4; ++e) {
            int el = r * 4 + e;
            float val = ((dead >> el) & 1u) ? NEG : vals[e];
            int gi = r * 256 + l * 4 + e;
            bool c1 = val > m1;
            float t  = c1 ? m1 : val;   int ti  = c1 ? i1 : gi;
            m1 = c1 ? val : m1;         i1 = c1 ? gi : i1;
            bool c2 = t > m2;
            float t2 = c2 ? m2 : t;     int t2i = c2 ? i2 : ti;
            m2 = c2 ? t : m2;           i2 = c2 ? ti : i2;
            bool c3 = t2 > m3;
            m3 = c3 ? t2 : m3;          i3 = c3 ? t2i : i3;
          }
        }
      }
    }
  }
}

// ---------------- layer-1 EdgeConv (C=3): whole-cloud-in-LDS ----------------
// One block per (batch, 32-point group). Entire xt[b] (24KB) staged once,
// coalesced; neighbor reads are LDS broadcasts (lane-uniform). Wave w owns
// points p0+{w*8..w*8+7}; lane = output channel o.
__global__ __launch_bounds__(256) void k_edge1(
    const float* __restrict__ xt, const int* __restrict__ idx,
    const float* __restrict__ wt1, const float* __restrict__ wd1,
    float* __restrict__ hmax, float* __restrict__ hmin,
    float* __restrict__ part) {
  __shared__ float xl[NP * 3];          // 24KB
  __shared__ int lidx[32 * NK];
  __shared__ float red[256];
  int tid = threadIdx.x;
  int b = blockIdx.x >> 6;
  int grp = blockIdx.x & 63;
  int p0 = grp * 32;
  for (int u = tid; u < NP * 3; u += 256) xl[u] = xt[(size_t)b * NP * 3 + u];
  for (int u = tid; u < 32 * NK; u += 256) lidx[u] = idx[((size_t)b * NP + p0) * NK + u];
  __syncthreads();
  int o = tid & 63;
  int pb = tid >> 6;
  float w0 = wt1[o], w1 = wt1[64 + o], w2 = wt1[128 + o];
  float d0 = wd1[o], d1 = wd1[64 + o], d2 = wd1[128 + o];
  float ps = 0.f, ps2 = 0.f;
#pragma unroll
  for (int i = 0; i < 8; ++i) {
    int pp = pb * 8 + i;
    int p = p0 + pp;
    float base = xl[p * 3] * d0 + xl[p * 3 + 1] * d1 + xl[p * 3 + 2] * d2;
    float mx = -3.4e38f, mn = 3.4e38f;
    for (int j = 0; j < NK; ++j) {
      int nb = lidx[pp * NK + j];
      float h = base + xl[nb * 3] * w0 + xl[nb * 3 + 1] * w1 + xl[nb * 3 + 2] * w2;
      mx = fmaxf(mx, h); mn = fminf(mn, h);
      ps += h; ps2 += h * h;
    }
    size_t P = (size_t)b * NP + p;
    hmax[P * 64 + o] = mx;
    hmin[P * 64 + o] = mn;
  }
  red[tid] = ps;
  __syncthreads();
  if (tid < 64) {
    float a = red[tid] + red[64 + tid] + red[128 + tid] + red[192 + tid];
    part[(size_t)blockIdx.x * 64 + tid] = a;
  }
  __syncthreads();
  red[tid] = ps2;
  __syncthreads();
  if (tid < 64) {
    float a = red[tid] + red[64 + tid] + red[128 + tid] + red[192 + tid];
    part[((size_t)gridDim.x + blockIdx.x) * 64 + tid] = a;
  }
}

// ---------------- self-term GEMM: sbase[p][o] = x[p]·(W1-W0) ----------------
// conv5-like structure: 64 rows/block, O cols, 4 waves (mg 2 x ng 2).
template <int C, int O>
__global__ __launch_bounds__(256) void k_self_mfma(
    const _Float16* __restrict__ xh, int in_off,
    const _Float16* __restrict__ Bp, float* __restrict__ sbase) {
  constexpr int NCH = C / 64;
  constexpr int NSLO = O / 16;
  constexpr int NS = NSLO / 2;       // 16-col slices per wave
  constexpr int PAIRS = 2 * NSLO;
  __shared__ __align__(16) _Float16 ldsA[64 * 64];
  __shared__ __align__(16) _Float16 ldsB[PAIRS * 512];
  int tid = threadIdx.x, wv = tid >> 6, l = tid & 63;
  int m0 = blockIdx.x * 64;
  int mg = wv & 1, ng = wv >> 1;
  f32x4 acc[2][NS];
#pragma unroll
  for (int m = 0; m < 2; ++m)
#pragma unroll
    for (int s = 0; s < NS; ++s)
#pragma unroll
      for (int r = 0; r < 4; ++r) acc[m][s][r] = 0.f;

  for (int ch = 0; ch < NCH; ++ch) {
#pragma unroll
    for (int it = 0; it < 2; ++it) {
      int r0 = wv * 16 + it * 8;
      int R = r0 + (l >> 3);
      int q = (l & 7) ^ (l >> 3);
      gload_lds16(xh + (size_t)(m0 + R) * 512 + in_off + ch * 64 + q * 8, ldsA + r0 * 64);
    }
    for (int u = wv; u < PAIRS; u += 4) {
      int ks = u / NSLO, sloc = u - ks * NSLO;
      gload_lds16(Bp + ((size_t)((ch * 2 + ks) * NSLO + sloc) * 64 + l) * 8,
                  ldsB + u * 512);
    }
    __syncthreads();
#pragma unroll
    for (int ks = 0; ks < 2; ++ks) {
      half8 b[NS];
#pragma unroll
      for (int s = 0; s < NS; ++s)
        b[s] = *(const half8*)(ldsB + (ks * NSLO + ng * NS + s) * 512 + l * 8);
#pragma unroll
      for (int mt = 0; mt < 2; ++mt) {
        int row = mg * 32 + mt * 16 + (l & 15);
        int slot = (ks * 4 + (l >> 4)) ^ (row & 7);
        half8 a = *(const half8*)(ldsA + row * 64 + slot * 8);
#pragma unroll
        for (int s = 0; s < NS; ++s)
          acc[mt][s] = __builtin_amdgcn_mfma_f32_16x16x32_f16(a, b[s], acc[mt][s], 0, 0, 0);
      }
    }
    __syncthreads();
  }
  int g = l >> 4;
#pragma unroll
  for (int s = 0; s < NS; ++s) {
    int col = ng * (NS * 16) + s * 16 + (l & 15);
#pragma unroll
    for (int mt = 0; mt < 2; ++mt)
#pragma unroll
      for (int r = 0; r < 4; ++r) {
        int row = m0 + mg * 32 + mt * 16 + 4 * g + r;
        sbase[(size_t)row * O + col] = acc[mt][s][r];
      }
  }
}

// ---------------- MFMA EdgeConv neighbor-GEMM (layers 2-4), K = C ----------------
// A-row r (0..79 within 80-row wave group) -> point pp=(r>>2)&3, j=4*(r>>4)+(r&3):
// each lane's C-fragment holds all 20 j of a single point -> lane-local max.
// Self-term (j-invariant) comes from sbase[], added in the epilogue.
template <int C, int O, int NSPLIT>
__global__ __launch_bounds__(256) void k_edge_mfma(
    const _Float16* __restrict__ xh, int in_off,
    const int* __restrict__ idx,
    const _Float16* __restrict__ Bp, const float* __restrict__ sbase,
    float* __restrict__ hmax, float* __restrict__ hmin,
    float* __restrict__ part) {
  constexpr int NCH = C / 64;        // 64-wide K chunks
  constexpr int NO = O / NSPLIT;     // columns handled by this block
  constexpr int NSLO = NO / 16;      // 16-col slices in block
  constexpr int NS = NSLO / 2;       // slices per wave (2 ng-groups)
  constexpr int PAIRS = 2 * NSLO;    // (ks, slice) B sub-tiles per chunk
  __shared__ __align__(16) _Float16 ldsA[160 * 64];   // 20KB, XOR-swizzled
  __shared__ __align__(16) _Float16 ldsB[PAIRS * 512];
  __shared__ float ldsS[2][NO], ldsQ[2][NO];
  int tid = threadIdx.x, wv = tid >> 6, l = tid & 63;
  int mblk = blockIdx.x, nid = 0;
  if (NSPLIT > 1) { nid = mblk >> 11; mblk &= 2047; }
  int p0 = mblk * 8;                 // 8 points per block
  int bbase = p0 & ~(NP - 1);
  int n_base = nid * NO;
  int mg = wv & 1, ng = wv >> 1;
  f32x4 acc[5][NS];
#pragma unroll
  for (int m = 0; m < 5; ++m)
#pragma unroll
    for (int s = 0; s < NS; ++s)
#pragma unroll
      for (int r = 0; r < 4; ++r) acc[m][s][r] = 0.f;

  for (int ch = 0; ch < NCH; ++ch) {
    int cbase = ch * 64;
    // stage A: wave stages rows [40*wv, 40*wv+40), 8 rows (1024B) per issue.
    // source pre-swizzled: lane slot (l&7) holds source 16B-segment q=(l&7)^(l>>3).
#pragma unroll
    for (int it = 0; it < 5; ++it) {
      int r0 = wv * 40 + it * 8;
      int R = r0 + (l >> 3);
      int mgR = R / 80;
      int r = R - mgR * 80;
      int pp = 4 * mgR + ((r >> 2) & 3);
      int j = ((r >> 4) << 2) | (r & 3);
      int p = p0 + pp;
      int srcn = bbase + idx[p * NK + j];
      int q = (l & 7) ^ (l >> 3);
      gload_lds16(xh + (size_t)srcn * 512 + in_off + cbase + q * 8, ldsA + r0 * 64);
    }
    // stage B chunk (already in frag order)
    for (int u = wv; u < PAIRS; u += 4) {
      int ks = u / NSLO, sloc = u - ks * NSLO;
      gload_lds16(Bp + ((size_t)((ch * 2 + ks) * (O / 16) + (n_base >> 4) + sloc) * 64 + l) * 8,
                  ldsB + u * 512);
    }
    __syncthreads();
#pragma unroll
    for (int ks = 0; ks < 2; ++ks) {
      half8 b[NS];
#pragma unroll
      for (int s = 0; s < NS; ++s)
        b[s] = *(const half8*)(ldsB + (ks * NSLO + ng * NS + s) * 512 + l * 8);
#pragma unroll
      for (int mt = 0; mt < 5; ++mt) {
        int row = mg * 80 + mt * 16 + (l & 15);
        int slot = (ks * 4 + (l >> 4)) ^ (row & 7);
        half8 a = *(const half8*)(ldsA + row * 64 + slot * 8);
#pragma unroll
        for (int s = 0; s < NS; ++s)
          acc[mt][s] = __builtin_amdgcn_mfma_f32_16x16x32_f16(a, b[s], acc[mt][s], 0, 0, 0);
      }
    }
    __syncthreads();
  }
  // epilogue: add j-invariant self-term, lane-local j-max/min per point;
  // cross-lane only for BN stats
  int g = l >> 4;
  int p = p0 + 4 * mg + g;
#pragma unroll
  for (int s = 0; s < NS; ++s) {
    int colL = ng * (NS * 16) + s * 16 + (l & 15);
    float sb = sbase[(size_t)p * O + n_base + colL];
    float mx = -3.4e38f, mn = 3.4e38f, sm = 0.f, sq = 0.f;
#pragma unroll
    for (int mt = 0; mt < 5; ++mt)
#pragma unroll
      for (int r = 0; r < 4; ++r) {
        float v = acc[mt][s][r] + sb;
        mx = fmaxf(mx, v); mn = fminf(mn, v); sm += v; sq += v * v;
      }
    hmax[(size_t)p * O + n_base + colL] = mx;
    hmin[(size_t)p * O + n_base + colL] = mn;
    sm += __shfl_xor(sm, 16); sm += __shfl_xor(sm, 32);
    sq += __shfl_xor(sq, 16); sq += __shfl_xor(sq, 32);
    if (l < 16) {
      ldsS[mg][ng * (NS * 16) + s * 16 + l] = sm;
      ldsQ[mg][ng * (NS * 16) + s * 16 + l] = sq;
    }
  }
  __syncthreads();
  for (int u = tid; u < NO; u += 256) {
    part[(size_t)mblk * O + n_base + u] = ldsS[0][u] + ldsS[1][u];
    part[((size_t)2048 + mblk) * O + n_base + u] = ldsQ[0][u] + ldsQ[1][u];
  }
}

// ---------------- conv5 MFMA: h5 = xcatH(16384x512) * B5(512x1024) ----------------
__global__ __launch_bounds__(256) void k_conv5_mfma(
    const _Float16* __restrict__ xh, const _Float16* __restrict__ Bp,
    _Float16* __restrict__ h5, float* __restrict__ part) {
  __shared__ __align__(16) _Float16 ldsA[64 * 64];     // 8KB
  __shared__ __align__(16) _Float16 ldsB[32 * 512];    // 32KB
  __shared__ float ldsS[2][256], ldsQ[2][256], ldsMx[2][256], ldsMn[2][256];
  int tid = threadIdx.x, wv = tid >> 6, l = tid & 63;
  int mblk = blockIdx.x & 255, nid = blockIdx.x >> 8;
  int m0 = mblk * 64;
  int n_base = nid * 256;
  int mg = wv & 1, ng = wv >> 1;
  f32x4 acc[2][8];
#pragma unroll
  for (int m = 0; m < 2; ++m)
#pragma unroll
    for (int s = 0; s < 8; ++s)
#pragma unroll
      for (int r = 0; r < 4; ++r) acc[m][s][r] = 0.f;

  for (int ch = 0; ch < 8; ++ch) {
#pragma unroll
    for (int it = 0; it < 2; ++it) {
      int r0 = wv * 16 + it * 8;
      int R = r0 + (l >> 3);
      int q = (l & 7) ^ (l >> 3);
      gload_lds16(xh + (size_t)(m0 + R) * 512 + ch * 64 + q * 8, ldsA + r0 * 64);
    }
    for (int u = wv; u < 32; u += 4) {
      int ks = u >> 4, sloc = u & 15;
      gload_lds16(Bp + ((size_t)((ch * 2 + ks) * 64 + (n_base >> 4) + sloc) * 64 + l) * 8,
                  ldsB + u * 512);
    }
    __syncthreads();
#pragma unroll
    for (int ks = 0; ks < 2; ++ks) {
      half8 b[8];
#pragma unroll
      for (int s = 0; s < 8; ++s)
        b[s] = *(const half8*)(ldsB + (ks * 16 + ng * 8 + s) * 512 + l * 8);
#pragma unroll
      for (int mt = 0; mt < 2; ++mt) {
        int row = mg * 32 + mt * 16 + (l & 15);
        int slot = (ks * 4 + (l >> 4)) ^ (row & 7);
        half8 a = *(const half8*)(ldsA + row * 64 + slot * 8);
#pragma unroll
        for (int s = 0; s < 8; ++s)
          acc[mt][s] = __builtin_amdgcn_mfma_f32_16x16x32_f16(a, b[s], acc[mt][s], 0, 0, 0);
      }
    }
    __syncthreads();
  }
  int g = l >> 4;
#pragma unroll
  for (int s = 0; s < 8; ++s) {
    float sm = 0.f, sq = 0.f, mx = -3.4e38f, mn = 3.4e38f;
    int col = n_base + ng * 128 + s * 16 + (l & 15);
#pragma unroll
    for (int mt = 0; mt < 2; ++mt)
#pragma unroll
      for (int r = 0; r < 4; ++r) {
        float v = acc[mt][s][r];
        int row = m0 + mg * 32 + mt * 16 + 4 * g + r;
        h5[(size_t)row * 1024 + col] = (_Float16)v;
        sm += v; sq += v * v; mx = fmaxf(mx, v); mn = fminf(mn, v);
      }
    sm += __shfl_xor(sm, 16); sm += __shfl_xor(sm, 32);
    sq += __shfl_xor(sq, 16); sq += __shfl_xor(sq, 32);
    mx = fmaxf(mx, __shfl_xor(mx, 16)); mx = fmaxf(mx, __shfl_xor(mx, 32));
    mn = fminf(mn, __shfl_xor(mn, 16)); mn = fminf(mn, __shfl_xor(mn, 32));
    if (l < 16) {
      int u = ng * 128 + s * 16 + l;
      ldsS[mg][u] = sm; ldsQ[mg][u] = sq; ldsMx[mg][u] = mx; ldsMn[mg][u] = mn;
    }
  }
  __syncthreads();
  {
    int u = tid;
    int col = n_base + u;
    part[(size_t)mblk * 1024 + col] = ldsS[0][u] + ldsS[1][u];
    part[((size_t)256 + mblk) * 1024 + col] = ldsQ[0][u] + ldsQ[1][u];
    part[((size_t)512 + mblk) * 1024 + col] = fmaxf(ldsMx[0][u], ldsMx[1][u]);
    part[((size_t)768 + mblk) * 1024 + col] = fminf(ldsMn[0][u], ldsMn[1][u]);
  }
}

// reduce partials -> per-channel BN scale/shift. grid = O blocks.
__global__ __launch_bounds__(256) void k_finalize(
    const float* __restrict__ part, int G, int O, float inv_count,
    const float* __restrict__ gamma, const float* __restrict__ beta,
    float* __restrict__ ss) {
  int o = blockIdx.x;
  float s = 0.f, s2 = 0.f;
  for (int g = threadIdx.x; g < G; g += 256) {
    s  += part[(size_t)g * O + o];
    s2 += part[((size_t)G + g) * O + o];
  }
#pragma unroll
  for (int sft = 32; sft; sft >>= 1) {
    s  += __shfl_down(s, sft);
    s2 += __shfl_down(s2, sft);
  }
  __shared__ float aw[4], aw2[4];
  int w = threadIdx.x >> 6;
  if ((threadIdx.x & 63) == 0) { aw[w] = s; aw2[w] = s2; }
  __syncthreads();
  if (threadIdx.x == 0) {
    s = aw[0] + aw[1] + aw[2] + aw[3];
    s2 = aw2[0] + aw2[1] + aw2[2] + aw2[3];
    float m   = s * inv_count;
    float var = s2 * inv_count - m * m;
    float scale = gamma[o] * rsqrtf(var + 1e-5f);
    ss[o]     = scale;
    ss[O + o] = beta[o] - m * scale;
  }
}

// apply BN+lrelu to (max or min per sign of scale), write fp16 into xcatH slice
__global__ void k_edge_apply(const float* __restrict__ hmax, const float* __restrict__ hmin,
                             const float* __restrict__ ss, _Float16* __restrict__ xh,
                             int O, int off) {
  int t = blockIdx.x * 256 + threadIdx.x;
  int o = t % O;
  int p = t / O;
  float scale = ss[o], shift = ss[O + o];
  float v = (scale >= 0.f) ? hmax[t] : hmin[t];
  v = scale * v + shift;
  v = (v >= 0.f) ? v : 0.2f * v;
  xh[(size_t)p * 512 + off + o] = (_Float16)v;
}

// conv5 mean-pool partials: grid = 8b*8ns*4cg = 256 blocks
__global__ __launch_bounds__(256) void k_pool5a(const _Float16* __restrict__ h5,
                                                const float* __restrict__ ss,
                                                float* __restrict__ pmean) {
  int bi = blockIdx.x;
  int b = bi >> 5, ns = (bi >> 2) & 7, cg = bi & 3;
  int col = cg * 256 + threadIdx.x;
  float scale = ss[col], shift = ss[1024 + col];
  float sm = 0.f;
  for (int n = ns * 256; n < ns * 256 + 256; ++n) {
    float v = (float)h5[(size_t)(b * 2048 + n) * 1024 + col];
    float y = scale * v + shift;
    y = (y >= 0.f) ? y : 0.2f * y;
    sm += y;
  }
  pmean[(size_t)(b * 8 + ns) * 1024 + col] = sm;
}

// final pool: exact max via fp32 partials (BN+lrelu commute), mean via pmean
__global__ __launch_bounds__(256) void k_pool5b(const float* __restrict__ part,
                                                const float* __restrict__ pmean,
                                                const float* __restrict__ ss,
                                                float* __restrict__ z) {
  int bi = blockIdx.x;
  int b = bi >> 2, cg = bi & 3;
  int col = cg * 256 + threadIdx.x;
  float scale = ss[col], shift = ss[1024 + col];
  const float* pmx = part + (size_t)512 * 1024;
  const float* pmn = part + (size_t)768 * 1024;
  float mxh = -3.4e38f, mnh = 3.4e38f;
  for (int q = 0; q < 32; ++q) {
    size_t base = (size_t)(b * 32 + q) * 1024 + col;
    mxh = fmaxf(mxh, pmx[base]);
    mnh = fminf(mnh, pmn[base]);
  }
  float hsel = (scale >= 0.f) ? mxh : mnh;
  float zmax = scale * hsel + shift;
  zmax = (zmax >= 0.f) ? zmax : 0.2f * zmax;
  float sm = 0.f;
  for (int ns = 0; ns < 8; ++ns) sm += pmean[(size_t)(b * 8 + ns) * 1024 + col];
  z[b * 2048 + col] = zmax;
  z[b * 2048 + 1024 + col] = sm * (1.f / 2048.f);
}

// generic FC: one wave per (b,o)
__global__ __launch_bounds__(64) void k_fc(const float* __restrict__ in,
                                           const float* __restrict__ Wf,
                                           const float* __restrict__ bias,
                                           float* __restrict__ out, int IN, int O) {
  int blk = blockIdx.x;
  int b = blk / O, o = blk % O;
  const float* a = in + (size_t)b * IN;
  const float* w = Wf + (size_t)o * IN;
  float s = 0.f;
  for (int i = threadIdx.x; i < IN; i += 64) s += a[i] * w[i];
#pragma unroll
  for (int sft = 32; sft; sft >>= 1) s += __shfl_down(s, sft);
  if (threadIdx.x == 0) out[(size_t)b * O + o] = s + (bias ? bias[o] : 0.f);
}

// batch-axis BN (count=8) + lrelu
__global__ void k_bn_fc(const float* __restrict__ pre, const float* __restrict__ gamma,
                        const float* __restrict__ beta, float* __restrict__ out, int O) {
  int o = blockIdx.x * 256 + threadIdx.x;
  if (o >= O) return;
  float v[NB];
  float s = 0.f, s2 = 0.f;
#pragma unroll
  for (int b = 0; b < NB; ++b) {
    v[b] = pre[(size_t)b * O + o];
    s += v[b]; s2 += v[b] * v[b];
  }
  float m = s * (1.f / NB);
  float var = s2 * (1.f / NB) - m * m;
  float scale = gamma[o] * rsqrtf(var + 1e-5f);
  float shift = beta[o] - m * scale;
#pragma unroll
  for (int b = 0; b < NB; ++b) {
    float x = scale * v[b] + shift;
    out[(size_t)b * O + o] = (x >= 0.f) ? x : 0.2f * x;
  }
}

// ---------------- launcher ----------------
extern "C" void kernel_launch(void* const* d_in, const int* in_sizes, int n_in,
                              void* d_out, int out_size, void* d_ws, size_t ws_size,
                              hipStream_t stream) {
  (void)in_sizes; (void)n_in; (void)out_size; (void)ws_size;
  const float* x    = (const float*)d_in[0];
  const float* geod = (const float*)d_in[1];
  const float* W1   = (const float*)d_in[2];
  const float* g1   = (const float*)d_in[3];
  const float* bt1  = (const float*)d_in[4];
  const float* W2   = (const float*)d_in[5];
  const float* g2   = (const float*)d_in[6];
  const float* bt2  = (const float*)d_in[7];
  const float* W3   = (const float*)d_in[8];
  const float* g3   = (const float*)d_in[9];
  const float* bt3  = (const float*)d_in[10];
  const float* W4   = (const float*)d_in[11];
  const float* g4   = (const float*)d_in[12];
  const float* bt4  = (const float*)d_in[13];
  const float* W5   = (const float*)d_in[14];
  const float* g5   = (const float*)d_in[15];
  const float* bt5  = (const float*)d_in[16];
  const float* L1   = (const float*)d_in[17];
  const float* g6   = (const float*)d_in[18];
  const float* bt6  = (const float*)d_in[19];
  const float* L2   = (const float*)d_in[20];
  const float* bl2  = (const float*)d_in[21];
  const float* g7   = (const float*)d_in[22];
  const float* bt7  = (const float*)d_in[23];
  const float* L3   = (const float*)d_in[24];
  const float* bl3  = (const float*)d_in[25];

  char* ws = (char*)d_ws;
  int*       idx   = (int*)(ws + OFF_IDX);
  float*     xt    = (float*)(ws + OFF_XT);
  _Float16*  xcatH = (_Float16*)(ws + OFF_XCATH);
  float*     wt1   = (float*)(ws + OFF_WT1);
  float*     wd1   = (float*)(ws + OFF_WD1);
  _Float16*  b2    = (_Float16*)(ws + OFF_B2);
  _Float16*  s2w   = (_Float16*)(ws + OFF_S2);
  _Float16*  b3    = (_Float16*)(ws + OFF_B3);
  _Float16*  s3w   = (_Float16*)(ws + OFF_S3);
  _Float16*  b4    = (_Float16*)(ws + OFF_B4);
  _Float16*  s4w   = (_Float16*)(ws + OFF_S4);
  _Float16*  b5    = (_Float16*)(ws + OFF_B5);
  float*     sbase = (float*)(ws + OFF_SBASE);
  float*     hmax  = (float*)(ws + OFF_HMAX);
  float*     hmin  = (float*)(ws + OFF_HMIN);
  _Float16*  h5    = (_Float16*)(ws + OFF_H5);
  float*     part  = (float*)(ws + OFF_PART);
  float*     pmean = (float*)(ws + OFF_PMEAN);
  float*     ssb   = (float*)(ws + OFF_SS);
  float*     z     = (float*)(ws + OFF_Z);
  float*     z1p   = (float*)(ws + OFF_Z1P);
  float*     z1    = (float*)(ws + OFF_Z1);
  float*     z2p   = (float*)(ws + OFF_Z2P);
  float*     z2    = (float*)(ws + OFF_Z2);

  const float invE = 1.f / (float)(BN * NK);
  const float inv5 = 1.f / (float)(BN);

  k_prep_all<<<PB_END, 256, 0, stream>>>(x, xt, W1, wt1, wd1,
                                         W2, b2, s2w, W3, b3, s3w,
                                         W4, b4, s4w, W5, b5);
  k_topk<<<BN / 4, 256, 0, stream>>>(geod, idx);

  // layer 1 (C=3, fp32, whole-cloud LDS)
  k_edge1<<<512, 256, 0, stream>>>(xt, idx, wt1, wd1, hmax, hmin, part);
  k_finalize<<<64, 256, 0, stream>>>(part, 512, 64, invE, g1, bt1, ssb);
  k_edge_apply<<<(BN * 64) / 256, 256, 0, stream>>>(hmax, hmin, ssb, xcatH, 64, 0);
  // layer 2 (C=64 -> O=64), input slice 0
  k_self_mfma<64, 64><<<256, 256, 0, stream>>>(xcatH, 0, s2w, sbase);
  k_edge_mfma<64, 64, 1><<<2048, 256, 0, stream>>>(xcatH, 0, idx, b2, sbase, hmax, hmin, part);
  k_finalize<<<64, 256, 0, stream>>>(part, 2048, 64, invE, g2, bt2, ssb);
  k_edge_apply<<<(BN * 64) / 256, 256, 0, stream>>>(hmax, hmin, ssb, xcatH, 64, 64);
  // layer 3 (C=64 -> O=128), input slice 64
  k_self_mfma<64, 128><<<256, 256, 0, stream>>>(xcatH, 64, s3w, sbase);
  k_edge_mfma<64, 128, 1><<<2048, 256, 0, stream>>>(xcatH, 64, idx, b3, sbase, hmax, hmin, part);
  k_finalize<<<128, 256, 0, stream>>>(part, 2048, 128, invE, g3, bt3, ssb);
  k_edge_apply<<<(BN * 128) / 256, 256, 0, stream>>>(hmax, hmin, ssb, xcatH, 128, 128);
  // layer 4 (C=128 -> O=256), input slice 128, N split in 2
  k_self_mfma<128, 256><<<256, 256, 0, stream>>>(xcatH, 128, s4w, sbase);
  k_edge_mfma<128, 256, 2><<<4096, 256, 0, stream>>>(xcatH, 128, idx, b4, sbase, hmax, hmin, part);
  k_finalize<<<256, 256, 0, stream>>>(part, 2048, 256, invE, g4, bt4, ssb);
  k_edge_apply<<<(BN * 256) / 256, 256, 0, stream>>>(hmax, hmin, ssb, xcatH, 256, 256);

  // conv5 (16384x512 @ 512x1024)
  k_conv5_mfma<<<1024, 256, 0, stream>>>(xcatH, b5, h5, part);
  k_finalize<<<1024, 256, 0, stream>>>(part, 256, 1024, inv5, g5, bt5, ssb);
  k_pool5a<<<256, 256, 0, stream>>>(h5, ssb, pmean);
  k_pool5b<<<32, 256, 0, stream>>>(part, pmean, ssb, z);

  // FC head
  k_fc<<<NB * 512, 64, 0, stream>>>(z, L1, nullptr, z1p, 2048, 512);
  k_bn_fc<<<2, 256, 0, stream>>>(z1p, g6, bt6, z1, 512);
  k_fc<<<NB * 256, 64, 0, stream>>>(z1, L2, bl2, z2p, 512, 256);
  k_bn_fc<<<1, 256, 0, stream>>>(z2p, g7, bt7, z2, 256);
  k_fc<<<NB * 40, 64, 0, stream>>>(z2, L3, bl3, (float*)d_out, 256, 40);
}

// Round 8
// 269.718 us; speedup vs baseline: 6.6727x; 1.0212x over previous
//
#include <hip/hip_runtime.h>
#include <hip/hip_bf16.h>
#include <cstdint>
#include <cstddef>

// Problem constants
#define NB 8
#define NP 2048
#define NK 20
#define BN 16384      // NB*NP

typedef _Float16 half8 __attribute__((ext_vector_type(8)));
typedef float f32x4 __attribute__((ext_vector_type(4)));

__device__ __forceinline__ void gload_lds16(const void* g, void* l) {
  __builtin_amdgcn_global_load_lds(
      (const __attribute__((address_space(1))) unsigned int*)g,
      (__attribute__((address_space(3))) unsigned int*)l, 16, 0, 0);
}

// ---------------- workspace layout (bytes) ----------------
static constexpr size_t OFF_IDX   = 0;                                // int[BN*20]
static constexpr size_t OFF_XT    = OFF_IDX + (size_t)BN*NK*4;        // f32[BN*3]
static constexpr size_t OFF_XCATH = OFF_XT + (size_t)BN*3*4;          // f16[BN*512]
static constexpr size_t OFF_WT1   = OFF_XCATH + (size_t)BN*512*2;
static constexpr size_t OFF_WD1   = OFF_WT1 + 3*64*4;
static constexpr size_t OFF_B2    = OFF_WD1 + 3*64*4;                 // f16[64*64]   W0
static constexpr size_t OFF_S2    = OFF_B2 + (size_t)64*64*2;         // f16[64*64]   W1-W0
static constexpr size_t OFF_B3    = OFF_S2 + (size_t)64*64*2;         // f16[64*128]
static constexpr size_t OFF_S3    = OFF_B3 + (size_t)64*128*2;
static constexpr size_t OFF_B4    = OFF_S3 + (size_t)64*128*2;        // f16[128*256]
static constexpr size_t OFF_S4    = OFF_B4 + (size_t)128*256*2;
static constexpr size_t OFF_B5    = OFF_S4 + (size_t)128*256*2;       // f16[512*1024]
static constexpr size_t OFF_SBASE = OFF_B5 + (size_t)512*1024*2;      // f32[BN*256] self-term
static constexpr size_t OFF_HMAX  = OFF_SBASE + (size_t)BN*256*4;     // f32[BN*256]
static constexpr size_t OFF_HMIN  = OFF_HMAX + (size_t)BN*256*4;      // f32[BN*256]
static constexpr size_t OFF_H5    = OFF_HMAX;                         // f16[BN*1024] overlay (edge bufs dead)
static constexpr size_t OFF_PART  = OFF_HMIN + (size_t)BN*256*4;      // 4 MB partials
static constexpr size_t OFF_PMEAN = OFF_PART + (size_t)4*1024*1024;   // f32[8*8*1024]
static constexpr size_t OFF_SS    = OFF_PMEAN + (size_t)8*8*1024*4;   // f32[2*1024]
static constexpr size_t OFF_Z     = OFF_SS + 2*1024*4;                // f32[8*2048]
static constexpr size_t OFF_Z1P   = OFF_Z + (size_t)NB*2048*4;
static constexpr size_t OFF_Z1    = OFF_Z1P + NB*512*4;
static constexpr size_t OFF_Z2P   = OFF_Z1 + NB*512*4;
static constexpr size_t OFF_Z2    = OFF_Z2P + NB*256*4;
// total ~75 MB

// ---------------- fused prep kernel ----------------
// b-frag order (mfma_f32_16x16x32_f16): lane l, elem e reads
// B[64*ch + 32*ks + 8*(l>>4)+e][16*sl + (l&15)].
__device__ __forceinline__ void prep_b_dev(const float* __restrict__ W,
                                           _Float16* __restrict__ Bp, int t,
                                           int K2, int lgO, int lgRS, bool diff) {
  int O = 1 << lgO;
  int o = t & (O - 1), k = t >> lgO;
  float v;
  if (diff) v = W[((size_t)o << lgRS) + K2 + k] - W[((size_t)o << lgRS) + k];
  else      v = W[((size_t)o << lgRS) + k];
  int ch = k >> 6, ks = (k >> 5) & 1, kg = (k >> 3) & 3, e = k & 7;
  int sl = o >> 4, ol = o & 15;
  size_t flat = (((size_t)(ch * 2 + ks) * (O >> 4) + sl) * 64 + (kg * 16 + ol)) * 8 + e;
  Bp[flat] = (_Float16)v;
}

// segment block offsets
static constexpr int PB_TR = 0;              // 192 blocks: transpose x
static constexpr int PB_W1 = PB_TR + 192;    // 1 block:   wt1/wd1
static constexpr int PB_B2 = PB_W1 + 1;      // 16
static constexpr int PB_S2 = PB_B2 + 16;     // 16
static constexpr int PB_B3 = PB_S2 + 16;     // 32
static constexpr int PB_S3 = PB_B3 + 32;     // 32
static constexpr int PB_B4 = PB_S3 + 32;     // 128
static constexpr int PB_S4 = PB_B4 + 128;    // 128
static constexpr int PB_B5 = PB_S4 + 128;    // 2048
static constexpr int PB_END = PB_B5 + 2048;  // 2593

__global__ __launch_bounds__(256) void k_prep_all(
    const float* __restrict__ x, float* __restrict__ xt,
    const float* __restrict__ W1, float* __restrict__ wt1, float* __restrict__ wd1,
    const float* __restrict__ W2, _Float16* __restrict__ b2, _Float16* __restrict__ s2w,
    const float* __restrict__ W3, _Float16* __restrict__ b3, _Float16* __restrict__ s3w,
    const float* __restrict__ W4, _Float16* __restrict__ b4, _Float16* __restrict__ s4w,
    const float* __restrict__ W5, _Float16* __restrict__ b5) {
  int blk = blockIdx.x, tid = threadIdx.x;
  if (blk < PB_W1) {                       // transpose x (B,3,N)->(B,N,3)
    int t = blk * 256 + tid;
    int n = t & (NP - 1);
    int c = (t / NP) % 3;
    int b = t / (3 * NP);
    xt[(size_t)(b * NP + n) * 3 + c] = x[t];
  } else if (blk < PB_B2) {                // layer-1 weights
    int t = tid;
    if (t < 192) {
      int o = t & 63, c = t >> 6;
      float w0 = W1[o * 6 + c];
      float w1 = W1[o * 6 + 3 + c];
      wt1[c * 64 + o] = w0;
      wd1[c * 64 + o] = w1 - w0;
    }
  } else if (blk < PB_S2) prep_b_dev(W2, b2,  (blk - PB_B2) * 256 + tid, 64, 6, 7, false);
  else if (blk < PB_B3)   prep_b_dev(W2, s2w, (blk - PB_S2) * 256 + tid, 64, 6, 7, true);
  else if (blk < PB_S3)   prep_b_dev(W3, b3,  (blk - PB_B3) * 256 + tid, 64, 7, 7, false);
  else if (blk < PB_B4)   prep_b_dev(W3, s3w, (blk - PB_S3) * 256 + tid, 64, 7, 7, true);
  else if (blk < PB_S4)   prep_b_dev(W4, b4,  (blk - PB_B4) * 256 + tid, 128, 8, 8, false);
  else if (blk < PB_B5)   prep_b_dev(W4, s4w, (blk - PB_S4) * 256 + tid, 128, 8, 8, true);
  else                    prep_b_dev(W5, b5,  (blk - PB_B5) * 256 + tid, 512, 10, 9, false);
}

// ---------------- top-20 (exact jax.lax.top_k semantics) ----------------
// TWO independent rows per wave, iterations interleaved: the two dependent
// 6-step shfl_xor max chains issue back-to-back (2x ILP on the latency-
// critical path). Per-lane sorted top-3 cache; rescan only on a 4th win.
#define INS3(val, gi, m1, i1, m2, i2, m3, i3)            \
  {                                                      \
    bool c1 = (val) > m1;                                \
    float t_ = c1 ? m1 : (val); int ti_ = c1 ? i1 : (gi);\
    m1 = c1 ? (val) : m1;       i1 = c1 ? (gi) : i1;     \
    bool c2 = t_ > m2;                                   \
    float t2_ = c2 ? m2 : t_;   int t2i_ = c2 ? i2 : ti_;\
    m2 = c2 ? t_ : m2;          i2 = c2 ? ti_ : i2;      \
    bool c3 = t2_ > m3;                                  \
    m3 = c3 ? t2_ : m3;         i3 = c3 ? t2i_ : i3;     \
  }

#define SCAN3(v, m1, i1, m2, i2, m3, i3)                               \
  _Pragma("unroll")                                                    \
  for (int r = 0; r < 8; ++r) {                                        \
    float vals[4] = {v[r].x, v[r].y, v[r].z, v[r].w};                  \
    _Pragma("unroll")                                                  \
    for (int e = 0; e < 4; ++e) {                                      \
      float val = vals[e];                                             \
      int gi = r * 256 + l * 4 + e;                                    \
      INS3(val, gi, m1, i1, m2, i2, m3, i3)                            \
    }                                                                  \
  }

#define SCAN3M(v, dead, m1, i1, m2, i2, m3, i3)                        \
  _Pragma("unroll")                                                    \
  for (int r = 0; r < 8; ++r) {                                        \
    float vals[4] = {v[r].x, v[r].y, v[r].z, v[r].w};                  \
    _Pragma("unroll")                                                  \
    for (int e = 0; e < 4; ++e) {                                      \
      int el = r * 4 + e;                                              \
      float val = ((dead >> el) & 1u) ? NEG : vals[e];                 \
      int gi = r * 256 + l * 4 + e;                                    \
      INS3(val, gi, m1, i1, m2, i2, m3, i3)                            \
    }                                                                  \
  }

#define TOPK_COMMIT(row, v, dead, cv, m1, i1, m2, i2, m3, i3)          \
  {                                                                    \
    unsigned long long mask = __ballot(m1 == cv);                      \
    int best_i = 1 << 30, best_l = 0;                                  \
    while (mask) {                                                     \
      int L = (int)__builtin_ctzll(mask);                              \
      int ii = __builtin_amdgcn_readlane(i1, L);                       \
      if (ii < best_i) { best_i = ii; best_l = L; }                    \
      mask &= mask - 1;                                                \
    }                                                                  \
    if (l == 0) idx[(size_t)(row) * NK + it] = best_i;                 \
    if (l == best_l) {                                                 \
      dead |= 1u << (((i1 >> 8) << 2) | (i1 & 3));                     \
      m1 = m2; i1 = i2; m2 = m3; i2 = i3; m3 = NEG; i3 = 0;            \
      if (m1 == NEG) { SCAN3M(v, dead, m1, i1, m2, i2, m3, i3) }       \
    }                                                                  \
  }

__global__ __launch_bounds__(256) void k_topk(const float* __restrict__ geod,
                                              int* __restrict__ idx) {
  int wv = threadIdx.x >> 6, l = threadIdx.x & 63;
  int rowA = blockIdx.x * 8 + wv * 2;
  int rowB = rowA + 1;
  const float* gA = geod + (size_t)rowA * NP;
  const float* gB = geod + (size_t)rowB * NP;
  float4 vA[8], vB[8];
#pragma unroll
  for (int r = 0; r < 8; ++r) {
    vA[r] = *(const float4*)&gA[r * 256 + l * 4];
    vB[r] = *(const float4*)&gB[r * 256 + l * 4];
  }
  const float NEG = -__builtin_huge_valf();
  unsigned int deadA = 0, deadB = 0;
  float m1A = NEG, m2A = NEG, m3A = NEG, m1B = NEG, m2B = NEG, m3B = NEG;
  int i1A = 0, i2A = 0, i3A = 0, i1B = 0, i2B = 0, i3B = 0;
  SCAN3(vA, m1A, i1A, m2A, i2A, m3A, i3A)
  SCAN3(vB, m1B, i1B, m2B, i2B, m3B, i3B)
  for (int it = 0; it < NK; ++it) {
    float cvA = m1A, cvB = m1B;
#pragma unroll
    for (int s = 1; s < 64; s <<= 1) {
      cvA = fmaxf(cvA, __shfl_xor(cvA, s));
      cvB = fmaxf(cvB, __shfl_xor(cvB, s));
    }
    TOPK_COMMIT(rowA, vA, deadA, cvA, m1A, i1A, m2A, i2A, m3A, i3A)
    TOPK_COMMIT(rowB, vB, deadB, cvB, m1B, i1B, m2B, i2B, m3B, i3B)
  }
}

// ---------------- layer-1 EdgeConv (C=3): whole-cloud-in-LDS ----------------
// One block per (batch, 32-point group). Entire xt[b] (24KB) staged once,
// coalesced; neighbor reads are LDS broadcasts (lane-uniform). Wave w owns
// points p0+{w*8..w*8+7}; lane = output channel o.
__global__ __launch_bounds__(256) void k_edge1(
    const float* __restrict__ xt, const int* __restrict__ idx,
    const float* __restrict__ wt1, const float* __restrict__ wd1,
    float* __restrict__ hmax, float* __restrict__ hmin,
    float* __restrict__ part) {
  __shared__ float xl[NP * 3];          // 24KB
  __shared__ int lidx[32 * NK];
  __shared__ float red[256];
  int tid = threadIdx.x;
  int b = blockIdx.x >> 6;
  int grp = blockIdx.x & 63;
  int p0 = grp * 32;
  for (int u = tid; u < NP * 3; u += 256) xl[u] = xt[(size_t)b * NP * 3 + u];
  for (int u = tid; u < 32 * NK; u += 256) lidx[u] = idx[((size_t)b * NP + p0) * NK + u];
  __syncthreads();
  int o = tid & 63;
  int pb = tid >> 6;
  float w0 = wt1[o], w1 = wt1[64 + o], w2 = wt1[128 + o];
  float d0 = wd1[o], d1 = wd1[64 + o], d2 = wd1[128 + o];
  float ps = 0.f, ps2 = 0.f;
#pragma unroll
  for (int i = 0; i < 8; ++i) {
    int pp = pb * 8 + i;
    int p = p0 + pp;
    float base = xl[p * 3] * d0 + xl[p * 3 + 1] * d1 + xl[p * 3 + 2] * d2;
    float mx = -3.4e38f, mn = 3.4e38f;
    for (int j = 0; j < NK; ++j) {
      int nb = lidx[pp * NK + j];
      float h = base + xl[nb * 3] * w0 + xl[nb * 3 + 1] * w1 + xl[nb * 3 + 2] * w2;
      mx = fmaxf(mx, h); mn = fminf(mn, h);
      ps += h; ps2 += h * h;
    }
    size_t P = (size_t)b * NP + p;
    hmax[P * 64 + o] = mx;
    hmin[P * 64 + o] = mn;
  }
  red[tid] = ps;
  __syncthreads();
  if (tid < 64) {
    float a = red[tid] + red[64 + tid] + red[128 + tid] + red[192 + tid];
    part[(size_t)blockIdx.x * 64 + tid] = a;
  }
  __syncthreads();
  red[tid] = ps2;
  __syncthreads();
  if (tid < 64) {
    float a = red[tid] + red[64 + tid] + red[128 + tid] + red[192 + tid];
    part[((size_t)gridDim.x + blockIdx.x) * 64 + tid] = a;
  }
}

// ---------------- self-term GEMM: sbase[p][o] = x[p]·(W1-W0) ----------------
// conv5-like structure: 64 rows/block, O cols, 4 waves (mg 2 x ng 2).
template <int C, int O>
__global__ __launch_bounds__(256) void k_self_mfma(
    const _Float16* __restrict__ xh, int in_off,
    const _Float16* __restrict__ Bp, float* __restrict__ sbase) {
  constexpr int NCH = C / 64;
  constexpr int NSLO = O / 16;
  constexpr int NS = NSLO / 2;       // 16-col slices per wave
  constexpr int PAIRS = 2 * NSLO;
  __shared__ __align__(16) _Float16 ldsA[64 * 64];
  __shared__ __align__(16) _Float16 ldsB[PAIRS * 512];
  int tid = threadIdx.x, wv = tid >> 6, l = tid & 63;
  int m0 = blockIdx.x * 64;
  int mg = wv & 1, ng = wv >> 1;
  f32x4 acc[2][NS];
#pragma unroll
  for (int m = 0; m < 2; ++m)
#pragma unroll
    for (int s = 0; s < NS; ++s)
#pragma unroll
      for (int r = 0; r < 4; ++r) acc[m][s][r] = 0.f;

  for (int ch = 0; ch < NCH; ++ch) {
#pragma unroll
    for (int it = 0; it < 2; ++it) {
      int r0 = wv * 16 + it * 8;
      int R = r0 + (l >> 3);
      int q = (l & 7) ^ (l >> 3);
      gload_lds16(xh + (size_t)(m0 + R) * 512 + in_off + ch * 64 + q * 8, ldsA + r0 * 64);
    }
    for (int u = wv; u < PAIRS; u += 4) {
      int ks = u / NSLO, sloc = u - ks * NSLO;
      gload_lds16(Bp + ((size_t)((ch * 2 + ks) * NSLO + sloc) * 64 + l) * 8,
                  ldsB + u * 512);
    }
    __syncthreads();
#pragma unroll
    for (int ks = 0; ks < 2; ++ks) {
      half8 b[NS];
#pragma unroll
      for (int s = 0; s < NS; ++s)
        b[s] = *(const half8*)(ldsB + (ks * NSLO + ng * NS + s) * 512 + l * 8);
#pragma unroll
      for (int mt = 0; mt < 2; ++mt) {
        int row = mg * 32 + mt * 16 + (l & 15);
        int slot = (ks * 4 + (l >> 4)) ^ (row & 7);
        half8 a = *(const half8*)(ldsA + row * 64 + slot * 8);
#pragma unroll
        for (int s = 0; s < NS; ++s)
          acc[mt][s] = __builtin_amdgcn_mfma_f32_16x16x32_f16(a, b[s], acc[mt][s], 0, 0, 0);
      }
    }
    __syncthreads();
  }
  int g = l >> 4;
#pragma unroll
  for (int s = 0; s < NS; ++s) {
    int col = ng * (NS * 16) + s * 16 + (l & 15);
#pragma unroll
    for (int mt = 0; mt < 2; ++mt)
#pragma unroll
      for (int r = 0; r < 4; ++r) {
        int row = m0 + mg * 32 + mt * 16 + 4 * g + r;
        sbase[(size_t)row * O + col] = acc[mt][s][r];
      }
  }
}

// ---------------- MFMA EdgeConv neighbor-GEMM (layers 2-4), K = C ----------------
// A-row r (0..79 within 80-row wave group) -> point pp=(r>>2)&3, j=4*(r>>4)+(r&3):
// each lane's C-fragment holds all 20 j of a single point -> lane-local max.
// Self-term (j-invariant) comes from sbase[], added in the epilogue.
template <int C, int O, int NSPLIT>
__global__ __launch_bounds__(256) void k_edge_mfma(
    const _Float16* __restrict__ xh, int in_off,
    const int* __restrict__ idx,
    const _Float16* __restrict__ Bp, const float* __restrict__ sbase,
    float* __restrict__ hmax, float* __restrict__ hmin,
    float* __restrict__ part) {
  constexpr int NCH = C / 64;        // 64-wide K chunks
  constexpr int NO = O / NSPLIT;     // columns handled by this block
  constexpr int NSLO = NO / 16;      // 16-col slices in block
  constexpr int NS = NSLO / 2;       // slices per wave (2 ng-groups)
  constexpr int PAIRS = 2 * NSLO;    // (ks, slice) B sub-tiles per chunk
  __shared__ __align__(16) _Float16 ldsA[160 * 64];   // 20KB, XOR-swizzled
  __shared__ __align__(16) _Float16 ldsB[PAIRS * 512];
  __shared__ float ldsS[2][NO], ldsQ[2][NO];
  int tid = threadIdx.x, wv = tid >> 6, l = tid & 63;
  int mblk = blockIdx.x, nid = 0;
  if (NSPLIT > 1) { nid = mblk >> 11; mblk &= 2047; }
  int p0 = mblk * 8;                 // 8 points per block
  int bbase = p0 & ~(NP - 1);
  int n_base = nid * NO;
  int mg = wv & 1, ng = wv >> 1;
  f32x4 acc[5][NS];
#pragma unroll
  for (int m = 0; m < 5; ++m)
#pragma unroll
    for (int s = 0; s < NS; ++s)
#pragma unroll
      for (int r = 0; r < 4; ++r) acc[m][s][r] = 0.f;

  for (int ch = 0; ch < NCH; ++ch) {
    int cbase = ch * 64;
    // stage A: wave stages rows [40*wv, 40*wv+40), 8 rows (1024B) per issue.
    // source pre-swizzled: lane slot (l&7) holds source 16B-segment q=(l&7)^(l>>3).
#pragma unroll
    for (int it = 0; it < 5; ++it) {
      int r0 = wv * 40 + it * 8;
      int R = r0 + (l >> 3);
      int mgR = R / 80;
      int r = R - mgR * 80;
      int pp = 4 * mgR + ((r >> 2) & 3);
      int j = ((r >> 4) << 2) | (r & 3);
      int p = p0 + pp;
      int srcn = bbase + idx[p * NK + j];
      int q = (l & 7) ^ (l >> 3);
      gload_lds16(xh + (size_t)srcn * 512 + in_off + cbase + q * 8, ldsA + r0 * 64);
    }
    // stage B chunk (already in frag order)
    for (int u = wv; u < PAIRS; u += 4) {
      int ks = u / NSLO, sloc = u - ks * NSLO;
      gload_lds16(Bp + ((size_t)((ch * 2 + ks) * (O / 16) + (n_base >> 4) + sloc) * 64 + l) * 8,
                  ldsB + u * 512);
    }
    __syncthreads();
#pragma unroll
    for (int ks = 0; ks < 2; ++ks) {
      half8 b[NS];
#pragma unroll
      for (int s = 0; s < NS; ++s)
        b[s] = *(const half8*)(ldsB + (ks * NSLO + ng * NS + s) * 512 + l * 8);
#pragma unroll
      for (int mt = 0; mt < 5; ++mt) {
        int row = mg * 80 + mt * 16 + (l & 15);
        int slot = (ks * 4 + (l >> 4)) ^ (row & 7);
        half8 a = *(const half8*)(ldsA + row * 64 + slot * 8);
#pragma unroll
        for (int s = 0; s < NS; ++s)
          acc[mt][s] = __builtin_amdgcn_mfma_f32_16x16x32_f16(a, b[s], acc[mt][s], 0, 0, 0);
      }
    }
    __syncthreads();
  }
  // epilogue: add j-invariant self-term, lane-local j-max/min per point;
  // cross-lane only for BN stats
  int g = l >> 4;
  int p = p0 + 4 * mg + g;
#pragma unroll
  for (int s = 0; s < NS; ++s) {
    int colL = ng * (NS * 16) + s * 16 + (l & 15);
    float sb = sbase[(size_t)p * O + n_base + colL];
    float mx = -3.4e38f, mn = 3.4e38f, sm = 0.f, sq = 0.f;
#pragma unroll
    for (int mt = 0; mt < 5; ++mt)
#pragma unroll
      for (int r = 0; r < 4; ++r) {
        float v = acc[mt][s][r] + sb;
        mx = fmaxf(mx, v); mn = fminf(mn, v); sm += v; sq += v * v;
      }
    hmax[(size_t)p * O + n_base + colL] = mx;
    hmin[(size_t)p * O + n_base + colL] = mn;
    sm += __shfl_xor(sm, 16); sm += __shfl_xor(sm, 32);
    sq += __shfl_xor(sq, 16); sq += __shfl_xor(sq, 32);
    if (l < 16) {
      ldsS[mg][ng * (NS * 16) + s * 16 + l] = sm;
      ldsQ[mg][ng * (NS * 16) + s * 16 + l] = sq;
    }
  }
  __syncthreads();
  for (int u = tid; u < NO; u += 256) {
    part[(size_t)mblk * O + n_base + u] = ldsS[0][u] + ldsS[1][u];
    part[((size_t)2048 + mblk) * O + n_base + u] = ldsQ[0][u] + ldsQ[1][u];
  }
}

// ---------------- conv5 MFMA: h5 = xcatH(16384x512) * B5(512x1024) ----------------
__global__ __launch_bounds__(256) void k_conv5_mfma(
    const _Float16* __restrict__ xh, const _Float16* __restrict__ Bp,
    _Float16* __restrict__ h5, float* __restrict__ part) {
  __shared__ __align__(16) _Float16 ldsA[64 * 64];     // 8KB
  __shared__ __align__(16) _Float16 ldsB[32 * 512];    // 32KB
  __shared__ float ldsS[2][256], ldsQ[2][256], ldsMx[2][256], ldsMn[2][256];
  int tid = threadIdx.x, wv = tid >> 6, l = tid & 63;
  int mblk = blockIdx.x & 255, nid = blockIdx.x >> 8;
  int m0 = mblk * 64;
  int n_base = nid * 256;
  int mg = wv & 1, ng = wv >> 1;
  f32x4 acc[2][8];
#pragma unroll
  for (int m = 0; m < 2; ++m)
#pragma unroll
    for (int s = 0; s < 8; ++s)
#pragma unroll
      for (int r = 0; r < 4; ++r) acc[m][s][r] = 0.f;

  for (int ch = 0; ch < 8; ++ch) {
#pragma unroll
    for (int it = 0; it < 2; ++it) {
      int r0 = wv * 16 + it * 8;
      int R = r0 + (l >> 3);
      int q = (l & 7) ^ (l >> 3);
      gload_lds16(xh + (size_t)(m0 + R) * 512 + ch * 64 + q * 8, ldsA + r0 * 64);
    }
    for (int u = wv; u < 32; u += 4) {
      int ks = u >> 4, sloc = u & 15;
      gload_lds16(Bp + ((size_t)((ch * 2 + ks) * 64 + (n_base >> 4) + sloc) * 64 + l) * 8,
                  ldsB + u * 512);
    }
    __syncthreads();
#pragma unroll
    for (int ks = 0; ks < 2; ++ks) {
      half8 b[8];
#pragma unroll
      for (int s = 0; s < 8; ++s)
        b[s] = *(const half8*)(ldsB + (ks * 16 + ng * 8 + s) * 512 + l * 8);
#pragma unroll
      for (int mt = 0; mt < 2; ++mt) {
        int row = mg * 32 + mt * 16 + (l & 15);
        int slot = (ks * 4 + (l >> 4)) ^ (row & 7);
        half8 a = *(const half8*)(ldsA + row * 64 + slot * 8);
#pragma unroll
        for (int s = 0; s < 8; ++s)
          acc[mt][s] = __builtin_amdgcn_mfma_f32_16x16x32_f16(a, b[s], acc[mt][s], 0, 0, 0);
      }
    }
    __syncthreads();
  }
  int g = l >> 4;
#pragma unroll
  for (int s = 0; s < 8; ++s) {
    float sm = 0.f, sq = 0.f, mx = -3.4e38f, mn = 3.4e38f;
    int col = n_base + ng * 128 + s * 16 + (l & 15);
#pragma unroll
    for (int mt = 0; mt < 2; ++mt)
#pragma unroll
      for (int r = 0; r < 4; ++r) {
        float v = acc[mt][s][r];
        int row = m0 + mg * 32 + mt * 16 + 4 * g + r;
        h5[(size_t)row * 1024 + col] = (_Float16)v;
        sm += v; sq += v * v; mx = fmaxf(mx, v); mn = fminf(mn, v);
      }
    sm += __shfl_xor(sm, 16); sm += __shfl_xor(sm, 32);
    sq += __shfl_xor(sq, 16); sq += __shfl_xor(sq, 32);
    mx = fmaxf(mx, __shfl_xor(mx, 16)); mx = fmaxf(mx, __shfl_xor(mx, 32));
    mn = fminf(mn, __shfl_xor(mn, 16)); mn = fminf(mn, __shfl_xor(mn, 32));
    if (l < 16) {
      int u = ng * 128 + s * 16 + l;
      ldsS[mg][u] = sm; ldsQ[mg][u] = sq; ldsMx[mg][u] = mx; ldsMn[mg][u] = mn;
    }
  }
  __syncthreads();
  {
    int u = tid;
    int col = n_base + u;
    part[(size_t)mblk * 1024 + col] = ldsS[0][u] + ldsS[1][u];
    part[((size_t)256 + mblk) * 1024 + col] = ldsQ[0][u] + ldsQ[1][u];
    part[((size_t)512 + mblk) * 1024 + col] = fmaxf(ldsMx[0][u], ldsMx[1][u]);
    part[((size_t)768 + mblk) * 1024 + col] = fminf(ldsMn[0][u], ldsMn[1][u]);
  }
}

// reduce partials -> per-channel BN scale/shift. grid = O blocks.
__global__ __launch_bounds__(256) void k_finalize(
    const float* __restrict__ part, int G, int O, float inv_count,
    const float* __restrict__ gamma, const float* __restrict__ beta,
    float* __restrict__ ss) {
  int o = blockIdx.x;
  float s = 0.f, s2 = 0.f;
  for (int g = threadIdx.x; g < G; g += 256) {
    s  += part[(size_t)g * O + o];
    s2 += part[((size_t)G + g) * O + o];
  }
#pragma unroll
  for (int sft = 32; sft; sft >>= 1) {
    s  += __shfl_down(s, sft);
    s2 += __shfl_down(s2, sft);
  }
  __shared__ float aw[4], aw2[4];
  int w = threadIdx.x >> 6;
  if ((threadIdx.x & 63) == 0) { aw[w] = s; aw2[w] = s2; }
  __syncthreads();
  if (threadIdx.x == 0) {
    s = aw[0] + aw[1] + aw[2] + aw[3];
    s2 = aw2[0] + aw2[1] + aw2[2] + aw2[3];
    float m   = s * inv_count;
    float var = s2 * inv_count - m * m;
    float scale = gamma[o] * rsqrtf(var + 1e-5f);
    ss[o]     = scale;
    ss[O + o] = beta[o] - m * scale;
  }
}

// apply BN+lrelu to (max or min per sign of scale), write fp16 into xcatH slice
__global__ void k_edge_apply(const float* __restrict__ hmax, const float* __restrict__ hmin,
                             const float* __restrict__ ss, _Float16* __restrict__ xh,
                             int O, int off) {
  int t = blockIdx.x * 256 + threadIdx.x;
  int o = t % O;
  int p = t / O;
  float scale = ss[o], shift = ss[O + o];
  float v = (scale >= 0.f) ? hmax[t] : hmin[t];
  v = scale * v + shift;
  v = (v >= 0.f) ? v : 0.2f * v;
  xh[(size_t)p * 512 + off + o] = (_Float16)v;
}

// conv5 mean-pool partials: grid = 8b*8ns*4cg = 256 blocks
__global__ __launch_bounds__(256) void k_pool5a(const _Float16* __restrict__ h5,
                                                const float* __restrict__ ss,
                                                float* __restrict__ pmean) {
  int bi = blockIdx.x;
  int b = bi >> 5, ns = (bi >> 2) & 7, cg = bi & 3;
  int col = cg * 256 + threadIdx.x;
  float scale = ss[col], shift = ss[1024 + col];
  float sm = 0.f;
  for (int n = ns * 256; n < ns * 256 + 256; ++n) {
    float v = (float)h5[(size_t)(b * 2048 + n) * 1024 + col];
    float y = scale * v + shift;
    y = (y >= 0.f) ? y : 0.2f * y;
    sm += y;
  }
  pmean[(size_t)(b * 8 + ns) * 1024 + col] = sm;
}

// final pool: exact max via fp32 partials (BN+lrelu commute), mean via pmean
__global__ __launch_bounds__(256) void k_pool5b(const float* __restrict__ part,
                                                const float* __restrict__ pmean,
                                                const float* __restrict__ ss,
                                                float* __restrict__ z) {
  int bi = blockIdx.x;
  int b = bi >> 2, cg = bi & 3;
  int col = cg * 256 + threadIdx.x;
  float scale = ss[col], shift = ss[1024 + col];
  const float* pmx = part + (size_t)512 * 1024;
  const float* pmn = part + (size_t)768 * 1024;
  float mxh = -3.4e38f, mnh = 3.4e38f;
  for (int q = 0; q < 32; ++q) {
    size_t base = (size_t)(b * 32 + q) * 1024 + col;
    mxh = fmaxf(mxh, pmx[base]);
    mnh = fminf(mnh, pmn[base]);
  }
  float hsel = (scale >= 0.f) ? mxh : mnh;
  float zmax = scale * hsel + shift;
  zmax = (zmax >= 0.f) ? zmax : 0.2f * zmax;
  float sm = 0.f;
  for (int ns = 0; ns < 8; ++ns) sm += pmean[(size_t)(b * 8 + ns) * 1024 + col];
  z[b * 2048 + col] = zmax;
  z[b * 2048 + 1024 + col] = sm * (1.f / 2048.f);
}

// generic FC: one wave per (b,o); float4-vectorized loads (IN % 256 == 0)
__global__ __launch_bounds__(64) void k_fc(const float* __restrict__ in,
                                           const float* __restrict__ Wf,
                                           const float* __restrict__ bias,
                                           float* __restrict__ out, int IN, int O) {
  int blk = blockIdx.x;
  int b = blk / O, o = blk % O;
  const float4* a = (const float4*)(in + (size_t)b * IN);
  const float4* w = (const float4*)(Wf + (size_t)o * IN);
  float s = 0.f;
  for (int i = threadIdx.x; i < (IN >> 2); i += 64) {
    float4 av = a[i], wv = w[i];
    s += av.x * wv.x + av.y * wv.y + av.z * wv.z + av.w * wv.w;
  }
#pragma unroll
  for (int sft = 32; sft; sft >>= 1) s += __shfl_down(s, sft);
  if (threadIdx.x == 0) out[(size_t)b * O + o] = s + (bias ? bias[o] : 0.f);
}

// batch-axis BN (count=8) + lrelu
__global__ void k_bn_fc(const float* __restrict__ pre, const float* __restrict__ gamma,
                        const float* __restrict__ beta, float* __restrict__ out, int O) {
  int o = blockIdx.x * 256 + threadIdx.x;
  if (o >= O) return;
  float v[NB];
  float s = 0.f, s2 = 0.f;
#pragma unroll
  for (int b = 0; b < NB; ++b) {
    v[b] = pre[(size_t)b * O + o];
    s += v[b]; s2 += v[b] * v[b];
  }
  float m = s * (1.f / NB);
  float var = s2 * (1.f / NB) - m * m;
  float scale = gamma[o] * rsqrtf(var + 1e-5f);
  float shift = beta[o] - m * scale;
#pragma unroll
  for (int b = 0; b < NB; ++b) {
    float x = scale * v[b] + shift;
    out[(size_t)b * O + o] = (x >= 0.f) ? x : 0.2f * x;
  }
}

// ---------------- launcher ----------------
extern "C" void kernel_launch(void* const* d_in, const int* in_sizes, int n_in,
                              void* d_out, int out_size, void* d_ws, size_t ws_size,
                              hipStream_t stream) {
  (void)in_sizes; (void)n_in; (void)out_size; (void)ws_size;
  const float* x    = (const float*)d_in[0];
  const float* geod = (const float*)d_in[1];
  const float* W1   = (const float*)d_in[2];
  const float* g1   = (const float*)d_in[3];
  const float* bt1  = (const float*)d_in[4];
  const float* W2   = (const float*)d_in[5];
  const float* g2   = (const float*)d_in[6];
  const float* bt2  = (const float*)d_in[7];
  const float* W3   = (const float*)d_in[8];
  const float* g3   = (const float*)d_in[9];
  const float* bt3  = (const float*)d_in[10];
  const float* W4   = (const float*)d_in[11];
  const float* g4   = (const float*)d_in[12];
  const float* bt4  = (const float*)d_in[13];
  const float* W5   = (const float*)d_in[14];
  const float* g5   = (const float*)d_in[15];
  const float* bt5  = (const float*)d_in[16];
  const float* L1   = (const float*)d_in[17];
  const float* g6   = (const float*)d_in[18];
  const float* bt6  = (const float*)d_in[19];
  const float* L2   = (const float*)d_in[20];
  const float* bl2  = (const float*)d_in[21];
  const float* g7   = (const float*)d_in[22];
  const float* bt7  = (const float*)d_in[23];
  const float* L3   = (const float*)d_in[24];
  const float* bl3  = (const float*)d_in[25];

  char* ws = (char*)d_ws;
  int*       idx   = (int*)(ws + OFF_IDX);
  float*     xt    = (float*)(ws + OFF_XT);
  _Float16*  xcatH = (_Float16*)(ws + OFF_XCATH);
  float*     wt1   = (float*)(ws + OFF_WT1);
  float*     wd1   = (float*)(ws + OFF_WD1);
  _Float16*  b2    = (_Float16*)(ws + OFF_B2);
  _Float16*  s2w   = (_Float16*)(ws + OFF_S2);
  _Float16*  b3    = (_Float16*)(ws + OFF_B3);
  _Float16*  s3w   = (_Float16*)(ws + OFF_S3);
  _Float16*  b4    = (_Float16*)(ws + OFF_B4);
  _Float16*  s4w   = (_Float16*)(ws + OFF_S4);
  _Float16*  b5    = (_Float16*)(ws + OFF_B5);
  float*     sbase = (float*)(ws + OFF_SBASE);
  float*     hmax  = (float*)(ws + OFF_HMAX);
  float*     hmin  = (float*)(ws + OFF_HMIN);
  _Float16*  h5    = (_Float16*)(ws + OFF_H5);
  float*     part  = (float*)(ws + OFF_PART);
  float*     pmean = (float*)(ws + OFF_PMEAN);
  float*     ssb   = (float*)(ws + OFF_SS);
  float*     z     = (float*)(ws + OFF_Z);
  float*     z1p   = (float*)(ws + OFF_Z1P);
  float*     z1    = (float*)(ws + OFF_Z1);
  float*     z2p   = (float*)(ws + OFF_Z2P);
  float*     z2    = (float*)(ws + OFF_Z2);

  const float invE = 1.f / (float)(BN * NK);
  const float inv5 = 1.f / (float)(BN);

  k_prep_all<<<PB_END, 256, 0, stream>>>(x, xt, W1, wt1, wd1,
                                         W2, b2, s2w, W3, b3, s3w,
                                         W4, b4, s4w, W5, b5);
  k_topk<<<BN / 8, 256, 0, stream>>>(geod, idx);

  // layer 1 (C=3, fp32, whole-cloud LDS)
  k_edge1<<<512, 256, 0, stream>>>(xt, idx, wt1, wd1, hmax, hmin, part);
  k_finalize<<<64, 256, 0, stream>>>(part, 512, 64, invE, g1, bt1, ssb);
  k_edge_apply<<<(BN * 64) / 256, 256, 0, stream>>>(hmax, hmin, ssb, xcatH, 64, 0);
  // layer 2 (C=64 -> O=64), input slice 0
  k_self_mfma<64, 64><<<256, 256, 0, stream>>>(xcatH, 0, s2w, sbase);
  k_edge_mfma<64, 64, 1><<<2048, 256, 0, stream>>>(xcatH, 0, idx, b2, sbase, hmax, hmin, part);
  k_finalize<<<64, 256, 0, stream>>>(part, 2048, 64, invE, g2, bt2, ssb);
  k_edge_apply<<<(BN * 64) / 256, 256, 0, stream>>>(hmax, hmin, ssb, xcatH, 64, 64);
  // layer 3 (C=64 -> O=128), input slice 64
  k_self_mfma<64, 128><<<256, 256, 0, stream>>>(xcatH, 64, s3w, sbase);
  k_edge_mfma<64, 128, 1><<<2048, 256, 0, stream>>>(xcatH, 64, idx, b3, sbase, hmax, hmin, part);
  k_finalize<<<128, 256, 0, stream>>>(part, 2048, 128, invE, g3, bt3, ssb);
  k_edge_apply<<<(BN * 128) / 256, 256, 0, stream>>>(hmax, hmin, ssb, xcatH, 128, 128);
  // layer 4 (C=128 -> O=256), input slice 128, N split in 2
  k_self_mfma<128, 256><<<256, 256, 0, stream>>>(xcatH, 128, s4w, sbase);
  k_edge_mfma<128, 256, 2><<<4096, 256, 0, stream>>>(xcatH, 128, idx, b4, sbase, hmax, hmin, part);
  k_finalize<<<256, 256, 0, stream>>>(part, 2048, 256, invE, g4, bt4, ssb);
  k_edge_apply<<<(BN * 256) / 256, 256, 0, stream>>>(hmax, hmin, ssb, xcatH, 256, 256);

  // conv5 (16384x512 @ 512x1024)
  k_conv5_mfma<<<1024, 256, 0, stream>>>(xcatH, b5, h5, part);
  k_finalize<<<1024, 256, 0, stream>>>(part, 256, 1024, inv5, g5, bt5, ssb);
  k_pool5a<<<256, 256, 0, stream>>>(h5, ssb, pmean);
  k_pool5b<<<32, 256, 0, stream>>>(part, pmean, ssb, z);

  // FC head
  k_fc<<<NB * 512, 64, 0, stream>>>(z, L1, nullptr, z1p, 2048, 512);
  k_bn_fc<<<2, 256, 0, stream>>>(z1p, g6, bt6, z1, 512);
  k_fc<<<NB * 256, 64, 0, stream>>>(z1, L2, bl2, z2p, 512, 256);
  k_bn_fc<<<1, 256, 0, stream>>>(z2p, g7, bt7, z2, 256);
  k_fc<<<NB * 40, 64, 0, stream>>>(z2, L3, bl3, (float*)d_out, 256, 40);
}

// Round 9
// 261.653 us; speedup vs baseline: 6.8784x; 1.0308x over previous
//
#include <hip/hip_runtime.h>
#include <hip/hip_bf16.h>
#include <cstdint>
#include <cstddef>

// Problem constants
#define NB 8
#define NP 2048
#define NK 20
#define BN 16384      // NB*NP

typedef _Float16 half8 __attribute__((ext_vector_type(8)));
typedef float f32x4 __attribute__((ext_vector_type(4)));

__device__ __forceinline__ void gload_lds16(const void* g, void* l) {
  __builtin_amdgcn_global_load_lds(
      (const __attribute__((address_space(1))) unsigned int*)g,
      (__attribute__((address_space(3))) unsigned int*)l, 16, 0, 0);
}

// ---------------- workspace layout (bytes) ----------------
static constexpr size_t OFF_IDX   = 0;                                // int[BN*20]
static constexpr size_t OFF_XT    = OFF_IDX + (size_t)BN*NK*4;        // f32[BN*3]
static constexpr size_t OFF_XCATH = OFF_XT + (size_t)BN*3*4;          // f16[BN*512]
static constexpr size_t OFF_WT1   = OFF_XCATH + (size_t)BN*512*2;
static constexpr size_t OFF_WD1   = OFF_WT1 + 3*64*4;
static constexpr size_t OFF_B2    = OFF_WD1 + 3*64*4;                 // f16[64*64]   W0
static constexpr size_t OFF_S2    = OFF_B2 + (size_t)64*64*2;         // f16[64*64]   W1-W0
static constexpr size_t OFF_B3    = OFF_S2 + (size_t)64*64*2;         // f16[64*128]
static constexpr size_t OFF_S3    = OFF_B3 + (size_t)64*128*2;
static constexpr size_t OFF_B4    = OFF_S3 + (size_t)64*128*2;        // f16[128*256]
static constexpr size_t OFF_S4    = OFF_B4 + (size_t)128*256*2;
static constexpr size_t OFF_B5    = OFF_S4 + (size_t)128*256*2;       // f16[512*1024]
static constexpr size_t OFF_SBASE = OFF_B5 + (size_t)512*1024*2;      // f32[BN*256] self-term
static constexpr size_t OFF_HMAX  = OFF_SBASE + (size_t)BN*256*4;     // f32[BN*256]
static constexpr size_t OFF_HMIN  = OFF_HMAX + (size_t)BN*256*4;      // f32[BN*256]
static constexpr size_t OFF_H5    = OFF_HMAX;                         // f16[BN*1024] overlay (edge bufs dead)
static constexpr size_t OFF_PART  = OFF_HMIN + (size_t)BN*256*4;      // 4 MB partials
static constexpr size_t OFF_PMEAN = OFF_PART + (size_t)4*1024*1024;   // f32[8*8*1024]
static constexpr size_t OFF_SS    = OFF_PMEAN + (size_t)8*8*1024*4;   // f32[2*1024]
static constexpr size_t OFF_Z     = OFF_SS + 2*1024*4;                // f32[8*2048]
static constexpr size_t OFF_Z1P   = OFF_Z + (size_t)NB*2048*4;
static constexpr size_t OFF_Z1    = OFF_Z1P + NB*512*4;
static constexpr size_t OFF_Z2P   = OFF_Z1 + NB*512*4;
static constexpr size_t OFF_Z2    = OFF_Z2P + NB*256*4;
// total ~75 MB

// ---------------- fused prep kernel ----------------
// b-frag order (mfma_f32_16x16x32_f16): lane l, elem e reads
// B[64*ch + 32*ks + 8*(l>>4)+e][16*sl + (l&15)].
__device__ __forceinline__ void prep_b_dev(const float* __restrict__ W,
                                           _Float16* __restrict__ Bp, int t,
                                           int K2, int lgO, int lgRS, bool diff) {
  int O = 1 << lgO;
  int o = t & (O - 1), k = t >> lgO;
  float v;
  if (diff) v = W[((size_t)o << lgRS) + K2 + k] - W[((size_t)o << lgRS) + k];
  else      v = W[((size_t)o << lgRS) + k];
  int ch = k >> 6, ks = (k >> 5) & 1, kg = (k >> 3) & 3, e = k & 7;
  int sl = o >> 4, ol = o & 15;
  size_t flat = (((size_t)(ch * 2 + ks) * (O >> 4) + sl) * 64 + (kg * 16 + ol)) * 8 + e;
  Bp[flat] = (_Float16)v;
}

// segment block offsets
static constexpr int PB_TR = 0;              // 192 blocks: transpose x
static constexpr int PB_W1 = PB_TR + 192;    // 1 block:   wt1/wd1
static constexpr int PB_B2 = PB_W1 + 1;      // 16
static constexpr int PB_S2 = PB_B2 + 16;     // 16
static constexpr int PB_B3 = PB_S2 + 16;     // 32
static constexpr int PB_S3 = PB_B3 + 32;     // 32
static constexpr int PB_B4 = PB_S3 + 32;     // 128
static constexpr int PB_S4 = PB_B4 + 128;    // 128
static constexpr int PB_B5 = PB_S4 + 128;    // 2048
static constexpr int PB_END = PB_B5 + 2048;  // 2593

__global__ __launch_bounds__(256) void k_prep_all(
    const float* __restrict__ x, float* __restrict__ xt,
    const float* __restrict__ W1, float* __restrict__ wt1, float* __restrict__ wd1,
    const float* __restrict__ W2, _Float16* __restrict__ b2, _Float16* __restrict__ s2w,
    const float* __restrict__ W3, _Float16* __restrict__ b3, _Float16* __restrict__ s3w,
    const float* __restrict__ W4, _Float16* __restrict__ b4, _Float16* __restrict__ s4w,
    const float* __restrict__ W5, _Float16* __restrict__ b5) {
  int blk = blockIdx.x, tid = threadIdx.x;
  if (blk < PB_W1) {                       // transpose x (B,3,N)->(B,N,3)
    int t = blk * 256 + tid;
    int n = t & (NP - 1);
    int c = (t / NP) % 3;
    int b = t / (3 * NP);
    xt[(size_t)(b * NP + n) * 3 + c] = x[t];
  } else if (blk < PB_B2) {                // layer-1 weights
    int t = tid;
    if (t < 192) {
      int o = t & 63, c = t >> 6;
      float w0 = W1[o * 6 + c];
      float w1 = W1[o * 6 + 3 + c];
      wt1[c * 64 + o] = w0;
      wd1[c * 64 + o] = w1 - w0;
    }
  } else if (blk < PB_S2) prep_b_dev(W2, b2,  (blk - PB_B2) * 256 + tid, 64, 6, 7, false);
  else if (blk < PB_B3)   prep_b_dev(W2, s2w, (blk - PB_S2) * 256 + tid, 64, 6, 7, true);
  else if (blk < PB_S3)   prep_b_dev(W3, b3,  (blk - PB_B3) * 256 + tid, 64, 7, 7, false);
  else if (blk < PB_B4)   prep_b_dev(W3, s3w, (blk - PB_S3) * 256 + tid, 64, 7, 7, true);
  else if (blk < PB_S4)   prep_b_dev(W4, b4,  (blk - PB_B4) * 256 + tid, 128, 8, 8, false);
  else if (blk < PB_B5)   prep_b_dev(W4, s4w, (blk - PB_S4) * 256 + tid, 128, 8, 8, true);
  else                    prep_b_dev(W5, b5,  (blk - PB_B5) * 256 + tid, 512, 10, 9, false);
}

// ---------------- top-20 (exact jax.lax.top_k semantics) ----------------
// One wave per row. Per iteration: 6-step DPP max reduce (VALU pipe, not the
// slow LDS-shuffle pipe) -> lane 63; readlane broadcasts cv; tie-break via a
// second DPP integer-min reduce over masked indices (replaces ballot + scalar
// loop). Per-lane sorted top-3 cache; rescan only on a 4th win (E~0.26/row).
template <int CTRL>
__device__ __forceinline__ float dppmax(float x) {
  int t = __builtin_amdgcn_update_dpp(__float_as_int(x), __float_as_int(x),
                                      CTRL, 0xF, 0xF, false);
  return fmaxf(x, __int_as_float(t));
}
template <int CTRL>
__device__ __forceinline__ int dppmin(int x) {
  int t = __builtin_amdgcn_update_dpp(x, x, CTRL, 0xF, 0xF, false);
  return (t < x) ? t : x;
}
// row_shr:1/2/4/8 = 0x111/0x112/0x114/0x118; row_bcast:15/31 = 0x142/0x143
__device__ __forceinline__ float wave_max63(float x) {
  x = dppmax<0x111>(x); x = dppmax<0x112>(x); x = dppmax<0x114>(x);
  x = dppmax<0x118>(x); x = dppmax<0x142>(x); x = dppmax<0x143>(x);
  return x;
}
__device__ __forceinline__ int wave_min63(int x) {
  x = dppmin<0x111>(x); x = dppmin<0x112>(x); x = dppmin<0x114>(x);
  x = dppmin<0x118>(x); x = dppmin<0x142>(x); x = dppmin<0x143>(x);
  return x;
}

#define INS3(val, gi, m1, i1, m2, i2, m3, i3)            \
  {                                                      \
    bool c1 = (val) > m1;                                \
    float t_ = c1 ? m1 : (val); int ti_ = c1 ? i1 : (gi);\
    m1 = c1 ? (val) : m1;       i1 = c1 ? (gi) : i1;     \
    bool c2 = t_ > m2;                                   \
    float t2_ = c2 ? m2 : t_;   int t2i_ = c2 ? i2 : ti_;\
    m2 = c2 ? t_ : m2;          i2 = c2 ? ti_ : i2;      \
    bool c3 = t2_ > m3;                                  \
    m3 = c3 ? t2_ : m3;         i3 = c3 ? t2i_ : i3;     \
  }

#define SCAN3(v, m1, i1, m2, i2, m3, i3)                               \
  _Pragma("unroll")                                                    \
  for (int r = 0; r < 8; ++r) {                                        \
    float vals[4] = {v[r].x, v[r].y, v[r].z, v[r].w};                  \
    _Pragma("unroll")                                                  \
    for (int e = 0; e < 4; ++e) {                                      \
      float val = vals[e];                                             \
      int gi = r * 256 + l * 4 + e;                                    \
      INS3(val, gi, m1, i1, m2, i2, m3, i3)                            \
    }                                                                  \
  }

#define SCAN3M(v, dead, m1, i1, m2, i2, m3, i3)                        \
  _Pragma("unroll")                                                    \
  for (int r = 0; r < 8; ++r) {                                        \
    float vals[4] = {v[r].x, v[r].y, v[r].z, v[r].w};                  \
    _Pragma("unroll")                                                  \
    for (int e = 0; e < 4; ++e) {                                      \
      int el = r * 4 + e;                                              \
      float val = ((dead >> el) & 1u) ? NEG : vals[e];                 \
      int gi = r * 256 + l * 4 + e;                                    \
      INS3(val, gi, m1, i1, m2, i2, m3, i3)                            \
    }                                                                  \
  }

__global__ __launch_bounds__(256) void k_topk(const float* __restrict__ geod,
                                              int* __restrict__ idx) {
  int wv = threadIdx.x >> 6, l = threadIdx.x & 63;
  int row = blockIdx.x * 4 + wv;
  const float* g = geod + (size_t)row * NP;
  float4 v[8];
#pragma unroll
  for (int r = 0; r < 8; ++r) v[r] = *(const float4*)&g[r * 256 + l * 4];
  const float NEG = -__builtin_huge_valf();
  unsigned int dead = 0;
  float m1 = NEG, m2 = NEG, m3 = NEG;
  int i1 = 0, i2 = 0, i3 = 0;
  SCAN3(v, m1, i1, m2, i2, m3, i3)
  for (int it = 0; it < NK; ++it) {
    float xr = wave_max63(m1);
    float cv = __int_as_float(__builtin_amdgcn_readlane(__float_as_int(xr), 63));
    int ci = (m1 == cv) ? i1 : (1 << 30);
    ci = wave_min63(ci);
    int best_i = __builtin_amdgcn_readlane(ci, 63);
    if (l == 0) idx[(size_t)row * NK + it] = best_i;
    if (((best_i >> 2) & 63) == l) {       // winner lane only
      dead |= 1u << (((best_i >> 8) << 2) | (best_i & 3));
      m1 = m2; i1 = i2; m2 = m3; i2 = i3; m3 = NEG; i3 = 0;
      if (m1 == NEG) { SCAN3M(v, dead, m1, i1, m2, i2, m3, i3) }
    }
  }
}

// ---------------- layer-1 EdgeConv (C=3): whole-cloud-in-LDS ----------------
// One block per (batch, 32-point group). Entire xt[b] (24KB) staged once,
// coalesced; neighbor reads are LDS broadcasts (lane-uniform). Wave w owns
// points p0+{w*8..w*8+7}; lane = output channel o.
__global__ __launch_bounds__(256) void k_edge1(
    const float* __restrict__ xt, const int* __restrict__ idx,
    const float* __restrict__ wt1, const float* __restrict__ wd1,
    float* __restrict__ hmax, float* __restrict__ hmin,
    float* __restrict__ part) {
  __shared__ float xl[NP * 3];          // 24KB
  __shared__ int lidx[32 * NK];
  __shared__ float red[256];
  int tid = threadIdx.x;
  int b = blockIdx.x >> 6;
  int grp = blockIdx.x & 63;
  int p0 = grp * 32;
  for (int u = tid; u < NP * 3; u += 256) xl[u] = xt[(size_t)b * NP * 3 + u];
  for (int u = tid; u < 32 * NK; u += 256) lidx[u] = idx[((size_t)b * NP + p0) * NK + u];
  __syncthreads();
  int o = tid & 63;
  int pb = tid >> 6;
  float w0 = wt1[o], w1 = wt1[64 + o], w2 = wt1[128 + o];
  float d0 = wd1[o], d1 = wd1[64 + o], d2 = wd1[128 + o];
  float ps = 0.f, ps2 = 0.f;
#pragma unroll
  for (int i = 0; i < 8; ++i) {
    int pp = pb * 8 + i;
    int p = p0 + pp;
    float base = xl[p * 3] * d0 + xl[p * 3 + 1] * d1 + xl[p * 3 + 2] * d2;
    float mx = -3.4e38f, mn = 3.4e38f;
    for (int j = 0; j < NK; ++j) {
      int nb = lidx[pp * NK + j];
      float h = base + xl[nb * 3] * w0 + xl[nb * 3 + 1] * w1 + xl[nb * 3 + 2] * w2;
      mx = fmaxf(mx, h); mn = fminf(mn, h);
      ps += h; ps2 += h * h;
    }
    size_t P = (size_t)b * NP + p;
    hmax[P * 64 + o] = mx;
    hmin[P * 64 + o] = mn;
  }
  red[tid] = ps;
  __syncthreads();
  if (tid < 64) {
    float a = red[tid] + red[64 + tid] + red[128 + tid] + red[192 + tid];
    part[(size_t)blockIdx.x * 64 + tid] = a;
  }
  __syncthreads();
  red[tid] = ps2;
  __syncthreads();
  if (tid < 64) {
    float a = red[tid] + red[64 + tid] + red[128 + tid] + red[192 + tid];
    part[((size_t)gridDim.x + blockIdx.x) * 64 + tid] = a;
  }
}

// ---------------- self-term GEMM: sbase[p][o] = x[p]·(W1-W0) ----------------
// conv5-like structure: 64 rows/block, O cols, 4 waves (mg 2 x ng 2).
template <int C, int O>
__global__ __launch_bounds__(256) void k_self_mfma(
    const _Float16* __restrict__ xh, int in_off,
    const _Float16* __restrict__ Bp, float* __restrict__ sbase) {
  constexpr int NCH = C / 64;
  constexpr int NSLO = O / 16;
  constexpr int NS = NSLO / 2;       // 16-col slices per wave
  constexpr int PAIRS = 2 * NSLO;
  __shared__ __align__(16) _Float16 ldsA[64 * 64];
  __shared__ __align__(16) _Float16 ldsB[PAIRS * 512];
  int tid = threadIdx.x, wv = tid >> 6, l = tid & 63;
  int m0 = blockIdx.x * 64;
  int mg = wv & 1, ng = wv >> 1;
  f32x4 acc[2][NS];
#pragma unroll
  for (int m = 0; m < 2; ++m)
#pragma unroll
    for (int s = 0; s < NS; ++s)
#pragma unroll
      for (int r = 0; r < 4; ++r) acc[m][s][r] = 0.f;

  for (int ch = 0; ch < NCH; ++ch) {
#pragma unroll
    for (int it = 0; it < 2; ++it) {
      int r0 = wv * 16 + it * 8;
      int R = r0 + (l >> 3);
      int q = (l & 7) ^ (l >> 3);
      gload_lds16(xh + (size_t)(m0 + R) * 512 + in_off + ch * 64 + q * 8, ldsA + r0 * 64);
    }
    for (int u = wv; u < PAIRS; u += 4) {
      int ks = u / NSLO, sloc = u - ks * NSLO;
      gload_lds16(Bp + ((size_t)((ch * 2 + ks) * NSLO + sloc) * 64 + l) * 8,
                  ldsB + u * 512);
    }
    __syncthreads();
#pragma unroll
    for (int ks = 0; ks < 2; ++ks) {
      half8 b[NS];
#pragma unroll
      for (int s = 0; s < NS; ++s)
        b[s] = *(const half8*)(ldsB + (ks * NSLO + ng * NS + s) * 512 + l * 8);
#pragma unroll
      for (int mt = 0; mt < 2; ++mt) {
        int row = mg * 32 + mt * 16 + (l & 15);
        int slot = (ks * 4 + (l >> 4)) ^ (row & 7);
        half8 a = *(const half8*)(ldsA + row * 64 + slot * 8);
#pragma unroll
        for (int s = 0; s < NS; ++s)
          acc[mt][s] = __builtin_amdgcn_mfma_f32_16x16x32_f16(a, b[s], acc[mt][s], 0, 0, 0);
      }
    }
    __syncthreads();
  }
  int g = l >> 4;
#pragma unroll
  for (int s = 0; s < NS; ++s) {
    int col = ng * (NS * 16) + s * 16 + (l & 15);
#pragma unroll
    for (int mt = 0; mt < 2; ++mt)
#pragma unroll
      for (int r = 0; r < 4; ++r) {
        int row = m0 + mg * 32 + mt * 16 + 4 * g + r;
        sbase[(size_t)row * O + col] = acc[mt][s][r];
      }
  }
}

// ---------------- MFMA EdgeConv neighbor-GEMM (layers 2-4), K = C ----------------
// A-row r (0..79 within 80-row wave group) -> point pp=(r>>2)&3, j=4*(r>>4)+(r&3):
// each lane's C-fragment holds all 20 j of a single point -> lane-local max.
// Self-term (j-invariant) comes from sbase[], added in the epilogue.
template <int C, int O, int NSPLIT>
__global__ __launch_bounds__(256) void k_edge_mfma(
    const _Float16* __restrict__ xh, int in_off,
    const int* __restrict__ idx,
    const _Float16* __restrict__ Bp, const float* __restrict__ sbase,
    float* __restrict__ hmax, float* __restrict__ hmin,
    float* __restrict__ part) {
  constexpr int NCH = C / 64;        // 64-wide K chunks
  constexpr int NO = O / NSPLIT;     // columns handled by this block
  constexpr int NSLO = NO / 16;      // 16-col slices in block
  constexpr int NS = NSLO / 2;       // slices per wave (2 ng-groups)
  constexpr int PAIRS = 2 * NSLO;    // (ks, slice) B sub-tiles per chunk
  __shared__ __align__(16) _Float16 ldsA[160 * 64];   // 20KB, XOR-swizzled
  __shared__ __align__(16) _Float16 ldsB[PAIRS * 512];
  __shared__ float ldsS[2][NO], ldsQ[2][NO];
  int tid = threadIdx.x, wv = tid >> 6, l = tid & 63;
  int mblk = blockIdx.x, nid = 0;
  if (NSPLIT > 1) { nid = mblk >> 11; mblk &= 2047; }
  int p0 = mblk * 8;                 // 8 points per block
  int bbase = p0 & ~(NP - 1);
  int n_base = nid * NO;
  int mg = wv & 1, ng = wv >> 1;
  f32x4 acc[5][NS];
#pragma unroll
  for (int m = 0; m < 5; ++m)
#pragma unroll
    for (int s = 0; s < NS; ++s)
#pragma unroll
      for (int r = 0; r < 4; ++r) acc[m][s][r] = 0.f;

  for (int ch = 0; ch < NCH; ++ch) {
    int cbase = ch * 64;
    // stage A: wave stages rows [40*wv, 40*wv+40), 8 rows (1024B) per issue.
    // source pre-swizzled: lane slot (l&7) holds source 16B-segment q=(l&7)^(l>>3).
#pragma unroll
    for (int it = 0; it < 5; ++it) {
      int r0 = wv * 40 + it * 8;
      int R = r0 + (l >> 3);
      int mgR = R / 80;
      int r = R - mgR * 80;
      int pp = 4 * mgR + ((r >> 2) & 3);
      int j = ((r >> 4) << 2) | (r & 3);
      int p = p0 + pp;
      int srcn = bbase + idx[p * NK + j];
      int q = (l & 7) ^ (l >> 3);
      gload_lds16(xh + (size_t)srcn * 512 + in_off + cbase + q * 8, ldsA + r0 * 64);
    }
    // stage B chunk (already in frag order)
    for (int u = wv; u < PAIRS; u += 4) {
      int ks = u / NSLO, sloc = u - ks * NSLO;
      gload_lds16(Bp + ((size_t)((ch * 2 + ks) * (O / 16) + (n_base >> 4) + sloc) * 64 + l) * 8,
                  ldsB + u * 512);
    }
    __syncthreads();
#pragma unroll
    for (int ks = 0; ks < 2; ++ks) {
      half8 b[NS];
#pragma unroll
      for (int s = 0; s < NS; ++s)
        b[s] = *(const half8*)(ldsB + (ks * NSLO + ng * NS + s) * 512 + l * 8);
#pragma unroll
      for (int mt = 0; mt < 5; ++mt) {
        int row = mg * 80 + mt * 16 + (l & 15);
        int slot = (ks * 4 + (l >> 4)) ^ (row & 7);
        half8 a = *(const half8*)(ldsA + row * 64 + slot * 8);
#pragma unroll
        for (int s = 0; s < NS; ++s)
          acc[mt][s] = __builtin_amdgcn_mfma_f32_16x16x32_f16(a, b[s], acc[mt][s], 0, 0, 0);
      }
    }
    __syncthreads();
  }
  // epilogue: add j-invariant self-term, lane-local j-max/min per point;
  // cross-lane only for BN stats
  int g = l >> 4;
  int p = p0 + 4 * mg + g;
#pragma unroll
  for (int s = 0; s < NS; ++s) {
    int colL = ng * (NS * 16) + s * 16 + (l & 15);
    float sb = sbase[(size_t)p * O + n_base + colL];
    float mx = -3.4e38f, mn = 3.4e38f, sm = 0.f, sq = 0.f;
#pragma unroll
    for (int mt = 0; mt < 5; ++mt)
#pragma unroll
      for (int r = 0; r < 4; ++r) {
        float v = acc[mt][s][r] + sb;
        mx = fmaxf(mx, v); mn = fminf(mn, v); sm += v; sq += v * v;
      }
    hmax[(size_t)p * O + n_base + colL] = mx;
    hmin[(size_t)p * O + n_base + colL] = mn;
    sm += __shfl_xor(sm, 16); sm += __shfl_xor(sm, 32);
    sq += __shfl_xor(sq, 16); sq += __shfl_xor(sq, 32);
    if (l < 16) {
      ldsS[mg][ng * (NS * 16) + s * 16 + l] = sm;
      ldsQ[mg][ng * (NS * 16) + s * 16 + l] = sq;
    }
  }
  __syncthreads();
  for (int u = tid; u < NO; u += 256) {
    part[(size_t)mblk * O + n_base + u] = ldsS[0][u] + ldsS[1][u];
    part[((size_t)2048 + mblk) * O + n_base + u] = ldsQ[0][u] + ldsQ[1][u];
  }
}

// ---------------- conv5 MFMA: h5 = xcatH(16384x512) * B5(512x1024) ----------------
__global__ __launch_bounds__(256) void k_conv5_mfma(
    const _Float16* __restrict__ xh, const _Float16* __restrict__ Bp,
    _Float16* __restrict__ h5, float* __restrict__ part) {
  __shared__ __align__(16) _Float16 ldsA[64 * 64];     // 8KB
  __shared__ __align__(16) _Float16 ldsB[32 * 512];    // 32KB
  __shared__ float ldsS[2][256], ldsQ[2][256], ldsMx[2][256], ldsMn[2][256];
  int tid = threadIdx.x, wv = tid >> 6, l = tid & 63;
  int mblk = blockIdx.x & 255, nid = blockIdx.x >> 8;
  int m0 = mblk * 64;
  int n_base = nid * 256;
  int mg = wv & 1, ng = wv >> 1;
  f32x4 acc[2][8];
#pragma unroll
  for (int m = 0; m < 2; ++m)
#pragma unroll
    for (int s = 0; s < 8; ++s)
#pragma unroll
      for (int r = 0; r < 4; ++r) acc[m][s][r] = 0.f;

  for (int ch = 0; ch < 8; ++ch) {
#pragma unroll
    for (int it = 0; it < 2; ++it) {
      int r0 = wv * 16 + it * 8;
      int R = r0 + (l >> 3);
      int q = (l & 7) ^ (l >> 3);
      gload_lds16(xh + (size_t)(m0 + R) * 512 + ch * 64 + q * 8, ldsA + r0 * 64);
    }
    for (int u = wv; u < 32; u += 4) {
      int ks = u >> 4, sloc = u & 15;
      gload_lds16(Bp + ((size_t)((ch * 2 + ks) * 64 + (n_base >> 4) + sloc) * 64 + l) * 8,
                  ldsB + u * 512);
    }
    __syncthreads();
#pragma unroll
    for (int ks = 0; ks < 2; ++ks) {
      half8 b[8];
#pragma unroll
      for (int s = 0; s < 8; ++s)
        b[s] = *(const half8*)(ldsB + (ks * 16 + ng * 8 + s) * 512 + l * 8);
#pragma unroll
      for (int mt = 0; mt < 2; ++mt) {
        int row = mg * 32 + mt * 16 + (l & 15);
        int slot = (ks * 4 + (l >> 4)) ^ (row & 7);
        half8 a = *(const half8*)(ldsA + row * 64 + slot * 8);
#pragma unroll
        for (int s = 0; s < 8; ++s)
          acc[mt][s] = __builtin_amdgcn_mfma_f32_16x16x32_f16(a, b[s], acc[mt][s], 0, 0, 0);
      }
    }
    __syncthreads();
  }
  int g = l >> 4;
#pragma unroll
  for (int s = 0; s < 8; ++s) {
    float sm = 0.f, sq = 0.f, mx = -3.4e38f, mn = 3.4e38f;
    int col = n_base + ng * 128 + s * 16 + (l & 15);
#pragma unroll
    for (int mt = 0; mt < 2; ++mt)
#pragma unroll
      for (int r = 0; r < 4; ++r) {
        float v = acc[mt][s][r];
        int row = m0 + mg * 32 + mt * 16 + 4 * g + r;
        h5[(size_t)row * 1024 + col] = (_Float16)v;
        sm += v; sq += v * v; mx = fmaxf(mx, v); mn = fminf(mn, v);
      }
    sm += __shfl_xor(sm, 16); sm += __shfl_xor(sm, 32);
    sq += __shfl_xor(sq, 16); sq += __shfl_xor(sq, 32);
    mx = fmaxf(mx, __shfl_xor(mx, 16)); mx = fmaxf(mx, __shfl_xor(mx, 32));
    mn = fminf(mn, __shfl_xor(mn, 16)); mn = fminf(mn, __shfl_xor(mn, 32));
    if (l < 16) {
      int u = ng * 128 + s * 16 + l;
      ldsS[mg][u] = sm; ldsQ[mg][u] = sq; ldsMx[mg][u] = mx; ldsMn[mg][u] = mn;
    }
  }
  __syncthreads();
  {
    int u = tid;
    int col = n_base + u;
    part[(size_t)mblk * 1024 + col] = ldsS[0][u] + ldsS[1][u];
    part[((size_t)256 + mblk) * 1024 + col] = ldsQ[0][u] + ldsQ[1][u];
    part[((size_t)512 + mblk) * 1024 + col] = fmaxf(ldsMx[0][u], ldsMx[1][u]);
    part[((size_t)768 + mblk) * 1024 + col] = fminf(ldsMn[0][u], ldsMn[1][u]);
  }
}

// reduce partials -> per-channel BN scale/shift. grid = O blocks.
__global__ __launch_bounds__(256) void k_finalize(
    const float* __restrict__ part, int G, int O, float inv_count,
    const float* __restrict__ gamma, const float* __restrict__ beta,
    float* __restrict__ ss) {
  int o = blockIdx.x;
  float s = 0.f, s2 = 0.f;
  for (int g = threadIdx.x; g < G; g += 256) {
    s  += part[(size_t)g * O + o];
    s2 += part[((size_t)G + g) * O + o];
  }
#pragma unroll
  for (int sft = 32; sft; sft >>= 1) {
    s  += __shfl_down(s, sft);
    s2 += __shfl_down(s2, sft);
  }
  __shared__ float aw[4], aw2[4];
  int w = threadIdx.x >> 6;
  if ((threadIdx.x & 63) == 0) { aw[w] = s; aw2[w] = s2; }
  __syncthreads();
  if (threadIdx.x == 0) {
    s = aw[0] + aw[1] + aw[2] + aw[3];
    s2 = aw2[0] + aw2[1] + aw2[2] + aw2[3];
    float m   = s * inv_count;
    float var = s2 * inv_count - m * m;
    float scale = gamma[o] * rsqrtf(var + 1e-5f);
    ss[o]     = scale;
    ss[O + o] = beta[o] - m * scale;
  }
}

// apply BN+lrelu to (max or min per sign of scale), write fp16 into xcatH slice
__global__ void k_edge_apply(const float* __restrict__ hmax, const float* __restrict__ hmin,
                             const float* __restrict__ ss, _Float16* __restrict__ xh,
                             int O, int off) {
  int t = blockIdx.x * 256 + threadIdx.x;
  int o = t % O;
  int p = t / O;
  float scale = ss[o], shift = ss[O + o];
  float v = (scale >= 0.f) ? hmax[t] : hmin[t];
  v = scale * v + shift;
  v = (v >= 0.f) ? v : 0.2f * v;
  xh[(size_t)p * 512 + off + o] = (_Float16)v;
}

// conv5 mean-pool partials: grid = 8b*8ns*4cg = 256 blocks
__global__ __launch_bounds__(256) void k_pool5a(const _Float16* __restrict__ h5,
                                                const float* __restrict__ ss,
                                                float* __restrict__ pmean) {
  int bi = blockIdx.x;
  int b = bi >> 5, ns = (bi >> 2) & 7, cg = bi & 3;
  int col = cg * 256 + threadIdx.x;
  float scale = ss[col], shift = ss[1024 + col];
  float sm = 0.f;
  for (int n = ns * 256; n < ns * 256 + 256; ++n) {
    float v = (float)h5[(size_t)(b * 2048 + n) * 1024 + col];
    float y = scale * v + shift;
    y = (y >= 0.f) ? y : 0.2f * y;
    sm += y;
  }
  pmean[(size_t)(b * 8 + ns) * 1024 + col] = sm;
}

// final pool: exact max via fp32 partials (BN+lrelu commute), mean via pmean
__global__ __launch_bounds__(256) void k_pool5b(const float* __restrict__ part,
                                                const float* __restrict__ pmean,
                                                const float* __restrict__ ss,
                                                float* __restrict__ z) {
  int bi = blockIdx.x;
  int b = bi >> 2, cg = bi & 3;
  int col = cg * 256 + threadIdx.x;
  float scale = ss[col], shift = ss[1024 + col];
  const float* pmx = part + (size_t)512 * 1024;
  const float* pmn = part + (size_t)768 * 1024;
  float mxh = -3.4e38f, mnh = 3.4e38f;
  for (int q = 0; q < 32; ++q) {
    size_t base = (size_t)(b * 32 + q) * 1024 + col;
    mxh = fmaxf(mxh, pmx[base]);
    mnh = fminf(mnh, pmn[base]);
  }
  float hsel = (scale >= 0.f) ? mxh : mnh;
  float zmax = scale * hsel + shift;
  zmax = (zmax >= 0.f) ? zmax : 0.2f * zmax;
  float sm = 0.f;
  for (int ns = 0; ns < 8; ++ns) sm += pmean[(size_t)(b * 8 + ns) * 1024 + col];
  z[b * 2048 + col] = zmax;
  z[b * 2048 + 1024 + col] = sm * (1.f / 2048.f);
}

// generic FC: one wave per (b,o); float4-vectorized loads (IN % 256 == 0)
__global__ __launch_bounds__(64) void k_fc(const float* __restrict__ in,
                                           const float* __restrict__ Wf,
                                           const float* __restrict__ bias,
                                           float* __restrict__ out, int IN, int O) {
  int blk = blockIdx.x;
  int b = blk / O, o = blk % O;
  const float4* a = (const float4*)(in + (size_t)b * IN);
  const float4* w = (const float4*)(Wf + (size_t)o * IN);
  float s = 0.f;
  for (int i = threadIdx.x; i < (IN >> 2); i += 64) {
    float4 av = a[i], wv = w[i];
    s += av.x * wv.x + av.y * wv.y + av.z * wv.z + av.w * wv.w;
  }
#pragma unroll
  for (int sft = 32; sft; sft >>= 1) s += __shfl_down(s, sft);
  if (threadIdx.x == 0) out[(size_t)b * O + o] = s + (bias ? bias[o] : 0.f);
}

// batch-axis BN (count=8) + lrelu
__global__ void k_bn_fc(const float* __restrict__ pre, const float* __restrict__ gamma,
                        const float* __restrict__ beta, float* __restrict__ out, int O) {
  int o = blockIdx.x * 256 + threadIdx.x;
  if (o >= O) return;
  float v[NB];
  float s = 0.f, s2 = 0.f;
#pragma unroll
  for (int b = 0; b < NB; ++b) {
    v[b] = pre[(size_t)b * O + o];
    s += v[b]; s2 += v[b] * v[b];
  }
  float m = s * (1.f / NB);
  float var = s2 * (1.f / NB) - m * m;
  float scale = gamma[o] * rsqrtf(var + 1e-5f);
  float shift = beta[o] - m * scale;
#pragma unroll
  for (int b = 0; b < NB; ++b) {
    float x = scale * v[b] + shift;
    out[(size_t)b * O + o] = (x >= 0.f) ? x : 0.2f * x;
  }
}

// ---------------- launcher ----------------
extern "C" void kernel_launch(void* const* d_in, const int* in_sizes, int n_in,
                              void* d_out, int out_size, void* d_ws, size_t ws_size,
                              hipStream_t stream) {
  (void)in_sizes; (void)n_in; (void)out_size; (void)ws_size;
  const float* x    = (const float*)d_in[0];
  const float* geod = (const float*)d_in[1];
  const float* W1   = (const float*)d_in[2];
  const float* g1   = (const float*)d_in[3];
  const float* bt1  = (const float*)d_in[4];
  const float* W2   = (const float*)d_in[5];
  const float* g2   = (const float*)d_in[6];
  const float* bt2  = (const float*)d_in[7];
  const float* W3   = (const float*)d_in[8];
  const float* g3   = (const float*)d_in[9];
  const float* bt3  = (const float*)d_in[10];
  const float* W4   = (const float*)d_in[11];
  const float* g4   = (const float*)d_in[12];
  const float* bt4  = (const float*)d_in[13];
  const float* W5   = (const float*)d_in[14];
  const float* g5   = (const float*)d_in[15];
  const float* bt5  = (const float*)d_in[16];
  const float* L1   = (const float*)d_in[17];
  const float* g6   = (const float*)d_in[18];
  const float* bt6  = (const float*)d_in[19];
  const float* L2   = (const float*)d_in[20];
  const float* bl2  = (const float*)d_in[21];
  const float* g7   = (const float*)d_in[22];
  const float* bt7  = (const float*)d_in[23];
  const float* L3   = (const float*)d_in[24];
  const float* bl3  = (const float*)d_in[25];

  char* ws = (char*)d_ws;
  int*       idx   = (int*)(ws + OFF_IDX);
  float*     xt    = (float*)(ws + OFF_XT);
  _Float16*  xcatH = (_Float16*)(ws + OFF_XCATH);
  float*     wt1   = (float*)(ws + OFF_WT1);
  float*     wd1   = (float*)(ws + OFF_WD1);
  _Float16*  b2    = (_Float16*)(ws + OFF_B2);
  _Float16*  s2w   = (_Float16*)(ws + OFF_S2);
  _Float16*  b3    = (_Float16*)(ws + OFF_B3);
  _Float16*  s3w   = (_Float16*)(ws + OFF_S3);
  _Float16*  b4    = (_Float16*)(ws + OFF_B4);
  _Float16*  s4w   = (_Float16*)(ws + OFF_S4);
  _Float16*  b5    = (_Float16*)(ws + OFF_B5);
  float*     sbase = (float*)(ws + OFF_SBASE);
  float*     hmax  = (float*)(ws + OFF_HMAX);
  float*     hmin  = (float*)(ws + OFF_HMIN);
  _Float16*  h5    = (_Float16*)(ws + OFF_H5);
  float*     part  = (float*)(ws + OFF_PART);
  float*     pmean = (float*)(ws + OFF_PMEAN);
  float*     ssb   = (float*)(ws + OFF_SS);
  float*     z     = (float*)(ws + OFF_Z);
  float*     z1p   = (float*)(ws + OFF_Z1P);
  float*     z1    = (float*)(ws + OFF_Z1);
  float*     z2p   = (float*)(ws + OFF_Z2P);
  float*     z2    = (float*)(ws + OFF_Z2);

  const float invE = 1.f / (float)(BN * NK);
  const float inv5 = 1.f / (float)(BN);

  k_prep_all<<<PB_END, 256, 0, stream>>>(x, xt, W1, wt1, wd1,
                                         W2, b2, s2w, W3, b3, s3w,
                                         W4, b4, s4w, W5, b5);
  k_topk<<<BN / 4, 256, 0, stream>>>(geod, idx);

  // layer 1 (C=3, fp32, whole-cloud LDS)
  k_edge1<<<512, 256, 0, stream>>>(xt, idx, wt1, wd1, hmax, hmin, part);
  k_finalize<<<64, 256, 0, stream>>>(part, 512, 64, invE, g1, bt1, ssb);
  k_edge_apply<<<(BN * 64) / 256, 256, 0, stream>>>(hmax, hmin, ssb, xcatH, 64, 0);
  // layer 2 (C=64 -> O=64), input slice 0
  k_self_mfma<64, 64><<<256, 256, 0, stream>>>(xcatH, 0, s2w, sbase);
  k_edge_mfma<64, 64, 1><<<2048, 256, 0, stream>>>(xcatH, 0, idx, b2, sbase, hmax, hmin, part);
  k_finalize<<<64, 256, 0, stream>>>(part, 2048, 64, invE, g2, bt2, ssb);
  k_edge_apply<<<(BN * 64) / 256, 256, 0, stream>>>(hmax, hmin, ssb, xcatH, 64, 64);
  // layer 3 (C=64 -> O=128), input slice 64
  k_self_mfma<64, 128><<<256, 256, 0, stream>>>(xcatH, 64, s3w, sbase);
  k_edge_mfma<64, 128, 1><<<2048, 256, 0, stream>>>(xcatH, 64, idx, b3, sbase, hmax, hmin, part);
  k_finalize<<<128, 256, 0, stream>>>(part, 2048, 128, invE, g3, bt3, ssb);
  k_edge_apply<<<(BN * 128) / 256, 256, 0, stream>>>(hmax, hmin, ssb, xcatH, 128, 128);
  // layer 4 (C=128 -> O=256), input slice 128, N split in 2
  k_self_mfma<128, 256><<<256, 256, 0, stream>>>(xcatH, 128, s4w, sbase);
  k_edge_mfma<128, 256, 2><<<4096, 256, 0, stream>>>(xcatH, 128, idx, b4, sbase, hmax, hmin, part);
  k_finalize<<<256, 256, 0, stream>>>(part, 2048, 256, invE, g4, bt4, ssb);
  k_edge_apply<<<(BN * 256) / 256, 256, 0, stream>>>(hmax, hmin, ssb, xcatH, 256, 256);

  // conv5 (16384x512 @ 512x1024)
  k_conv5_mfma<<<1024, 256, 0, stream>>>(xcatH, b5, h5, part);
  k_finalize<<<1024, 256, 0, stream>>>(part, 256, 1024, inv5, g5, bt5, ssb);
  k_pool5a<<<256, 256, 0, stream>>>(h5, ssb, pmean);
  k_pool5b<<<32, 256, 0, stream>>>(part, pmean, ssb, z);

  // FC head
  k_fc<<<NB * 512, 64, 0, stream>>>(z, L1, nullptr, z1p, 2048, 512);
  k_bn_fc<<<2, 256, 0, stream>>>(z1p, g6, bt6, z1, 512);
  k_fc<<<NB * 256, 64, 0, stream>>>(z1, L2, bl2, z2p, 512, 256);
  k_bn_fc<<<1, 256, 0, stream>>>(z2p, g7, bt7, z2, 256);
  k_fc<<<NB * 40, 64, 0, stream>>>(z2, L3, bl3, (float*)d_out, 256, 40);
}

// Round 10
// 243.329 us; speedup vs baseline: 7.3963x; 1.0753x over previous
//
#include <hip/hip_runtime.h>
#include <hip/hip_bf16.h>
#include <cstdint>
#include <cstddef>

// Problem constants
#define NB 8
#define NP 2048
#define NK 20
#define BN 16384      // NB*NP

typedef _Float16 half8 __attribute__((ext_vector_type(8)));
typedef _Float16 half4v __attribute__((ext_vector_type(4)));
typedef float f32x4 __attribute__((ext_vector_type(4)));

__device__ __forceinline__ void gload_lds16(const void* g, void* l) {
  __builtin_amdgcn_global_load_lds(
      (const __attribute__((address_space(1))) unsigned int*)g,
      (__attribute__((address_space(3))) unsigned int*)l, 16, 0, 0);
}

// ---------------- workspace layout (bytes) ----------------
static constexpr size_t OFF_IDX   = 0;                                // int[BN*20]
static constexpr size_t OFF_XT    = OFF_IDX + (size_t)BN*NK*4;        // f32[BN*3]
static constexpr size_t OFF_XCATH = OFF_XT + (size_t)BN*3*4;          // f16[BN*512]
static constexpr size_t OFF_WT1   = OFF_XCATH + (size_t)BN*512*2;
static constexpr size_t OFF_WD1   = OFF_WT1 + 3*64*4;
static constexpr size_t OFF_BC2   = OFF_WD1 + 3*64*4;                 // f16[64*128]  [W0|W1-W0]
static constexpr size_t OFF_BC3   = OFF_BC2 + (size_t)64*128*2;       // f16[64*256]
static constexpr size_t OFF_BC4   = OFF_BC3 + (size_t)64*256*2;       // f16[128*512]
static constexpr size_t OFF_B5    = OFF_BC4 + (size_t)128*512*2;      // f16[512*1024]
static constexpr size_t OFF_YH    = OFF_B5 + (size_t)512*1024*2;      // f16[BN*512]  [y|sbase]
static constexpr size_t OFF_HMAX  = OFF_YH + (size_t)BN*512*2;        // f32[BN*256]
static constexpr size_t OFF_HMIN  = OFF_HMAX + (size_t)BN*256*4;      // f32[BN*256]
static constexpr size_t OFF_H5    = OFF_HMAX;                         // f16[BN*1024] overlay (edge bufs dead)
static constexpr size_t OFF_PART  = OFF_HMIN + (size_t)BN*256*4;      // 8 MB partials
static constexpr size_t OFF_PMEAN = OFF_PART + (size_t)8*1024*1024;   // f32[8*8*1024]
static constexpr size_t OFF_SS    = OFF_PMEAN + (size_t)8*8*1024*4;   // f32[2*1024]
static constexpr size_t OFF_Z     = OFF_SS + 2*1024*4;                // f32[8*2048]
static constexpr size_t OFF_Z1P   = OFF_Z + (size_t)NB*2048*4;
static constexpr size_t OFF_Z1    = OFF_Z1P + NB*512*4;
static constexpr size_t OFF_Z2P   = OFF_Z1 + NB*512*4;
static constexpr size_t OFF_Z2    = OFF_Z2P + NB*256*4;
// total ~79 MB

// ---------------- fused prep kernel ----------------
// b-frag order (mfma_f32_16x16x32_f16): lane l, elem e reads
// B[64*ch + 32*ks + 8*(l>>4)+e][16*sl + (l&15)].
__device__ __forceinline__ void prep_b_dev(const float* __restrict__ W,
                                           _Float16* __restrict__ Bp, int t,
                                           int K2, int lgO, int lgRS) {
  int O = 1 << lgO;
  int o = t & (O - 1), k = t >> lgO;
  float v = W[((size_t)o << lgRS) + k];
  int ch = k >> 6, ks = (k >> 5) & 1, kg = (k >> 3) & 3, e = k & 7;
  int sl = o >> 4, ol = o & 15;
  size_t flat = (((size_t)(ch * 2 + ks) * (O >> 4) + sl) * 64 + (kg * 16 + ol)) * 8 + e;
  Bp[flat] = (_Float16)v;
}

// combined pack [W0 | W1-W0]: O2 = 2*O_logical cols, K = C.
__device__ __forceinline__ void prep_bc_dev(const float* __restrict__ W,
                                            _Float16* __restrict__ Bp, int t,
                                            int C, int lgO2, int lgRS) {
  int O2 = 1 << lgO2, O = O2 >> 1;
  int o2 = t & (O2 - 1), k = t >> lgO2;
  float v;
  if (o2 < O) v = W[((size_t)o2 << lgRS) + k];
  else {
    int o = o2 - O;
    v = W[((size_t)o << lgRS) + C + k] - W[((size_t)o << lgRS) + k];
  }
  int ch = k >> 6, ks = (k >> 5) & 1, kg = (k >> 3) & 3, e = k & 7;
  int sl = o2 >> 4, ol = o2 & 15;
  size_t flat = (((size_t)(ch * 2 + ks) * (O2 >> 4) + sl) * 64 + (kg * 16 + ol)) * 8 + e;
  Bp[flat] = (_Float16)v;
}

// segment block offsets
static constexpr int PB_TR  = 0;               // 192 blocks: transpose x
static constexpr int PB_W1  = PB_TR + 192;     // 1 block
static constexpr int PB_BC2 = PB_W1 + 1;       // 32  (64*128)
static constexpr int PB_BC3 = PB_BC2 + 32;     // 64  (64*256)
static constexpr int PB_BC4 = PB_BC3 + 64;     // 256 (128*512)
static constexpr int PB_B5  = PB_BC4 + 256;    // 2048
static constexpr int PB_END = PB_B5 + 2048;    // 2593

__global__ __launch_bounds__(256) void k_prep_all(
    const float* __restrict__ x, float* __restrict__ xt,
    const float* __restrict__ W1, float* __restrict__ wt1, float* __restrict__ wd1,
    const float* __restrict__ W2, _Float16* __restrict__ bc2,
    const float* __restrict__ W3, _Float16* __restrict__ bc3,
    const float* __restrict__ W4, _Float16* __restrict__ bc4,
    const float* __restrict__ W5, _Float16* __restrict__ b5) {
  int blk = blockIdx.x, tid = threadIdx.x;
  if (blk < PB_W1) {                       // transpose x (B,3,N)->(B,N,3)
    int t = blk * 256 + tid;
    int n = t & (NP - 1);
    int c = (t / NP) % 3;
    int b = t / (3 * NP);
    xt[(size_t)(b * NP + n) * 3 + c] = x[t];
  } else if (blk < PB_BC2) {               // layer-1 weights
    int t = tid;
    if (t < 192) {
      int o = t & 63, c = t >> 6;
      float w0 = W1[o * 6 + c];
      float w1 = W1[o * 6 + 3 + c];
      wt1[c * 64 + o] = w0;
      wd1[c * 64 + o] = w1 - w0;
    }
  } else if (blk < PB_BC3) prep_bc_dev(W2, bc2, (blk - PB_BC2) * 256 + tid, 64, 7, 7);
  else if (blk < PB_BC4)   prep_bc_dev(W3, bc3, (blk - PB_BC3) * 256 + tid, 64, 8, 7);
  else if (blk < PB_B5)    prep_bc_dev(W4, bc4, (blk - PB_BC4) * 256 + tid, 128, 9, 8);
  else                     prep_b_dev(W5, b5,   (blk - PB_B5) * 256 + tid, 512, 10, 9);
}

// ---------------- top-20 (exact jax.lax.top_k semantics) ----------------
// One wave per row; DPP max reduce on the VALU pipe; DPP int-min tie-break;
// per-lane sorted top-3 cache; rescan only on a 4th win.
template <int CTRL>
__device__ __forceinline__ float dppmax(float x) {
  int t = __builtin_amdgcn_update_dpp(__float_as_int(x), __float_as_int(x),
                                      CTRL, 0xF, 0xF, false);
  return fmaxf(x, __int_as_float(t));
}
template <int CTRL>
__device__ __forceinline__ int dppmin(int x) {
  int t = __builtin_amdgcn_update_dpp(x, x, CTRL, 0xF, 0xF, false);
  return (t < x) ? t : x;
}
__device__ __forceinline__ float wave_max63(float x) {
  x = dppmax<0x111>(x); x = dppmax<0x112>(x); x = dppmax<0x114>(x);
  x = dppmax<0x118>(x); x = dppmax<0x142>(x); x = dppmax<0x143>(x);
  return x;
}
__device__ __forceinline__ int wave_min63(int x) {
  x = dppmin<0x111>(x); x = dppmin<0x112>(x); x = dppmin<0x114>(x);
  x = dppmin<0x118>(x); x = dppmin<0x142>(x); x = dppmin<0x143>(x);
  return x;
}

#define INS3(val, gi, m1, i1, m2, i2, m3, i3)            \
  {                                                      \
    bool c1 = (val) > m1;                                \
    float t_ = c1 ? m1 : (val); int ti_ = c1 ? i1 : (gi);\
    m1 = c1 ? (val) : m1;       i1 = c1 ? (gi) : i1;     \
    bool c2 = t_ > m2;                                   \
    float t2_ = c2 ? m2 : t_;   int t2i_ = c2 ? i2 : ti_;\
    m2 = c2 ? t_ : m2;          i2 = c2 ? ti_ : i2;      \
    bool c3 = t2_ > m3;                                  \
    m3 = c3 ? t2_ : m3;         i3 = c3 ? t2i_ : i3;     \
  }

#define SCAN3(v, m1, i1, m2, i2, m3, i3)                               \
  _Pragma("unroll")                                                    \
  for (int r = 0; r < 8; ++r) {                                        \
    float vals[4] = {v[r].x, v[r].y, v[r].z, v[r].w};                  \
    _Pragma("unroll")                                                  \
    for (int e = 0; e < 4; ++e) {                                      \
      float val = vals[e];                                             \
      int gi = r * 256 + l * 4 + e;                                    \
      INS3(val, gi, m1, i1, m2, i2, m3, i3)                            \
    }                                                                  \
  }

#define SCAN3M(v, dead, m1, i1, m2, i2, m3, i3)                        \
  _Pragma("unroll")                                                    \
  for (int r = 0; r < 8; ++r) {                                        \
    float vals[4] = {v[r].x, v[r].y, v[r].z, v[r].w};                  \
    _Pragma("unroll")                                                  \
    for (int e = 0; e < 4; ++e) {                                      \
      int el = r * 4 + e;                                              \
      float val = ((dead >> el) & 1u) ? NEG : vals[e];                 \
      int gi = r * 256 + l * 4 + e;                                    \
      INS3(val, gi, m1, i1, m2, i2, m3, i3)                            \
    }                                                                  \
  }

__global__ __launch_bounds__(256) void k_topk(const float* __restrict__ geod,
                                              int* __restrict__ idx) {
  int wv = threadIdx.x >> 6, l = threadIdx.x & 63;
  int row = blockIdx.x * 4 + wv;
  const float* g = geod + (size_t)row * NP;
  float4 v[8];
#pragma unroll
  for (int r = 0; r < 8; ++r) v[r] = *(const float4*)&g[r * 256 + l * 4];
  const float NEG = -__builtin_huge_valf();
  unsigned int dead = 0;
  float m1 = NEG, m2 = NEG, m3 = NEG;
  int i1 = 0, i2 = 0, i3 = 0;
  SCAN3(v, m1, i1, m2, i2, m3, i3)
  for (int it = 0; it < NK; ++it) {
    float xr = wave_max63(m1);
    float cv = __int_as_float(__builtin_amdgcn_readlane(__float_as_int(xr), 63));
    int ci = (m1 == cv) ? i1 : (1 << 30);
    ci = wave_min63(ci);
    int best_i = __builtin_amdgcn_readlane(ci, 63);
    if (l == 0) idx[(size_t)row * NK + it] = best_i;
    if (((best_i >> 2) & 63) == l) {       // winner lane only
      dead |= 1u << (((best_i >> 8) << 2) | (best_i & 3));
      m1 = m2; i1 = i2; m2 = m3; i2 = i3; m3 = NEG; i3 = 0;
      if (m1 == NEG) { SCAN3M(v, dead, m1, i1, m2, i2, m3, i3) }
    }
  }
}

// ---------------- layer-1 EdgeConv (C=3): whole-cloud-in-LDS ----------------
__global__ __launch_bounds__(256) void k_edge1(
    const float* __restrict__ xt, const int* __restrict__ idx,
    const float* __restrict__ wt1, const float* __restrict__ wd1,
    float* __restrict__ hmax, float* __restrict__ hmin,
    float* __restrict__ part) {
  __shared__ float xl[NP * 3];          // 24KB
  __shared__ int lidx[32 * NK];
  __shared__ float red[256];
  int tid = threadIdx.x;
  int b = blockIdx.x >> 6;
  int grp = blockIdx.x & 63;
  int p0 = grp * 32;
  for (int u = tid; u < NP * 3; u += 256) xl[u] = xt[(size_t)b * NP * 3 + u];
  for (int u = tid; u < 32 * NK; u += 256) lidx[u] = idx[((size_t)b * NP + p0) * NK + u];
  __syncthreads();
  int o = tid & 63;
  int pb = tid >> 6;
  float w0 = wt1[o], w1 = wt1[64 + o], w2 = wt1[128 + o];
  float d0 = wd1[o], d1 = wd1[64 + o], d2 = wd1[128 + o];
  float ps = 0.f, ps2 = 0.f;
#pragma unroll
  for (int i = 0; i < 8; ++i) {
    int pp = pb * 8 + i;
    int p = p0 + pp;
    float base = xl[p * 3] * d0 + xl[p * 3 + 1] * d1 + xl[p * 3 + 2] * d2;
    float mx = -3.4e38f, mn = 3.4e38f;
    for (int j = 0; j < NK; ++j) {
      int nb = lidx[pp * NK + j];
      float h = base + xl[nb * 3] * w0 + xl[nb * 3 + 1] * w1 + xl[nb * 3 + 2] * w2;
      mx = fmaxf(mx, h); mn = fminf(mn, h);
      ps += h; ps2 += h * h;
    }
    size_t P = (size_t)b * NP + p;
    hmax[P * 64 + o] = mx;
    hmin[P * 64 + o] = mn;
  }
  red[tid] = ps;
  __syncthreads();
  if (tid < 64) {
    float a = red[tid] + red[64 + tid] + red[128 + tid] + red[192 + tid];
    part[(size_t)blockIdx.x * 64 + tid] = a;
  }
  __syncthreads();
  red[tid] = ps2;
  __syncthreads();
  if (tid < 64) {
    float a = red[tid] + red[64 + tid] + red[128 + tid] + red[192 + tid];
    part[((size_t)gridDim.x + blockIdx.x) * 64 + tid] = a;
  }
}

// ---------------- dense per-point GEMM: yH[p] = x[p]·[W0 | W1-W0] (fp16 out) ----------------
// 64 rows/block, O2 cols (optionally N-split), 4 waves (mg 2 x ng 2).
template <int C, int O2, int NSPLIT>
__global__ __launch_bounds__(256) void k_dense_mfma(
    const _Float16* __restrict__ xh, int in_off,
    const _Float16* __restrict__ Bp, _Float16* __restrict__ yH) {
  constexpr int NCH = C / 64;
  constexpr int NO = O2 / NSPLIT;
  constexpr int NSLO = NO / 16;
  constexpr int NS = NSLO / 2;
  constexpr int PAIRS = 2 * NSLO;
  __shared__ __align__(16) _Float16 ldsA[64 * 64];
  __shared__ __align__(16) _Float16 ldsB[PAIRS * 512];
  int tid = threadIdx.x, wv = tid >> 6, l = tid & 63;
  int mblk = blockIdx.x, nid = 0;
  if (NSPLIT > 1) { nid = mblk >> 8; mblk &= 255; }   // BN/64 = 256 m-blocks
  int m0 = mblk * 64;
  int n_base = nid * NO;
  int mg = wv & 1, ng = wv >> 1;
  f32x4 acc[2][NS];
#pragma unroll
  for (int m = 0; m < 2; ++m)
#pragma unroll
    for (int s = 0; s < NS; ++s)
#pragma unroll
      for (int r = 0; r < 4; ++r) acc[m][s][r] = 0.f;

  for (int ch = 0; ch < NCH; ++ch) {
#pragma unroll
    for (int it = 0; it < 2; ++it) {
      int r0 = wv * 16 + it * 8;
      int R = r0 + (l >> 3);
      int q = (l & 7) ^ (l >> 3);
      gload_lds16(xh + (size_t)(m0 + R) * 512 + in_off + ch * 64 + q * 8, ldsA + r0 * 64);
    }
    for (int u = wv; u < PAIRS; u += 4) {
      int ks = u / NSLO, sloc = u - ks * NSLO;
      gload_lds16(Bp + ((size_t)((ch * 2 + ks) * (O2 / 16) + (n_base >> 4) + sloc) * 64 + l) * 8,
                  ldsB + u * 512);
    }
    __syncthreads();
#pragma unroll
    for (int ks = 0; ks < 2; ++ks) {
      half8 b[NS];
#pragma unroll
      for (int s = 0; s < NS; ++s)
        b[s] = *(const half8*)(ldsB + (ks * NSLO + ng * NS + s) * 512 + l * 8);
#pragma unroll
      for (int mt = 0; mt < 2; ++mt) {
        int row = mg * 32 + mt * 16 + (l & 15);
        int slot = (ks * 4 + (l >> 4)) ^ (row & 7);
        half8 a = *(const half8*)(ldsA + row * 64 + slot * 8);
#pragma unroll
        for (int s = 0; s < NS; ++s)
          acc[mt][s] = __builtin_amdgcn_mfma_f32_16x16x32_f16(a, b[s], acc[mt][s], 0, 0, 0);
      }
    }
    __syncthreads();
  }
  int g = l >> 4;
#pragma unroll
  for (int s = 0; s < NS; ++s) {
    int col = n_base + ng * (NS * 16) + s * 16 + (l & 15);
#pragma unroll
    for (int mt = 0; mt < 2; ++mt)
#pragma unroll
      for (int r = 0; r < 4; ++r) {
        int row = m0 + mg * 32 + mt * 16 + 4 * g + r;
        yH[(size_t)row * O2 + col] = (_Float16)acc[mt][s][r];
      }
  }
}

// ---------------- gather-max pass: per point, max/min/sum/sumsq over 20 nbrs ----------------
// h[p,j,o] = y[nbr_j][o] + sbase[p][o]; yH = [y | sbase] fp16, row stride 2O.
// Thread (pp, colgroup g of 4): fully coalesced 8B row-segment reads (L2-resident).
template <int O>
__global__ __launch_bounds__(256) void k_gather(
    const _Float16* __restrict__ yH, const int* __restrict__ idx,
    float* __restrict__ hmax, float* __restrict__ hmin,
    float* __restrict__ part) {
  constexpr int O2 = 2 * O;
  constexpr int CG = O / 4;          // 8B col groups
  constexpr int PPB = 256 / CG;      // points per block
  __shared__ int lidx[PPB * NK];
  __shared__ float4 redS[256], redQ[256];
  int tid = threadIdx.x;
  int p0 = blockIdx.x * PPB;
  int bbase = p0 & ~(NP - 1);
  for (int u = tid; u < PPB * NK; u += 256) lidx[u] = idx[(size_t)p0 * NK + u];
  __syncthreads();
  int pp = tid / CG, g = tid - pp * CG;
  int p = p0 + pp;
  half4v sb4 = *(const half4v*)&yH[(size_t)p * O2 + O + g * 4];
  float sb[4] = {(float)sb4[0], (float)sb4[1], (float)sb4[2], (float)sb4[3]};
  float mx[4], mn[4], sm[4], sq[4];
#pragma unroll
  for (int e = 0; e < 4; ++e) { mx[e] = -3.4e38f; mn[e] = 3.4e38f; sm[e] = 0.f; sq[e] = 0.f; }
#pragma unroll
  for (int j = 0; j < NK; ++j) {
    int nb = bbase + lidx[pp * NK + j];
    half4v y4 = *(const half4v*)&yH[(size_t)nb * O2 + g * 4];
#pragma unroll
    for (int e = 0; e < 4; ++e) {
      float h = (float)y4[e] + sb[e];
      mx[e] = fmaxf(mx[e], h); mn[e] = fminf(mn[e], h);
      sm[e] += h; sq[e] += h * h;
    }
  }
  *(float4*)&hmax[(size_t)p * O + g * 4] = make_float4(mx[0], mx[1], mx[2], mx[3]);
  *(float4*)&hmin[(size_t)p * O + g * 4] = make_float4(mn[0], mn[1], mn[2], mn[3]);
  redS[tid] = make_float4(sm[0], sm[1], sm[2], sm[3]);
  redQ[tid] = make_float4(sq[0], sq[1], sq[2], sq[3]);
  __syncthreads();
  if (tid < CG) {
    float4 a = redS[tid], q = redQ[tid];
    for (int k = 1; k < PPB; ++k) {
      float4 b = redS[tid + k * CG], c = redQ[tid + k * CG];
      a.x += b.x; a.y += b.y; a.z += b.z; a.w += b.w;
      q.x += c.x; q.y += c.y; q.z += c.z; q.w += c.w;
    }
    *(float4*)&part[(size_t)blockIdx.x * O + tid * 4] = a;
    *(float4*)&part[((size_t)gridDim.x + blockIdx.x) * O + tid * 4] = q;
  }
}

// ---------------- conv5 MFMA: h5 = xcatH(16384x512) * B5(512x1024) ----------------
__global__ __launch_bounds__(256) void k_conv5_mfma(
    const _Float16* __restrict__ xh, const _Float16* __restrict__ Bp,
    _Float16* __restrict__ h5, float* __restrict__ part) {
  __shared__ __align__(16) _Float16 ldsA[64 * 64];     // 8KB
  __shared__ __align__(16) _Float16 ldsB[32 * 512];    // 32KB
  __shared__ float ldsS[2][256], ldsQ[2][256], ldsMx[2][256], ldsMn[2][256];
  int tid = threadIdx.x, wv = tid >> 6, l = tid & 63;
  int mblk = blockIdx.x & 255, nid = blockIdx.x >> 8;
  int m0 = mblk * 64;
  int n_base = nid * 256;
  int mg = wv & 1, ng = wv >> 1;
  f32x4 acc[2][8];
#pragma unroll
  for (int m = 0; m < 2; ++m)
#pragma unroll
    for (int s = 0; s < 8; ++s)
#pragma unroll
      for (int r = 0; r < 4; ++r) acc[m][s][r] = 0.f;

  for (int ch = 0; ch < 8; ++ch) {
#pragma unroll
    for (int it = 0; it < 2; ++it) {
      int r0 = wv * 16 + it * 8;
      int R = r0 + (l >> 3);
      int q = (l & 7) ^ (l >> 3);
      gload_lds16(xh + (size_t)(m0 + R) * 512 + ch * 64 + q * 8, ldsA + r0 * 64);
    }
    for (int u = wv; u < 32; u += 4) {
      int ks = u >> 4, sloc = u & 15;
      gload_lds16(Bp + ((size_t)((ch * 2 + ks) * 64 + (n_base >> 4) + sloc) * 64 + l) * 8,
                  ldsB + u * 512);
    }
    __syncthreads();
#pragma unroll
    for (int ks = 0; ks < 2; ++ks) {
      half8 b[8];
#pragma unroll
      for (int s = 0; s < 8; ++s)
        b[s] = *(const half8*)(ldsB + (ks * 16 + ng * 8 + s) * 512 + l * 8);
#pragma unroll
      for (int mt = 0; mt < 2; ++mt) {
        int row = mg * 32 + mt * 16 + (l & 15);
        int slot = (ks * 4 + (l >> 4)) ^ (row & 7);
        half8 a = *(const half8*)(ldsA + row * 64 + slot * 8);
#pragma unroll
        for (int s = 0; s < 8; ++s)
          acc[mt][s] = __builtin_amdgcn_mfma_f32_16x16x32_f16(a, b[s], acc[mt][s], 0, 0, 0);
      }
    }
    __syncthreads();
  }
  int g = l >> 4;
#pragma unroll
  for (int s = 0; s < 8; ++s) {
    float sm = 0.f, sq = 0.f, mx = -3.4e38f, mn = 3.4e38f;
    int col = n_base + ng * 128 + s * 16 + (l & 15);
#pragma unroll
    for (int mt = 0; mt < 2; ++mt)
#pragma unroll
      for (int r = 0; r < 4; ++r) {
        float v = acc[mt][s][r];
        int row = m0 + mg * 32 + mt * 16 + 4 * g + r;
        h5[(size_t)row * 1024 + col] = (_Float16)v;
        sm += v; sq += v * v; mx = fmaxf(mx, v); mn = fminf(mn, v);
      }
    sm += __shfl_xor(sm, 16); sm += __shfl_xor(sm, 32);
    sq += __shfl_xor(sq, 16); sq += __shfl_xor(sq, 32);
    mx = fmaxf(mx, __shfl_xor(mx, 16)); mx = fmaxf(mx, __shfl_xor(mx, 32));
    mn = fminf(mn, __shfl_xor(mn, 16)); mn = fminf(mn, __shfl_xor(mn, 32));
    if (l < 16) {
      int u = ng * 128 + s * 16 + l;
      ldsS[mg][u] = sm; ldsQ[mg][u] = sq; ldsMx[mg][u] = mx; ldsMn[mg][u] = mn;
    }
  }
  __syncthreads();
  {
    int u = tid;
    int col = n_base + u;
    part[(size_t)mblk * 1024 + col] = ldsS[0][u] + ldsS[1][u];
    part[((size_t)256 + mblk) * 1024 + col] = ldsQ[0][u] + ldsQ[1][u];
    part[((size_t)512 + mblk) * 1024 + col] = fmaxf(ldsMx[0][u], ldsMx[1][u]);
    part[((size_t)768 + mblk) * 1024 + col] = fminf(ldsMn[0][u], ldsMn[1][u]);
  }
}

// reduce partials -> per-channel BN scale/shift. grid = O blocks.
__global__ __launch_bounds__(256) void k_finalize(
    const float* __restrict__ part, int G, int O, float inv_count,
    const float* __restrict__ gamma, const float* __restrict__ beta,
    float* __restrict__ ss) {
  int o = blockIdx.x;
  float s = 0.f, s2 = 0.f;
  for (int g = threadIdx.x; g < G; g += 256) {
    s  += part[(size_t)g * O + o];
    s2 += part[((size_t)G + g) * O + o];
  }
#pragma unroll
  for (int sft = 32; sft; sft >>= 1) {
    s  += __shfl_down(s, sft);
    s2 += __shfl_down(s2, sft);
  }
  __shared__ float aw[4], aw2[4];
  int w = threadIdx.x >> 6;
  if ((threadIdx.x & 63) == 0) { aw[w] = s; aw2[w] = s2; }
  __syncthreads();
  if (threadIdx.x == 0) {
    s = aw[0] + aw[1] + aw[2] + aw[3];
    s2 = aw2[0] + aw2[1] + aw2[2] + aw2[3];
    float m   = s * inv_count;
    float var = s2 * inv_count - m * m;
    float scale = gamma[o] * rsqrtf(var + 1e-5f);
    ss[o]     = scale;
    ss[O + o] = beta[o] - m * scale;
  }
}

// apply BN+lrelu to (max or min per sign of scale), write fp16 into xcatH slice
__global__ void k_edge_apply(const float* __restrict__ hmax, const float* __restrict__ hmin,
                             const float* __restrict__ ss, _Float16* __restrict__ xh,
                             int O, int off) {
  int t = blockIdx.x * 256 + threadIdx.x;
  int o = t % O;
  int p = t / O;
  float scale = ss[o], shift = ss[O + o];
  float v = (scale >= 0.f) ? hmax[t] : hmin[t];
  v = scale * v + shift;
  v = (v >= 0.f) ? v : 0.2f * v;
  xh[(size_t)p * 512 + off + o] = (_Float16)v;
}

// conv5 mean-pool partials: grid = 8b*8ns*4cg = 256 blocks
__global__ __launch_bounds__(256) void k_pool5a(const _Float16* __restrict__ h5,
                                                const float* __restrict__ ss,
                                                float* __restrict__ pmean) {
  int bi = blockIdx.x;
  int b = bi >> 5, ns = (bi >> 2) & 7, cg = bi & 3;
  int col = cg * 256 + threadIdx.x;
  float scale = ss[col], shift = ss[1024 + col];
  float sm = 0.f;
  for (int n = ns * 256; n < ns * 256 + 256; ++n) {
    float v = (float)h5[(size_t)(b * 2048 + n) * 1024 + col];
    float y = scale * v + shift;
    y = (y >= 0.f) ? y : 0.2f * y;
    sm += y;
  }
  pmean[(size_t)(b * 8 + ns) * 1024 + col] = sm;
}

// final pool: exact max via fp32 partials (BN+lrelu commute), mean via pmean
__global__ __launch_bounds__(256) void k_pool5b(const float* __restrict__ part,
                                                const float* __restrict__ pmean,
                                                const float* __restrict__ ss,
                                                float* __restrict__ z) {
  int bi = blockIdx.x;
  int b = bi >> 2, cg = bi & 3;
  int col = cg * 256 + threadIdx.x;
  float scale = ss[col], shift = ss[1024 + col];
  const float* pmx = part + (size_t)512 * 1024;
  const float* pmn = part + (size_t)768 * 1024;
  float mxh = -3.4e38f, mnh = 3.4e38f;
  for (int q = 0; q < 32; ++q) {
    size_t base = (size_t)(b * 32 + q) * 1024 + col;
    mxh = fmaxf(mxh, pmx[base]);
    mnh = fminf(mnh, pmn[base]);
  }
  float hsel = (scale >= 0.f) ? mxh : mnh;
  float zmax = scale * hsel + shift;
  zmax = (zmax >= 0.f) ? zmax : 0.2f * zmax;
  float sm = 0.f;
  for (int ns = 0; ns < 8; ++ns) sm += pmean[(size_t)(b * 8 + ns) * 1024 + col];
  z[b * 2048 + col] = zmax;
  z[b * 2048 + 1024 + col] = sm * (1.f / 2048.f);
}

// generic FC: one wave per (b,o); float4-vectorized loads (IN % 256 == 0)
__global__ __launch_bounds__(64) void k_fc(const float* __restrict__ in,
                                           const float* __restrict__ Wf,
                                           const float* __restrict__ bias,
                                           float* __restrict__ out, int IN, int O) {
  int blk = blockIdx.x;
  int b = blk / O, o = blk % O;
  const float4* a = (const float4*)(in + (size_t)b * IN);
  const float4* w = (const float4*)(Wf + (size_t)o * IN);
  float s = 0.f;
  for (int i = threadIdx.x; i < (IN >> 2); i += 64) {
    float4 av = a[i], wv = w[i];
    s += av.x * wv.x + av.y * wv.y + av.z * wv.z + av.w * wv.w;
  }
#pragma unroll
  for (int sft = 32; sft; sft >>= 1) s += __shfl_down(s, sft);
  if (threadIdx.x == 0) out[(size_t)b * O + o] = s + (bias ? bias[o] : 0.f);
}

// batch-axis BN (count=8) + lrelu
__global__ void k_bn_fc(const float* __restrict__ pre, const float* __restrict__ gamma,
                        const float* __restrict__ beta, float* __restrict__ out, int O) {
  int o = blockIdx.x * 256 + threadIdx.x;
  if (o >= O) return;
  float v[NB];
  float s = 0.f, s2 = 0.f;
#pragma unroll
  for (int b = 0; b < NB; ++b) {
    v[b] = pre[(size_t)b * O + o];
    s += v[b]; s2 += v[b] * v[b];
  }
  float m = s * (1.f / NB);
  float var = s2 * (1.f / NB) - m * m;
  float scale = gamma[o] * rsqrtf(var + 1e-5f);
  float shift = beta[o] - m * scale;
#pragma unroll
  for (int b = 0; b < NB; ++b) {
    float x = scale * v[b] + shift;
    out[(size_t)b * O + o] = (x >= 0.f) ? x : 0.2f * x;
  }
}

// ---------------- launcher ----------------
extern "C" void kernel_launch(void* const* d_in, const int* in_sizes, int n_in,
                              void* d_out, int out_size, void* d_ws, size_t ws_size,
                              hipStream_t stream) {
  (void)in_sizes; (void)n_in; (void)out_size; (void)ws_size;
  const float* x    = (const float*)d_in[0];
  const float* geod = (const float*)d_in[1];
  const float* W1   = (const float*)d_in[2];
  const float* g1   = (const float*)d_in[3];
  const float* bt1  = (const float*)d_in[4];
  const float* W2   = (const float*)d_in[5];
  const float* g2   = (const float*)d_in[6];
  const float* bt2  = (const float*)d_in[7];
  const float* W3   = (const float*)d_in[8];
  const float* g3   = (const float*)d_in[9];
  const float* bt3  = (const float*)d_in[10];
  const float* W4   = (const float*)d_in[11];
  const float* g4   = (const float*)d_in[12];
  const float* bt4  = (const float*)d_in[13];
  const float* W5   = (const float*)d_in[14];
  const float* g5   = (const float*)d_in[15];
  const float* bt5  = (const float*)d_in[16];
  const float* L1   = (const float*)d_in[17];
  const float* g6   = (const float*)d_in[18];
  const float* bt6  = (const float*)d_in[19];
  const float* L2   = (const float*)d_in[20];
  const float* bl2  = (const float*)d_in[21];
  const float* g7   = (const float*)d_in[22];
  const float* bt7  = (const float*)d_in[23];
  const float* L3   = (const float*)d_in[24];
  const float* bl3  = (const float*)d_in[25];

  char* ws = (char*)d_ws;
  int*       idx   = (int*)(ws + OFF_IDX);
  float*     xt    = (float*)(ws + OFF_XT);
  _Float16*  xcatH = (_Float16*)(ws + OFF_XCATH);
  float*     wt1   = (float*)(ws + OFF_WT1);
  float*     wd1   = (float*)(ws + OFF_WD1);
  _Float16*  bc2   = (_Float16*)(ws + OFF_BC2);
  _Float16*  bc3   = (_Float16*)(ws + OFF_BC3);
  _Float16*  bc4   = (_Float16*)(ws + OFF_BC4);
  _Float16*  b5    = (_Float16*)(ws + OFF_B5);
  _Float16*  yH    = (_Float16*)(ws + OFF_YH);
  float*     hmax  = (float*)(ws + OFF_HMAX);
  float*     hmin  = (float*)(ws + OFF_HMIN);
  _Float16*  h5    = (_Float16*)(ws + OFF_H5);
  float*     part  = (float*)(ws + OFF_PART);
  float*     pmean = (float*)(ws + OFF_PMEAN);
  float*     ssb   = (float*)(ws + OFF_SS);
  float*     z     = (float*)(ws + OFF_Z);
  float*     z1p   = (float*)(ws + OFF_Z1P);
  float*     z1    = (float*)(ws + OFF_Z1);
  float*     z2p   = (float*)(ws + OFF_Z2P);
  float*     z2    = (float*)(ws + OFF_Z2);

  const float invE = 1.f / (float)(BN * NK);
  const float inv5 = 1.f / (float)(BN);

  k_prep_all<<<PB_END, 256, 0, stream>>>(x, xt, W1, wt1, wd1,
                                         W2, bc2, W3, bc3, W4, bc4, W5, b5);
  k_topk<<<BN / 4, 256, 0, stream>>>(geod, idx);

  // layer 1 (C=3, fp32, whole-cloud LDS)
  k_edge1<<<512, 256, 0, stream>>>(xt, idx, wt1, wd1, hmax, hmin, part);
  k_finalize<<<64, 256, 0, stream>>>(part, 512, 64, invE, g1, bt1, ssb);
  k_edge_apply<<<(BN * 64) / 256, 256, 0, stream>>>(hmax, hmin, ssb, xcatH, 64, 0);
  // layer 2 (C=64 -> O=64): dense y|sbase GEMM + gather-max
  k_dense_mfma<64, 128, 1><<<256, 256, 0, stream>>>(xcatH, 0, bc2, yH);
  k_gather<64><<<BN / 16, 256, 0, stream>>>(yH, idx, hmax, hmin, part);
  k_finalize<<<64, 256, 0, stream>>>(part, BN / 16, 64, invE, g2, bt2, ssb);
  k_edge_apply<<<(BN * 64) / 256, 256, 0, stream>>>(hmax, hmin, ssb, xcatH, 64, 64);
  // layer 3 (C=64 -> O=128)
  k_dense_mfma<64, 256, 1><<<256, 256, 0, stream>>>(xcatH, 64, bc3, yH);
  k_gather<128><<<BN / 8, 256, 0, stream>>>(yH, idx, hmax, hmin, part);
  k_finalize<<<128, 256, 0, stream>>>(part, BN / 8, 128, invE, g3, bt3, ssb);
  k_edge_apply<<<(BN * 128) / 256, 256, 0, stream>>>(hmax, hmin, ssb, xcatH, 128, 128);
  // layer 4 (C=128 -> O=256)
  k_dense_mfma<128, 512, 2><<<512, 256, 0, stream>>>(xcatH, 128, bc4, yH);
  k_gather<256><<<BN / 4, 256, 0, stream>>>(yH, idx, hmax, hmin, part);
  k_finalize<<<256, 256, 0, stream>>>(part, BN / 4, 256, invE, g4, bt4, ssb);
  k_edge_apply<<<(BN * 256) / 256, 256, 0, stream>>>(hmax, hmin, ssb, xcatH, 256, 256);

  // conv5 (16384x512 @ 512x1024)
  k_conv5_mfma<<<1024, 256, 0, stream>>>(xcatH, b5, h5, part);
  k_finalize<<<1024, 256, 0, stream>>>(part, 256, 1024, inv5, g5, bt5, ssb);
  k_pool5a<<<256, 256, 0, stream>>>(h5, ssb, pmean);
  k_pool5b<<<32, 256, 0, stream>>>(part, pmean, ssb, z);

  // FC head
  k_fc<<<NB * 512, 64, 0, stream>>>(z, L1, nullptr, z1p, 2048, 512);
  k_bn_fc<<<2, 256, 0, stream>>>(z1p, g6, bt6, z1, 512);
  k_fc<<<NB * 256, 64, 0, stream>>>(z1, L2, bl2, z2p, 512, 256);
  k_bn_fc<<<1, 256, 0, stream>>>(z2p, g7, bt7, z2, 256);
  k_fc<<<NB * 40, 64, 0, stream>>>(z2, L3, bl3, (float*)d_out, 256, 40);
}